// Round 1
// baseline (8386.223 us; speedup 1.0000x reference)
//
#include <hip/hip_runtime.h>

#define HW 1296
#define HW4 324
#define Tt 16
#define T2 32
#define Nn 20736
#define N2 41472
#define TTILE 162

// ---------------- utility kernels ----------------

__global__ void k_zero(float* p, int n){
  int i = blockIdx.x*blockDim.x + threadIdx.x;
  if (i < n) p[i] = 0.f;
}

// w layout (Cout,Cin,KT) -> wT layout (KT,Cin,Cout)
__global__ void k_wtrans(const float* __restrict__ w, float* __restrict__ wT,
                         int Cout, int Cin, int KT){
  int idx = blockIdx.x*blockDim.x + threadIdx.x;
  int tot = Cout*Cin*KT;
  if (idx >= tot) return;
  int o  = idx / (Cin*KT);
  int r  = idx % (Cin*KT);
  int i  = r / KT;
  int dt = r % KT;
  wT[((size_t)dt*Cin + i)*Cout + o] = w[idx];
}

// generic temporal conv (kernel (KT,1,1)), raw output (no bias, no BN)
// input element (b,i,tl,hw) at xp[((b*Cin+i)*Tpart + tl)*HW + hw]; split at t_split to xB
__global__ void k_tconv(const float* __restrict__ xA, const float* __restrict__ xB,
                        int t_split, int Tpart,
                        const float* __restrict__ wT,
                        float* __restrict__ out,
                        int Cin, int Cout, int Tin, int Tout, int stride, int KT, int pad,
                        int out_cstride, int out_coff, int OC)
{
  int b  = blockIdx.z / OC;
  int oc = blockIdx.z % OC;
  int o  = oc*blockDim.x + threadIdx.x;
  int t  = blockIdx.y;
  int hw4 = blockIdx.x*blockDim.y + threadIdx.y;
  if (hw4 >= HW4) return;
  float4 acc = make_float4(0.f,0.f,0.f,0.f);
  for (int dt=0; dt<KT; ++dt){
    int tt = t*stride + dt - pad;
    if (tt < 0 || tt >= Tin) continue;
    const float* xp = (tt < t_split) ? xA : xB;
    int tl = (tt < t_split) ? tt : (tt - t_split);
    const float4* xr = (const float4*)xp + ((size_t)b*Cin*Tpart + tl)*HW4 + hw4;
    const float* wp  = wT + (size_t)dt*Cin*Cout + o;
    size_t xstep = (size_t)Tpart*HW4;
    for (int i=0; i<Cin; ++i){
      float4 xv = *xr;
      float  wv = *wp;
      acc.x = fmaf(wv, xv.x, acc.x);
      acc.y = fmaf(wv, xv.y, acc.y);
      acc.z = fmaf(wv, xv.z, acc.z);
      acc.w = fmaf(wv, xv.w, acc.w);
      xr += xstep; wp += Cout;
    }
  }
  float4* op = (float4*)out + ((size_t)(b*out_cstride + out_coff + o)*Tout + t)*HW4 + hw4;
  *op = acc;
}

// per-channel sum/sumsq over (b in [0,4), l in [0,L)); element at x[b*bstride + c*cstride + l]
__global__ void k_bnstats(const float* __restrict__ x, int Bn, int Cn, int L,
                          long bstride, long cstride, float* __restrict__ sums)
{
  int c = blockIdx.y;
  int tid = threadIdx.x;
  float s = 0.f, sq = 0.f;
  int tot = Bn*L;
  for (int idx = blockIdx.x*blockDim.x + tid; idx < tot; idx += gridDim.x*blockDim.x){
    int b = idx / L; int l = idx - b*L;
    float v = x[(size_t)b*bstride + (size_t)c*cstride + l];
    s += v; sq += v*v;
  }
  __shared__ float r1[256], r2[256];
  r1[tid] = s; r2[tid] = sq; __syncthreads();
  for (int k=128; k>0; k>>=1){
    if (tid < k){ r1[tid]+=r1[tid+k]; r2[tid]+=r2[tid+k]; }
    __syncthreads();
  }
  if (tid == 0){ atomicAdd(&sums[c], r1[0]); atomicAdd(&sums[Cn+c], r2[0]); }
}

__global__ void k_bnrelu(float* __restrict__ x, int Cn, int L, long bstride, long cstride,
                         const float* __restrict__ sums, const float* __restrict__ g,
                         const float* __restrict__ bet, float invc)
{
  int c = blockIdx.y, b = blockIdx.z;
  int l = blockIdx.x*blockDim.x + threadIdx.x;
  if (l >= L) return;
  float m  = sums[c]*invc;
  float v  = fmaxf(sums[Cn+c]*invc - m*m, 0.f);
  float sc = g[c]*rsqrtf(v + 1e-5f);
  float bb = bet[c] - m*sc;
  size_t idx = (size_t)b*bstride + (size_t)c*cstride + l;
  float val = fmaf(x[idx], sc, bb);
  x[idx] = fmaxf(val, 0.f);
}

// ---------------- PAM encoder ----------------

__global__ void k_meanT(const float* __restrict__ x, float* __restrict__ xm){
  int c = blockIdx.y, b = blockIdx.z;
  int hw = blockIdx.x*blockDim.x + threadIdx.x;
  if (hw >= HW) return;
  const float* xp = x + ((size_t)(b*64+c)*Tt)*HW + hw;
  float s = 0.f;
  for (int t=0; t<Tt; ++t) s += xp[(size_t)t*HW];
  xm[(size_t)(b*64+c)*HW + hw] = s*(1.f/16.f);
}

__global__ void k_pool(const float* __restrict__ xm, float* __restrict__ pp){
  int c = blockIdx.y, b = blockIdx.z;
  int cell = threadIdx.x;
  if (cell >= 50) return;
  int s, off;
  if (cell < 1){ s=1; off=0; } else if (cell < 5){ s=2; off=1; }
  else if (cell < 14){ s=3; off=5; } else { s=6; off=14; }
  int local = cell - off, ph = local/s, pw = local%s, bh = 36/s;
  const float* xp = xm + (size_t)(b*64+c)*HW;
  float sum = 0.f;
  for (int h = ph*bh; h < (ph+1)*bh; ++h)
    for (int w = pw*bh; w < (pw+1)*bh; ++w) sum += xp[h*36 + w];
  pp[(size_t)(b*64+c)*50 + cell] = sum / (float)(bh*bh);
}

__global__ void k_pemm(const float* __restrict__ pp, const float* __restrict__ pew,
                       float* __restrict__ pf){
  int cell = blockIdx.x, b = blockIdx.z;
  int o = threadIdx.x;  // 64
  int sc;
  if (cell < 1) sc=0; else if (cell < 5) sc=1; else if (cell < 14) sc=2; else sc=3;
  const float* w = pew + (size_t)sc*4096 + o*64;
  const float* p = pp + (size_t)b*3200 + cell;
  float s = 0.f;
  for (int i=0; i<64; ++i) s = fmaf(w[i], p[(size_t)i*50], s);
  pf[(size_t)(b*64+o)*50 + cell] = s;
}

__global__ void k_ytrans(const float* __restrict__ pf, float* __restrict__ y){
  int k = blockIdx.x, b = blockIdx.z; int c = threadIdx.x;
  y[((size_t)b*50 + k)*64 + c] = pf[((size_t)b*64 + c)*50 + k];
}

__global__ void k_pamkv(const float* __restrict__ y, const float* __restrict__ wk,
                        const float* __restrict__ bk, const float* __restrict__ wv,
                        const float* __restrict__ bv,
                        float* __restrict__ kb, float* __restrict__ vb){
  int kk = blockIdx.x, b = blockIdx.z; int t = threadIdx.x;
  const float* yp = y + ((size_t)b*50 + kk)*64;
  if (t < 16){
    float s = bk[t]; const float* w = wk + t*64;
    for (int i=0; i<64; ++i) s = fmaf(w[i], yp[i], s);
    kb[((size_t)b*50 + kk)*16 + t] = s;
  } else if (t < 80){
    int c = t - 16;
    float s = bv[c]; const float* w = wv + c*64;
    for (int i=0; i<64; ++i) s = fmaf(w[i], yp[i], s);
    vb[((size_t)b*50 + kk)*64 + c] = s;
  }
}

// q = Wq x + bq; attn = softmax(q k^T); out = x + scale * (attn @ v)
__global__ void k_pamattn(const float* __restrict__ x, const float* __restrict__ kb,
                          const float* __restrict__ vb, const float* __restrict__ wq,
                          const float* __restrict__ bq, const float* __restrict__ scp,
                          float* __restrict__ outp)
{
  __shared__ float kl[800];
  __shared__ float vl[3200];
  int b = blockIdx.z;
  int n = blockIdx.x*256 + threadIdx.x;  // N = 81*256 exact
  for (int i=threadIdx.x; i<800;  i+=256) kl[i] = kb[(size_t)b*800 + i];
  for (int i=threadIdx.x; i<3200; i+=256) vl[i] = vb[(size_t)b*3200 + i];
  __syncthreads();
  float q[16];
  for (int o=0; o<16; ++o) q[o] = bq[o];
  const float* xb = x + (size_t)b*64*Nn + n;
  for (int i=0; i<64; ++i){
    float xv = xb[(size_t)i*Nn];
    for (int o=0; o<16; ++o) q[o] = fmaf(wq[o*64+i], xv, q[o]);
  }
  float lg[50]; float mx = -1e30f;
  for (int kk=0; kk<50; ++kk){
    float s = 0.f;
    for (int o=0; o<16; ++o) s = fmaf(q[o], kl[kk*16+o], s);
    lg[kk] = s; mx = fmaxf(mx, s);
  }
  float sum = 0.f;
  for (int kk=0; kk<50; ++kk){ float p = expf(lg[kk]-mx); lg[kk]=p; sum+=p; }
  float inv = 1.f/sum;
  float sc = scp[0];
  float* ob = outp + (size_t)b*64*Nn + n;
  for (int c=0; c<64; ++c){
    float acc = 0.f;
    for (int kk=0; kk<50; ++kk) acc = fmaf(lg[kk], vl[kk*64+c], acc);
    ob[(size_t)c*Nn] = fmaf(sc*inv, acc, xb[(size_t)c*Nn]);
  }
}

// ---------------- CAM ----------------

__global__ void k_camenergy(const float* __restrict__ x, const float* __restrict__ yc,
                            float* __restrict__ e){
  int c = blockIdx.y, b = blockIdx.z, tid = threadIdx.x;
  const float4* x4 = (const float4*)x + (size_t)(b*64+c)*5184;
  const float4* y4 = (const float4*)yc + (size_t)b*4*5184;
  float acc[4] = {0.f,0.f,0.f,0.f};
  for (int n4=tid; n4<5184; n4+=256){
    float4 xv = x4[n4];
    for (int kk=0; kk<4; ++kk){
      float4 yv = y4[kk*5184 + n4];
      acc[kk] += xv.x*yv.x + xv.y*yv.y + xv.z*yv.z + xv.w*yv.w;
    }
  }
  __shared__ float red[256];
  for (int kk=0; kk<4; ++kk){
    red[tid] = acc[kk]; __syncthreads();
    for (int s=128; s>0; s>>=1){ if (tid < s) red[tid]+=red[tid+s]; __syncthreads(); }
    if (tid == 0) e[(size_t)(b*64+c)*4 + kk] = red[0];
    __syncthreads();
  }
}

__global__ void k_camapply(const float* __restrict__ x, const float* __restrict__ yc,
                           const float* __restrict__ e, const float* __restrict__ scp,
                           float* __restrict__ out){
  int n4 = blockIdx.x*256 + threadIdx.x;
  if (n4 >= 5184) return;
  int c = blockIdx.y, b = blockIdx.z;
  const float* er = e + (size_t)(b*64+c)*4;
  float e0=er[0], e1=er[1], e2=er[2], e3=er[3];
  float mx = fmaxf(fmaxf(e0,e1), fmaxf(e2,e3));
  float z0=mx-e0, z1=mx-e1, z2=mx-e2, z3=mx-e3;
  float zm = fmaxf(fmaxf(z0,z1), fmaxf(z2,z3));
  float p0=expf(z0-zm), p1=expf(z1-zm), p2=expf(z2-zm), p3=expf(z3-zm);
  float inv = 1.f/(p0+p1+p2+p3);
  p0*=inv; p1*=inv; p2*=inv; p3*=inv;
  float sc = scp[0];
  const float4* y4 = (const float4*)yc + (size_t)b*4*5184;
  float4 ya = y4[0*5184+n4], yb2 = y4[1*5184+n4], yc2 = y4[2*5184+n4], yd = y4[3*5184+n4];
  float4 xv = ((const float4*)x)[(size_t)(b*64+c)*5184 + n4];
  float4 o;
  o.x = fmaf(sc, p0*ya.x + p1*yb2.x + p2*yc2.x + p3*yd.x, xv.x);
  o.y = fmaf(sc, p0*ya.y + p1*yb2.y + p2*yc2.y + p3*yd.y, xv.y);
  o.z = fmaf(sc, p0*ya.z + p1*yb2.z + p2*yc2.z + p3*yd.z, xv.z);
  o.w = fmaf(sc, p0*ya.w + p1*yb2.w + p2*yc2.w + p3*yd.w, xv.w);
  ((float4*)out)[(size_t)(b*64+c)*5184 + n4] = o;
}

// ---------------- TAM ----------------

__global__ void k_tamenergy(const float* __restrict__ xf, const float* __restrict__ yf,
                            float* __restrict__ e){
  __shared__ float xt[32*TTILE];
  __shared__ float yt[32*TTILE];
  int hw0 = blockIdx.x*TTILE, c = blockIdx.y, b = blockIdx.z, tid = threadIdx.x;
  const float* xb = xf + (size_t)(b*64+c)*T2*HW;
  const float* yb = yf + (size_t)(b*64+c)*T2*HW;
  for (int idx=tid; idx<32*TTILE; idx+=256){
    int t = idx/TTILE, hl = idx - t*TTILE;
    xt[idx] = xb[(size_t)t*HW + hw0 + hl];
    yt[idx] = yb[(size_t)t*HW + hw0 + hl];
  }
  __syncthreads();
  int i  = tid >> 3;
  int j0 = (tid & 7)*4;
  float a0=0.f, a1=0.f, a2=0.f, a3=0.f;
  const float* xr = &xt[i*TTILE];
  const float* y0 = &yt[(j0+0)*TTILE];
  const float* y1 = &yt[(j0+1)*TTILE];
  const float* y2 = &yt[(j0+2)*TTILE];
  const float* y3 = &yt[(j0+3)*TTILE];
  for (int h=0; h<TTILE; ++h){
    float xv = xr[h];
    a0 = fmaf(xv, y0[h], a0);
    a1 = fmaf(xv, y1[h], a1);
    a2 = fmaf(xv, y2[h], a2);
    a3 = fmaf(xv, y3[h], a3);
  }
  float* ep = e + ((size_t)(b*32+i)*32 + j0);
  atomicAdd(ep+0, a0); atomicAdd(ep+1, a1);
  atomicAdd(ep+2, a2); atomicAdd(ep+3, a3);
}

__global__ void k_tamsoftmax(const float* __restrict__ e, float* __restrict__ at){
  int tid = threadIdx.x; if (tid >= 128) return;
  int b = tid >> 5, i = tid & 31;
  const float* er = e + ((size_t)b*32 + i)*32;
  float mx = -1e30f, mn = 1e30f;
  for (int j=0; j<32; ++j){ mx = fmaxf(mx, er[j]); mn = fminf(mn, er[j]); }
  float zmax = mx - mn;
  float sum = 0.f;
  float* ar = at + ((size_t)b*32 + i)*32;
  for (int j=0; j<32; ++j){ float p = expf((mx - er[j]) - zmax); ar[j]=p; sum+=p; }
  float inv = 1.f/sum;
  for (int j=0; j<32; ++j) ar[j] *= inv;
}

__global__ void k_tamapply(const float* __restrict__ x, const float* __restrict__ y,
                           const float* __restrict__ at, const float* __restrict__ scp,
                           float* __restrict__ out){
  __shared__ float yt[32*TTILE];
  __shared__ float al[1024];
  int hw0 = blockIdx.x*TTILE, c = blockIdx.y, b = blockIdx.z, tid = threadIdx.x;
  const float* yb = y + (size_t)(b*64+c)*T2*HW;
  for (int idx=tid; idx<32*TTILE; idx+=256){
    int t = idx/TTILE, hl = idx - t*TTILE;
    yt[idx] = yb[(size_t)t*HW + hw0 + hl];
  }
  for (int idx=tid; idx<1024; idx+=256) al[idx] = at[(size_t)b*1024 + idx];
  __syncthreads();
  float sc = scp[0];
  const float* xb = x + (size_t)(b*64+c)*T2*HW;
  float* ob = out + (size_t)(b*64+c)*T2*HW;
  for (int idx=tid; idx<32*TTILE; idx+=256){
    int t = idx/TTILE, hl = idx - t*TTILE;
    float acc = 0.f;
    const float* ar = &al[t*32];
    for (int j=0; j<32; ++j) acc = fmaf(ar[j], yt[j*TTILE + hl], acc);
    size_t g = (size_t)t*HW + hw0 + hl;
    ob[g] = fmaf(sc, acc, xb[g]);
  }
}

__global__ void k_copyxta(const float* __restrict__ g, float* __restrict__ c1,
                          float* __restrict__ c2){
  int idx = blockIdx.x*blockDim.x + threadIdx.x;
  const int per_b = 64*Tt*HW4;
  const int tot = 4*per_b;
  if (idx >= tot) return;
  int b = idx / per_b; int r = idx - b*per_b;
  float4 v = ((const float4*)g)[(size_t)b*per_b + r];
  size_t co = ((size_t)b*192 + 128)*Tt*HW4 + r;
  ((float4*)c1)[co] = v;
  ((float4*)c2)[co] = v;
}

// ---------------- host ----------------

extern "C" void kernel_launch(void* const* d_in, const int* in_sizes, int n_in,
                              void* d_out, int out_size, void* d_ws, size_t ws_size,
                              hipStream_t stream) {
  const float* x1      = (const float*)d_in[0];
  const float* x2      = (const float*)d_in[1];
  const float* w_conv1 = (const float*)d_in[2];
  const float* g_conv1 = (const float*)d_in[3];
  const float* b_conv1 = (const float*)d_in[4];
  const float* w_conv2 = (const float*)d_in[5];
  const float* g_conv2 = (const float*)d_in[6];
  const float* b_conv2 = (const float*)d_in[7];
  const float* w_tam   = (const float*)d_in[8];
  const float* g_tam   = (const float*)d_in[9];
  const float* b_tam   = (const float*)d_in[10];
  const float* w_cat   = (const float*)d_in[11];
  const float* g_cat   = (const float*)d_in[12];
  const float* b_cat   = (const float*)d_in[13];
  const float* pe_w    = (const float*)d_in[14];
  const float* pe_g    = (const float*)d_in[15];
  const float* pe_b    = (const float*)d_in[16];
  const float* pd_wq   = (const float*)d_in[17];
  const float* pd_bq   = (const float*)d_in[18];
  const float* pd_wk   = (const float*)d_in[19];
  const float* pd_bk   = (const float*)d_in[20];
  const float* pd_wv   = (const float*)d_in[21];
  const float* pd_bv   = (const float*)d_in[22];
  const float* pd_scale= (const float*)d_in[23];
  const float* ce_w    = (const float*)d_in[24];
  const float* ce_g    = (const float*)d_in[25];
  const float* ce_b    = (const float*)d_in[26];
  const float* cd_scale= (const float*)d_in[27];
  const float* te_w    = (const float*)d_in[28];
  const float* te_g    = (const float*)d_in[29];
  const float* te_b    = (const float*)d_in[30];
  const float* td_scale= (const float*)d_in[31];

  float* ws = (float*)d_ws;
  size_t off = 0;
  auto alloc = [&](size_t n){ float* p = ws + off; off += (n + 3) & ~(size_t)3; return p; };
  float* stats = alloc(16384);   // 32 slots x 512
  float* e_tam = alloc(4096);    // zeroed together with stats (contiguous)
  float* attn_t= alloc(4096);
  float* wT1   = alloc(3*256*64);
  float* wT2   = alloc(3*64*64);
  float* wTt   = alloc(3*64*64);
  float* wTc   = alloc(3*192*256);
  float* wTte  = alloc(64*64);
  float* wTce  = alloc(64*4);
  float* xm    = alloc(4*64*HW);
  float* pp    = alloc(4*64*50);
  float* pf    = alloc(4*64*50);
  float* yb    = alloc(4*50*64);
  float* kb    = alloc(4*50*16);
  float* vb    = alloc(4*50*64);
  float* yc    = alloc(4*4*Nn);
  float* e_cam = alloc(4*64*4);
  float* A     = alloc((size_t)4*64*Nn);      // x1i
  float* Bb    = alloc((size_t)4*64*Nn);      // x2i
  float* G     = alloc((size_t)4*64*Nn);      // scratch
  float* CAT   = alloc((size_t)2*4*192*Nn);   // CAT1|CAT2 ; also aliases Cc/D/E
  float* CAT1 = CAT;
  float* CAT2 = CAT + (size_t)4*192*Nn;
  float* Cc = CAT;                            // xt1 (B,64,32,HW)
  float* Dd = CAT + (size_t)4*64*N2;          // xt2
  float* Ee = CAT + (size_t)2*4*64*N2;        // tam out

  // zero stats + e_tam (contiguous 20480 floats)
  k_zero<<<dim3(80), 256, 0, stream>>>(stats, 20480);

  // weight transposes
  auto wtrans = [&](const float* w, float* wT, int Cout, int Cin, int KT){
    int tot = Cout*Cin*KT;
    k_wtrans<<<dim3((tot+255)/256), 256, 0, stream>>>(w, wT, Cout, Cin, KT);
  };
  wtrans(w_conv1, wT1, 64, 256, 3);
  wtrans(w_conv2, wT2, 64, 64, 3);
  wtrans(w_tam,  wTt, 64, 64, 3);
  wtrans(w_cat,  wTc, 256, 192, 3);
  wtrans(te_w,   wTte, 64, 64, 1);
  wtrans(ce_w,   wTce, 4, 64, 1);

  auto conv_bn = [&](const float* xA, const float* xB, int t_split, int Tpart,
                     const float* wTp, float* outp, int Cin, int Cout, int Tin, int Tout,
                     int stride, int KT, int pad, int out_cstride, int out_coff,
                     int slot, const float* g, const float* bt){
    int BX = (Cout >= 64) ? 64 : Cout;
    int BY = 256 / BX;
    int OC = (Cout >= 64) ? Cout/64 : 1;
    dim3 blk(BX, BY), grd((HW4 + BY - 1)/BY, Tout, 4*OC);
    k_tconv<<<grd, blk, 0, stream>>>(xA, xB, t_split, Tpart, wTp, outp,
                                     Cin, Cout, Tin, Tout, stride, KT, pad,
                                     out_cstride, out_coff, OC);
    float* sums = stats + (size_t)slot*512;
    int L = Tout*HW;
    float* base = outp + (size_t)out_coff*L;
    k_bnstats<<<dim3(16, Cout), 256, 0, stream>>>(base, 4, Cout, L,
                                                  (long)out_cstride*L, (long)L, sums);
    float invc = 1.f/(4.f*(float)L);
    k_bnrelu<<<dim3((L+255)/256, Cout, 4), 256, 0, stream>>>(base, Cout, L,
                                                  (long)out_cstride*L, (long)L,
                                                  sums, g, bt, invc);
  };

  // conv1 x3
  conv_bn(x1, nullptr, 16, 16, wT1, A,  256, 64, 16, 16, 1, 3, 1, 64, 0, 0, g_conv1, b_conv1);
  conv_bn(x2, nullptr, 16, 16, wT1, Bb, 256, 64, 16, 16, 1, 3, 1, 64, 0, 1, g_conv1, b_conv1);
  conv_bn(x1, x2,      16, 16, wT1, Cc, 256, 64, 32, 32, 1, 3, 1, 64, 0, 2, g_conv1, b_conv1);
  // xt2 = pw_bn_relu(xt1, te_w)
  conv_bn(Cc, nullptr, 32, 32, wTte, Dd, 64, 64, 32, 32, 1, 1, 0, 64, 0, 3, te_g, te_b);

  // TAM
  k_tamenergy<<<dim3(8, 64, 4), 256, 0, stream>>>(Cc, Dd, e_tam);
  k_tamsoftmax<<<dim3(1), 128, 0, stream>>>(e_tam, attn_t);
  k_tamapply<<<dim3(8, 64, 4), 256, 0, stream>>>(Cc, Dd, attn_t, td_scale, Ee);
  // x_ta = conv_bn_relu(tam, w_tam, stride 2)
  conv_bn(Ee, nullptr, 32, 32, wTt, G, 64, 64, 32, 16, 2, 3, 1, 64, 0, 4, g_tam, b_tam);
  // copy x_ta into both concat buffers (channels 128..191) -- CAT aliases Cc/D/E, all dead now
  k_copyxta<<<dim3((4*64*Tt*HW4 + 255)/256), 256, 0, stream>>>(G, CAT1, CAT2);

  // PAM encoder chain
  auto pam_enc = [&](const float* xin, int slotbase){
    k_meanT<<<dim3(6, 64, 4), 256, 0, stream>>>(xin, xm);
    k_pool<<<dim3(1, 64, 4), 64, 0, stream>>>(xm, pp);
    k_pemm<<<dim3(50, 1, 4), 64, 0, stream>>>(pp, pe_w, pf);
    const int ss[4] = {1,2,3,6}; const int so[4] = {0,1,5,14};
    for (int i=0; i<4; ++i){
      int s2 = ss[i]*ss[i];
      float* sums = stats + (size_t)(slotbase+i)*512;
      k_bnstats<<<dim3(1, 64), 256, 0, stream>>>(pf + so[i], 4, 64, s2, 3200L, 50L, sums);
      k_bnrelu<<<dim3(1, 64, 4), 256, 0, stream>>>(pf + so[i], 64, s2, 3200L, 50L,
                                                   sums, pe_g + i*64, pe_b + i*64,
                                                   1.f/(4.f*(float)s2));
    }
    k_ytrans<<<dim3(50, 1, 4), 64, 0, stream>>>(pf, yb);
    k_pamkv<<<dim3(50, 1, 4), 128, 0, stream>>>(yb, pd_wk, pd_bk, pd_wv, pd_bv, kb, vb);
  };

  // PAM x1 -> CAT1[0:64]
  pam_enc(A, 5);
  k_pamattn<<<dim3(81, 1, 4), 256, 0, stream>>>(A, kb, vb, pd_wq, pd_bq, pd_scale, G);
  conv_bn(G, nullptr, 16, 16, wT2, CAT1, 64, 64, 16, 16, 1, 3, 1, 192, 0, 13, g_conv2, b_conv2);
  // PAM x2 -> CAT2[0:64]
  pam_enc(Bb, 9);
  k_pamattn<<<dim3(81, 1, 4), 256, 0, stream>>>(Bb, kb, vb, pd_wq, pd_bq, pd_scale, G);
  conv_bn(G, nullptr, 16, 16, wT2, CAT2, 64, 64, 16, 16, 1, 3, 1, 192, 0, 14, g_conv2, b_conv2);

  // CAM
  auto cam = [&](const float* xin, float* catp, int slot_ce, int slot_c2){
    conv_bn(xin, nullptr, 16, 16, wTce, yc, 64, 4, 16, 16, 1, 1, 0, 4, 0, slot_ce, ce_g, ce_b);
    k_camenergy<<<dim3(1, 64, 4), 256, 0, stream>>>(xin, yc, e_cam);
    k_camapply<<<dim3(21, 64, 4), 256, 0, stream>>>(xin, yc, e_cam, cd_scale, G);
    conv_bn(G, nullptr, 16, 16, wT2, catp, 64, 64, 16, 16, 1, 3, 1, 192, 64, slot_c2, g_conv2, b_conv2);
  };
  cam(A,  CAT2, 15, 17);  // x1_ca -> CAT2[64:128]
  cam(Bb, CAT1, 16, 18);  // x2_ca -> CAT1[64:128]

  // final cat convs -> d_out
  float* out1 = (float*)d_out;
  float* out2 = out1 + (size_t)4*256*Nn;
  conv_bn(CAT1, nullptr, 16, 16, wTc, out1, 192, 256, 16, 16, 1, 3, 1, 256, 0, 19, g_cat, b_cat);
  conv_bn(CAT2, nullptr, 16, 16, wTc, out2, 192, 256, 16, 16, 1, 3, 1, 256, 0, 20, g_cat, b_cat);
}

// Round 2
// 1872.286 us; speedup vs baseline: 4.4791x; 4.4791x over previous
//
#include <hip/hip_runtime.h>

#define HW 1296
#define HW4 324
#define Tt 16
#define T2 32
#define Nn 20736
#define N2 41472
#define TTILE 162

typedef short bf16x8 __attribute__((ext_vector_type(8)));
typedef float f32x4 __attribute__((ext_vector_type(4)));

__device__ inline unsigned short f2b(float f){
  union { float f; unsigned u; } v; v.f = f;
  unsigned r = v.u + 0x7FFF + ((v.u >> 16) & 1);
  return (unsigned short)(r >> 16);
}

// ---------------- utility kernels ----------------

__global__ void k_zero(float* p, int n){
  int i = blockIdx.x*blockDim.x + threadIdx.x;
  if (i < n) p[i] = 0.f;
}

// w layout (Cout,Cin,KT) -> wT layout (KT,Cin,Cout)  (kept for ce pw conv only)
__global__ void k_wtrans(const float* __restrict__ w, float* __restrict__ wT,
                         int Cout, int Cin, int KT){
  int idx = blockIdx.x*blockDim.x + threadIdx.x;
  int tot = Cout*Cin*KT;
  if (idx >= tot) return;
  int o  = idx / (Cin*KT);
  int r  = idx % (Cin*KT);
  int i  = r / KT;
  int dt = r % KT;
  wT[((size_t)dt*Cin + i)*Cout + o] = w[idx];
}

// pack conv weights (Cout,Cin,KT) f32 -> MFMA A-frag order bf16:
// wp[((mt*Kt32 + ks)*64 + lane)*8 + j] = bf16( W[m=mt*16+(lane&15)][k=ks*32+(lane>>4)*8+j] )
// with k = dt*Cin + ci
__global__ void k_wpack(const float* __restrict__ w, unsigned short* __restrict__ wp,
                        int Cout, int Cin, int KT){
  int e = blockIdx.x*256 + threadIdx.x;
  int tot = Cout*Cin*KT;
  if (e >= tot) return;
  int Kt32 = (Cin*KT) >> 5;
  int j    = e & 7;
  int lane = (e >> 3) & 63;
  int rest = e >> 9;
  int ks   = rest % Kt32;
  int mt   = rest / Kt32;
  int m  = mt*16 + (lane & 15);
  int k  = ks*32 + (lane >> 4)*8 + j;
  int dt = k / Cin, ci = k - dt*Cin;
  wp[e] = f2b(w[((size_t)m*Cin + ci)*KT + dt]);
}

// f32 [b][C][L] -> bf16 P-layout [b][plane][hw][C]  (L = T*1296, planes contiguous at p0)
__global__ void k_convT(const float* __restrict__ x, unsigned short* __restrict__ Pb,
                        int C, int L, int PT, int p0){
  int n = blockIdx.x*256 + threadIdx.x;
  int b = blockIdx.z;
  const float* xb = x + (size_t)b*C*L + n;
  unsigned short* ob = Pb + ((size_t)(b*PT + p0)*1296 + (size_t)n)*C;
  for (int c0 = 0; c0 < C; c0 += 64){
    unsigned short buf[64];
    #pragma unroll
    for (int c = 0; c < 64; ++c) buf[c] = f2b(xb[(size_t)(c0 + c)*L]);
    uint4* dst = (uint4*)(ob + c0);
    #pragma unroll
    for (int w = 0; w < 8; ++w){
      uint4 v;
      v.x = (unsigned)buf[w*8+0] | ((unsigned)buf[w*8+1] << 16);
      v.y = (unsigned)buf[w*8+2] | ((unsigned)buf[w*8+3] << 16);
      v.z = (unsigned)buf[w*8+4] | ((unsigned)buf[w*8+5] << 16);
      v.w = (unsigned)buf[w*8+6] | ((unsigned)buf[w*8+7] << 16);
      dst[w] = v;
    }
  }
}

// ---------------- MFMA conv-as-GEMM ----------------
// D[m][n] = sum_k W[m][k] * X[k][n],  k = dt*Cin+ci, n within plane (48 per wave, 27*48=1296)
__launch_bounds__(256)
__global__ void k_mfconv(const unsigned short* __restrict__ P, const unsigned short* __restrict__ Wp,
                         float* __restrict__ out, int Cin, int Cout, int Mz,
                         int Tout, int stride, int KT, int pad, int p0, int plo, int phi, int PT)
{
  int bz = blockIdx.z; int b = bz / Mz; int mz = bz - b*Mz;
  int lane = threadIdx.x & 63;
  int tile = blockIdx.x*4 + (threadIdx.x >> 6);
  if (tile >= 27) return;
  int t = blockIdx.y;
  int col = lane & 15, grp = lane >> 4;
  int hw0 = tile*48 + col;
  int Kt32 = (KT*Cin) >> 5;
  f32x4 acc[4][3];
  #pragma unroll
  for (int i = 0; i < 4; ++i)
    #pragma unroll
    for (int j = 0; j < 3; ++j) acc[i][j] = (f32x4){0.f, 0.f, 0.f, 0.f};
  const unsigned short* wbase = Wp + ((size_t)(mz*4)*Kt32)*512 + lane*8;
  for (int dt = 0; dt < KT; ++dt){
    int p = t*stride + dt - pad + p0;
    if (p < plo || p >= phi) continue;
    const unsigned short* Pp = P + ((size_t)(b*PT + p)*1296 + hw0)*Cin + grp*8;
    int nCk = Cin >> 5;
    int ksg = (dt*Cin) >> 5;
    for (int kc = 0; kc < nCk; ++kc){
      bf16x8 bf0 = *(const bf16x8*)(Pp + (size_t)0*Cin  + kc*32);
      bf16x8 bf1 = *(const bf16x8*)(Pp + (size_t)16*Cin + kc*32);
      bf16x8 bf2 = *(const bf16x8*)(Pp + (size_t)32*Cin + kc*32);
      #pragma unroll
      for (int mf = 0; mf < 4; ++mf){
        bf16x8 af = *(const bf16x8*)(wbase + ((size_t)mf*Kt32 + ksg + kc)*512);
        acc[mf][0] = __builtin_amdgcn_mfma_f32_16x16x32_bf16(af, bf0, acc[mf][0], 0, 0, 0);
        acc[mf][1] = __builtin_amdgcn_mfma_f32_16x16x32_bf16(af, bf1, acc[mf][1], 0, 0, 0);
        acc[mf][2] = __builtin_amdgcn_mfma_f32_16x16x32_bf16(af, bf2, acc[mf][2], 0, 0, 0);
      }
    }
  }
  size_t cs = (size_t)Tout*1296;
  size_t obase = ((size_t)(b*Cout + mz*64 + grp*4))*cs + (size_t)t*1296;
  #pragma unroll
  for (int mf = 0; mf < 4; ++mf)
    #pragma unroll
    for (int f = 0; f < 3; ++f){
      int hw = tile*48 + f*16 + col;
      #pragma unroll
      for (int r = 0; r < 4; ++r)
        out[obase + (size_t)(mf*16 + r)*cs + hw] = acc[mf][f][r];
    }
}

// ---------------- naive temporal conv (kept only for ce pw 64->4) ----------------
__global__ void k_tconv(const float* __restrict__ xA, const float* __restrict__ xB,
                        int t_split, int Tpart,
                        const float* __restrict__ wT,
                        float* __restrict__ out,
                        int Cin, int Cout, int Tin, int Tout, int stride, int KT, int pad,
                        int out_cstride, int out_coff, int OC)
{
  int b  = blockIdx.z / OC;
  int oc = blockIdx.z % OC;
  int o  = oc*blockDim.x + threadIdx.x;
  int t  = blockIdx.y;
  int hw4 = blockIdx.x*blockDim.y + threadIdx.y;
  if (hw4 >= HW4) return;
  float4 acc = make_float4(0.f,0.f,0.f,0.f);
  for (int dt = 0; dt < KT; ++dt){
    int tt = t*stride + dt - pad;
    if (tt < 0 || tt >= Tin) continue;
    const float* xp = (tt < t_split) ? xA : xB;
    int tl = (tt < t_split) ? tt : (tt - t_split);
    const float4* xr = (const float4*)xp + ((size_t)b*Cin*Tpart + tl)*HW4 + hw4;
    const float* wp  = wT + (size_t)dt*Cin*Cout + o;
    size_t xstep = (size_t)Tpart*HW4;
    for (int i = 0; i < Cin; ++i){
      float4 xv = *xr;
      float  wv = *wp;
      acc.x = fmaf(wv, xv.x, acc.x);
      acc.y = fmaf(wv, xv.y, acc.y);
      acc.z = fmaf(wv, xv.z, acc.z);
      acc.w = fmaf(wv, xv.w, acc.w);
      xr += xstep; wp += Cout;
    }
  }
  float4* op = (float4*)out + ((size_t)(b*out_cstride + out_coff + o)*Tout + t)*HW4 + hw4;
  *op = acc;
}

// ---------------- BN ----------------

__global__ void k_bnstats(const float* __restrict__ x, int Bn, int Cn, int L,
                          long bstride, long cstride, float* __restrict__ sums)
{
  int c = blockIdx.y;
  int tid = threadIdx.x;
  float s = 0.f, sq = 0.f;
  int tot = Bn*L;
  for (int idx = blockIdx.x*blockDim.x + tid; idx < tot; idx += gridDim.x*blockDim.x){
    int b = idx / L; int l = idx - b*L;
    float v = x[(size_t)b*bstride + (size_t)c*cstride + l];
    s += v; sq += v*v;
  }
  __shared__ float r1[256], r2[256];
  r1[tid] = s; r2[tid] = sq; __syncthreads();
  for (int k = 128; k > 0; k >>= 1){
    if (tid < k){ r1[tid] += r1[tid+k]; r2[tid] += r2[tid+k]; }
    __syncthreads();
  }
  if (tid == 0){ atomicAdd(&sums[c], r1[0]); atomicAdd(&sums[Cn+c], r2[0]); }
}

__global__ void k_bnrelu(float* __restrict__ x, int Cn, int L, long bstride, long cstride,
                         const float* __restrict__ sums, const float* __restrict__ g,
                         const float* __restrict__ bet, float invc)
{
  int c = blockIdx.y, b = blockIdx.z;
  int l = blockIdx.x*blockDim.x + threadIdx.x;
  if (l >= L) return;
  float m  = sums[c]*invc;
  float v  = fmaxf(sums[Cn+c]*invc - m*m, 0.f);
  float sc = g[c]*rsqrtf(v + 1e-5f);
  float bb = bet[c] - m*sc;
  size_t idx = (size_t)b*bstride + (size_t)c*cstride + l;
  float val = fmaf(x[idx], sc, bb);
  x[idx] = fmaxf(val, 0.f);
}

// BN+ReLU on raw f32 [b][64][L], write bf16 transposed into P-cat layout [b][n][outC] at coff
__global__ void k_bnT(const float* __restrict__ x, const float* __restrict__ sums,
                      const float* __restrict__ g, const float* __restrict__ bet, float invc,
                      unsigned short* __restrict__ P1, unsigned short* __restrict__ P2,
                      int L, int outC, int coff)
{
  int n = blockIdx.x*256 + threadIdx.x;
  int b = blockIdx.z;
  const float* xb = x + (size_t)b*64*L + n;
  unsigned short buf[64];
  #pragma unroll
  for (int c = 0; c < 64; ++c){
    float m  = sums[c]*invc;
    float vv = fmaxf(sums[64+c]*invc - m*m, 0.f);
    float sc = g[c]*rsqrtf(vv + 1e-5f);
    float bb = bet[c] - m*sc;
    float val = fmaxf(fmaf(xb[(size_t)c*L], sc, bb), 0.f);
    buf[c] = f2b(val);
  }
  size_t ob = ((size_t)b*L + n)*outC + coff;
  #pragma unroll
  for (int w = 0; w < 8; ++w){
    uint4 v;
    v.x = (unsigned)buf[w*8+0] | ((unsigned)buf[w*8+1] << 16);
    v.y = (unsigned)buf[w*8+2] | ((unsigned)buf[w*8+3] << 16);
    v.z = (unsigned)buf[w*8+4] | ((unsigned)buf[w*8+5] << 16);
    v.w = (unsigned)buf[w*8+6] | ((unsigned)buf[w*8+7] << 16);
    ((uint4*)(P1 + ob))[w] = v;
    if (P2) ((uint4*)(P2 + ob))[w] = v;
  }
}

// ---------------- PAM encoder ----------------

__global__ void k_meanT(const float* __restrict__ x, float* __restrict__ xm){
  int c = blockIdx.y, b = blockIdx.z;
  int hw = blockIdx.x*blockDim.x + threadIdx.x;
  if (hw >= HW) return;
  const float* xp = x + ((size_t)(b*64+c)*Tt)*HW + hw;
  float s = 0.f;
  for (int t = 0; t < Tt; ++t) s += xp[(size_t)t*HW];
  xm[(size_t)(b*64+c)*HW + hw] = s*(1.f/16.f);
}

__global__ void k_pool(const float* __restrict__ xm, float* __restrict__ pp){
  int c = blockIdx.y, b = blockIdx.z;
  int cell = threadIdx.x;
  if (cell >= 50) return;
  int s, off;
  if (cell < 1){ s=1; off=0; } else if (cell < 5){ s=2; off=1; }
  else if (cell < 14){ s=3; off=5; } else { s=6; off=14; }
  int local = cell - off, ph = local/s, pw = local%s, bh = 36/s;
  const float* xp = xm + (size_t)(b*64+c)*HW;
  float sum = 0.f;
  for (int h = ph*bh; h < (ph+1)*bh; ++h)
    for (int w = pw*bh; w < (pw+1)*bh; ++w) sum += xp[h*36 + w];
  pp[(size_t)(b*64+c)*50 + cell] = sum / (float)(bh*bh);
}

__global__ void k_pemm(const float* __restrict__ pp, const float* __restrict__ pew,
                       float* __restrict__ pf){
  int cell = blockIdx.x, b = blockIdx.z;
  int o = threadIdx.x;  // 64
  int sc;
  if (cell < 1) sc=0; else if (cell < 5) sc=1; else if (cell < 14) sc=2; else sc=3;
  const float* w = pew + (size_t)sc*4096 + o*64;
  const float* p = pp + (size_t)b*3200 + cell;
  float s = 0.f;
  for (int i = 0; i < 64; ++i) s = fmaf(w[i], p[(size_t)i*50], s);
  pf[(size_t)(b*64+o)*50 + cell] = s;
}

__global__ void k_ytrans(const float* __restrict__ pf, float* __restrict__ y){
  int k = blockIdx.x, b = blockIdx.z; int c = threadIdx.x;
  y[((size_t)b*50 + k)*64 + c] = pf[((size_t)b*64 + c)*50 + k];
}

__global__ void k_pamkv(const float* __restrict__ y, const float* __restrict__ wk,
                        const float* __restrict__ bk, const float* __restrict__ wv,
                        const float* __restrict__ bv,
                        float* __restrict__ kb, float* __restrict__ vb){
  int kk = blockIdx.x, b = blockIdx.z; int t = threadIdx.x;
  const float* yp = y + ((size_t)b*50 + kk)*64;
  if (t < 16){
    float s = bk[t]; const float* w = wk + t*64;
    for (int i = 0; i < 64; ++i) s = fmaf(w[i], yp[i], s);
    kb[((size_t)b*50 + kk)*16 + t] = s;
  } else if (t < 80){
    int c = t - 16;
    float s = bv[c]; const float* w = wv + c*64;
    for (int i = 0; i < 64; ++i) s = fmaf(w[i], yp[i], s);
    vb[((size_t)b*50 + kk)*64 + c] = s;
  }
}

// q = Wq x + bq; attn = softmax(q k^T); out = bf16 P-layout of (x + scale * attn V)
__global__ void k_pamattn(const float* __restrict__ x, const float* __restrict__ kb,
                          const float* __restrict__ vb, const float* __restrict__ wq,
                          const float* __restrict__ bq, const float* __restrict__ scp,
                          unsigned short* __restrict__ Pg)
{
  __shared__ float kl[800];
  __shared__ float vl[3200];
  int b = blockIdx.z;
  int n = blockIdx.x*256 + threadIdx.x;  // Nn = 81*256 exact
  for (int i = threadIdx.x; i < 800;  i += 256) kl[i] = kb[(size_t)b*800 + i];
  for (int i = threadIdx.x; i < 3200; i += 256) vl[i] = vb[(size_t)b*3200 + i];
  __syncthreads();
  float q[16];
  #pragma unroll
  for (int o = 0; o < 16; ++o) q[o] = bq[o];
  const float* xb = x + (size_t)b*64*Nn + n;
  for (int i = 0; i < 64; ++i){
    float xv = xb[(size_t)i*Nn];
    #pragma unroll
    for (int o = 0; o < 16; ++o) q[o] = fmaf(wq[o*64+i], xv, q[o]);
  }
  float lg[50]; float mx = -1e30f;
  #pragma unroll
  for (int kk = 0; kk < 50; ++kk){
    float s = 0.f;
    #pragma unroll
    for (int o = 0; o < 16; ++o) s = fmaf(q[o], kl[kk*16+o], s);
    lg[kk] = s; mx = fmaxf(mx, s);
  }
  float sum = 0.f;
  #pragma unroll
  for (int kk = 0; kk < 50; ++kk){ float p = __expf(lg[kk]-mx); lg[kk] = p; sum += p; }
  float sc = scp[0]/sum;
  unsigned short buf[64];
  #pragma unroll
  for (int c0 = 0; c0 < 64; c0 += 8){
    float a[8];
    #pragma unroll
    for (int i = 0; i < 8; ++i) a[i] = 0.f;
    #pragma unroll
    for (int kk = 0; kk < 50; ++kk){
      float4 v0 = *(const float4*)&vl[kk*64 + c0];
      float4 v1 = *(const float4*)&vl[kk*64 + c0 + 4];
      float pk = lg[kk];
      a[0] = fmaf(pk, v0.x, a[0]); a[1] = fmaf(pk, v0.y, a[1]);
      a[2] = fmaf(pk, v0.z, a[2]); a[3] = fmaf(pk, v0.w, a[3]);
      a[4] = fmaf(pk, v1.x, a[4]); a[5] = fmaf(pk, v1.y, a[5]);
      a[6] = fmaf(pk, v1.z, a[6]); a[7] = fmaf(pk, v1.w, a[7]);
    }
    #pragma unroll
    for (int i = 0; i < 8; ++i)
      buf[c0+i] = f2b(fmaf(sc, a[i], xb[(size_t)(c0+i)*Nn]));
  }
  size_t ob = ((size_t)b*Nn + n)*64;
  #pragma unroll
  for (int w = 0; w < 8; ++w){
    uint4 v;
    v.x = (unsigned)buf[w*8+0] | ((unsigned)buf[w*8+1] << 16);
    v.y = (unsigned)buf[w*8+2] | ((unsigned)buf[w*8+3] << 16);
    v.z = (unsigned)buf[w*8+4] | ((unsigned)buf[w*8+5] << 16);
    v.w = (unsigned)buf[w*8+6] | ((unsigned)buf[w*8+7] << 16);
    ((uint4*)(Pg + ob))[w] = v;
  }
}

// ---------------- CAM ----------------

__global__ void k_camenergy(const float* __restrict__ x, const float* __restrict__ yc,
                            float* __restrict__ e){
  int c = blockIdx.y, b = blockIdx.z, tid = threadIdx.x;
  const float4* x4 = (const float4*)x + (size_t)(b*64+c)*5184;
  const float4* y4 = (const float4*)yc + (size_t)b*4*5184;
  float acc[4] = {0.f,0.f,0.f,0.f};
  for (int n4 = tid; n4 < 5184; n4 += 256){
    float4 xv = x4[n4];
    for (int kk = 0; kk < 4; ++kk){
      float4 yv = y4[kk*5184 + n4];
      acc[kk] += xv.x*yv.x + xv.y*yv.y + xv.z*yv.z + xv.w*yv.w;
    }
  }
  __shared__ float red[256];
  for (int kk = 0; kk < 4; ++kk){
    red[tid] = acc[kk]; __syncthreads();
    for (int s = 128; s > 0; s >>= 1){ if (tid < s) red[tid] += red[tid+s]; __syncthreads(); }
    if (tid == 0) e[(size_t)(b*64+c)*4 + kk] = red[0];
    __syncthreads();
  }
}

// out bf16 P-layout = x + scale * (attn @ y)
__global__ void k_camapplyT(const float* __restrict__ x, const float* __restrict__ yc,
                            const float* __restrict__ e, const float* __restrict__ scp,
                            unsigned short* __restrict__ Pg){
  __shared__ float pw[64][4];
  int tid = threadIdx.x;
  int b = blockIdx.z;
  if (tid < 64){
    const float* er = e + (size_t)(b*64+tid)*4;
    float e0=er[0], e1=er[1], e2=er[2], e3=er[3];
    float mx = fmaxf(fmaxf(e0,e1), fmaxf(e2,e3));
    float z0=mx-e0, z1=mx-e1, z2=mx-e2, z3=mx-e3;
    float zm = fmaxf(fmaxf(z0,z1), fmaxf(z2,z3));
    float p0=__expf(z0-zm), p1=__expf(z1-zm), p2=__expf(z2-zm), p3=__expf(z3-zm);
    float inv = 1.f/(p0+p1+p2+p3);
    pw[tid][0]=p0*inv; pw[tid][1]=p1*inv; pw[tid][2]=p2*inv; pw[tid][3]=p3*inv;
  }
  __syncthreads();
  int n = blockIdx.x*256 + tid;
  float y0 = yc[((size_t)b*4+0)*Nn + n];
  float y1 = yc[((size_t)b*4+1)*Nn + n];
  float y2 = yc[((size_t)b*4+2)*Nn + n];
  float y3 = yc[((size_t)b*4+3)*Nn + n];
  float sc = scp[0];
  const float* xb = x + (size_t)b*64*Nn + n;
  unsigned short buf[64];
  #pragma unroll
  for (int c = 0; c < 64; ++c){
    float val = fmaf(sc, pw[c][0]*y0 + pw[c][1]*y1 + pw[c][2]*y2 + pw[c][3]*y3,
                     xb[(size_t)c*Nn]);
    buf[c] = f2b(val);
  }
  size_t ob = ((size_t)b*Nn + n)*64;
  #pragma unroll
  for (int w = 0; w < 8; ++w){
    uint4 v;
    v.x = (unsigned)buf[w*8+0] | ((unsigned)buf[w*8+1] << 16);
    v.y = (unsigned)buf[w*8+2] | ((unsigned)buf[w*8+3] << 16);
    v.z = (unsigned)buf[w*8+4] | ((unsigned)buf[w*8+5] << 16);
    v.w = (unsigned)buf[w*8+6] | ((unsigned)buf[w*8+7] << 16);
    ((uint4*)(Pg + ob))[w] = v;
  }
}

// ---------------- TAM ----------------

__global__ void k_tamenergy(const float* __restrict__ xf, const float* __restrict__ yf,
                            float* __restrict__ e){
  __shared__ float xt[32*TTILE];
  __shared__ float yt[32*TTILE];
  int hw0 = blockIdx.x*TTILE, c = blockIdx.y, b = blockIdx.z, tid = threadIdx.x;
  const float* xb = xf + (size_t)(b*64+c)*T2*HW;
  const float* yb = yf + (size_t)(b*64+c)*T2*HW;
  for (int idx = tid; idx < 32*TTILE; idx += 256){
    int t = idx/TTILE, hl = idx - t*TTILE;
    xt[idx] = xb[(size_t)t*HW + hw0 + hl];
    yt[idx] = yb[(size_t)t*HW + hw0 + hl];
  }
  __syncthreads();
  int i  = tid >> 3;
  int j0 = (tid & 7)*4;
  float a0=0.f, a1=0.f, a2=0.f, a3=0.f;
  const float* xr = &xt[i*TTILE];
  const float* y0 = &yt[(j0+0)*TTILE];
  const float* y1 = &yt[(j0+1)*TTILE];
  const float* y2 = &yt[(j0+2)*TTILE];
  const float* y3 = &yt[(j0+3)*TTILE];
  for (int h = 0; h < TTILE; ++h){
    float xv = xr[h];
    a0 = fmaf(xv, y0[h], a0);
    a1 = fmaf(xv, y1[h], a1);
    a2 = fmaf(xv, y2[h], a2);
    a3 = fmaf(xv, y3[h], a3);
  }
  float* ep = e + ((size_t)(b*32+i)*32 + j0);
  atomicAdd(ep+0, a0); atomicAdd(ep+1, a1);
  atomicAdd(ep+2, a2); atomicAdd(ep+3, a3);
}

__global__ void k_tamsoftmax(const float* __restrict__ e, float* __restrict__ at){
  int tid = threadIdx.x; if (tid >= 128) return;
  int b = tid >> 5, i = tid & 31;
  const float* er = e + ((size_t)b*32 + i)*32;
  float mx = -1e30f;
  for (int j = 0; j < 32; ++j) mx = fmaxf(mx, er[j]);
  float mn = 1e30f;
  for (int j = 0; j < 32; ++j) mn = fminf(mn, er[j]);
  float zmax = mx - mn;
  float sum = 0.f;
  float* ar = at + ((size_t)b*32 + i)*32;
  for (int j = 0; j < 32; ++j){ float p = __expf((mx - er[j]) - zmax); ar[j] = p; sum += p; }
  float inv = 1.f/sum;
  for (int j = 0; j < 32; ++j) ar[j] *= inv;
}

__global__ void k_tamapply(const float* __restrict__ x, const float* __restrict__ y,
                           const float* __restrict__ at, const float* __restrict__ scp,
                           float* __restrict__ out){
  __shared__ float yt[32*TTILE];
  __shared__ float al[1024];
  int hw0 = blockIdx.x*TTILE, c = blockIdx.y, b = blockIdx.z, tid = threadIdx.x;
  const float* yb = y + (size_t)(b*64+c)*T2*HW;
  for (int idx = tid; idx < 32*TTILE; idx += 256){
    int t = idx/TTILE, hl = idx - t*TTILE;
    yt[idx] = yb[(size_t)t*HW + hw0 + hl];
  }
  for (int idx = tid; idx < 1024; idx += 256) al[idx] = at[(size_t)b*1024 + idx];
  __syncthreads();
  float sc = scp[0];
  const float* xb = x + (size_t)(b*64+c)*T2*HW;
  float* ob = out + (size_t)(b*64+c)*T2*HW;
  for (int idx = tid; idx < 32*TTILE; idx += 256){
    int t = idx/TTILE, hl = idx - t*TTILE;
    float acc = 0.f;
    const float* ar = &al[t*32];
    for (int j = 0; j < 32; ++j) acc = fmaf(ar[j], yt[j*TTILE + hl], acc);
    size_t g = (size_t)t*HW + hw0 + hl;
    ob[g] = fmaf(sc, acc, xb[g]);
  }
}

// ---------------- host ----------------

extern "C" void kernel_launch(void* const* d_in, const int* in_sizes, int n_in,
                              void* d_out, int out_size, void* d_ws, size_t ws_size,
                              hipStream_t stream) {
  const float* x1      = (const float*)d_in[0];
  const float* x2      = (const float*)d_in[1];
  const float* w_conv1 = (const float*)d_in[2];
  const float* g_conv1 = (const float*)d_in[3];
  const float* b_conv1 = (const float*)d_in[4];
  const float* w_conv2 = (const float*)d_in[5];
  const float* g_conv2 = (const float*)d_in[6];
  const float* b_conv2 = (const float*)d_in[7];
  const float* w_tam   = (const float*)d_in[8];
  const float* g_tam   = (const float*)d_in[9];
  const float* b_tam   = (const float*)d_in[10];
  const float* w_cat   = (const float*)d_in[11];
  const float* g_cat   = (const float*)d_in[12];
  const float* b_cat   = (const float*)d_in[13];
  const float* pe_w    = (const float*)d_in[14];
  const float* pe_g    = (const float*)d_in[15];
  const float* pe_b    = (const float*)d_in[16];
  const float* pd_wq   = (const float*)d_in[17];
  const float* pd_bq   = (const float*)d_in[18];
  const float* pd_wk   = (const float*)d_in[19];
  const float* pd_bk   = (const float*)d_in[20];
  const float* pd_wv   = (const float*)d_in[21];
  const float* pd_bv   = (const float*)d_in[22];
  const float* pd_scale= (const float*)d_in[23];
  const float* ce_w    = (const float*)d_in[24];
  const float* ce_g    = (const float*)d_in[25];
  const float* ce_b    = (const float*)d_in[26];
  const float* cd_scale= (const float*)d_in[27];
  const float* te_w    = (const float*)d_in[28];
  const float* te_g    = (const float*)d_in[29];
  const float* te_b    = (const float*)d_in[30];
  const float* td_scale= (const float*)d_in[31];

  float* ws = (float*)d_ws;
  size_t off = 0;
  auto alloc = [&](size_t n){ float* p = ws + off; off += (n + 3) & ~(size_t)3; return p; };
  float* stats = alloc(16384);   // 32 slots x 512
  float* e_tam = alloc(4096);    // contiguous with stats for the zeroing pass
  float* attn_t= alloc(4096);
  float* wTce  = alloc(256);
  unsigned short* Wp1  = (unsigned short*)alloc(24576);  // conv1: 4*24*512 bf16
  unsigned short* Wp2  = (unsigned short*)alloc(6144);   // conv2: 4*6*512
  unsigned short* Wpt  = (unsigned short*)alloc(6144);   // tam
  unsigned short* Wpc  = (unsigned short*)alloc(73728);  // cat: 16*18*512
  unsigned short* Wpte = (unsigned short*)alloc(2048);   // te: 4*2*512
  float* xm    = alloc(331776);
  float* pp    = alloc(12800);
  float* pf    = alloc(12800);
  float* yb    = alloc(12800);
  float* kb    = alloc(3200);
  float* vb    = alloc(12800);
  float* yc    = alloc(331776);
  float* e_cam = alloc(1024);
  float* A     = alloc(5308416);   // conv1(x1) -> f32 (PAM/CAM consume)
  float* Bb    = alloc(5308416);   // conv1(x2)
  float* PTEf  = alloc(5308416);   // PTE / PE bf16 (10.6M ushort)
  float* COMB  = alloc(31850496);  // overlaid region

  // COMB overlays (all offsets in floats):
  unsigned short* P0 = (unsigned short*)COMB;            // 42.5M bf16 [steps 1-5]
  float* Dd = COMB;                                      // [0 .. 10.6M)   [7-8]
  float* Ee = COMB + 10616832;                           // [10.6 .. 21.2M) [8-9]
  float* Cc = COMB + 21233664;                           // [21.2 .. 31.85M) [5-8]
  unsigned short* PCAT1 = (unsigned short*)COMB;                  // 15.9M us [10-12]
  unsigned short* PCAT2 = (unsigned short*)(COMB + 7962624);      // 15.9M us [10-12]
  float* Rraw = COMB + 15925248;                         // 5.3M f [10-11]
  unsigned short* PG = (unsigned short*)(COMB + 21233664);        // 5.3M us [11]
  unsigned short* PTE = (unsigned short*)PTEf;

  k_zero<<<dim3(80), 256, 0, stream>>>(stats, 20480);

  // weight prep
  k_wtrans<<<dim3(1), 256, 0, stream>>>(ce_w, wTce, 4, 64, 1);
  k_wpack<<<dim3(192), 256, 0, stream>>>(w_conv1, Wp1, 64, 256, 3);
  k_wpack<<<dim3(48),  256, 0, stream>>>(w_conv2, Wp2, 64, 64, 3);
  k_wpack<<<dim3(48),  256, 0, stream>>>(w_tam,  Wpt, 64, 64, 3);
  k_wpack<<<dim3(576), 256, 0, stream>>>(w_cat,  Wpc, 256, 192, 3);
  k_wpack<<<dim3(16),  256, 0, stream>>>(te_w,   Wpte, 64, 64, 1);

  // inputs -> P0 bf16 transposed (planes 0-15: x1, 16-31: x2)
  k_convT<<<dim3(81, 1, 4), 256, 0, stream>>>(x1, P0, 256, Nn, 32, 0);
  k_convT<<<dim3(81, 1, 4), 256, 0, stream>>>(x2, P0, 256, Nn, 32, 16);

  const float invc16 = 1.f/(4.f*20736.f);
  const float invc32 = 1.f/(4.f*41472.f);

  auto bnstats = [&](float* base, int C, int L, int slot){
    k_bnstats<<<dim3(16, C), 256, 0, stream>>>(base, 4, C, L, (long)C*L, (long)L,
                                               stats + (size_t)slot*512);
  };
  auto bnrelu = [&](float* base, int C, int L, int slot, const float* g, const float* bt,
                    float invc){
    k_bnrelu<<<dim3((L+255)/256, C, 4), 256, 0, stream>>>(base, C, L, (long)C*L, (long)L,
                                               stats + (size_t)slot*512, g, bt, invc);
  };

  // conv1 x1 -> A
  k_mfconv<<<dim3(7,16,4), 256, 0, stream>>>(P0, Wp1, A, 256, 64, 1, 16, 1, 3, 1, 0, 0, 16, 32);
  bnstats(A, 64, Nn, 0); bnrelu(A, 64, Nn, 0, g_conv1, b_conv1, invc16);
  // conv1 x2 -> Bb
  k_mfconv<<<dim3(7,16,4), 256, 0, stream>>>(P0, Wp1, Bb, 256, 64, 1, 16, 1, 3, 1, 16, 16, 32, 32);
  bnstats(Bb, 64, Nn, 1); bnrelu(Bb, 64, Nn, 1, g_conv1, b_conv1, invc16);
  // conv1 concat -> Cc
  k_mfconv<<<dim3(7,32,4), 256, 0, stream>>>(P0, Wp1, Cc, 256, 64, 1, 32, 1, 3, 1, 0, 0, 32, 32);
  bnstats(Cc, 64, N2, 2); bnrelu(Cc, 64, N2, 2, g_conv1, b_conv1, invc32);

  // xt2 = pw_bn_relu(xt1, te_w): Cc -> PTE -> te GEMM -> Dd
  k_convT<<<dim3(162, 1, 4), 256, 0, stream>>>(Cc, PTE, 64, N2, 32, 0);
  k_mfconv<<<dim3(7,32,4), 256, 0, stream>>>(PTE, Wpte, Dd, 64, 64, 1, 32, 1, 1, 0, 0, 0, 32, 32);
  bnstats(Dd, 64, N2, 3); bnrelu(Dd, 64, N2, 3, te_g, te_b, invc32);

  // TAM
  k_tamenergy<<<dim3(8, 64, 4), 256, 0, stream>>>(Cc, Dd, e_tam);
  k_tamsoftmax<<<dim3(1), 128, 0, stream>>>(e_tam, attn_t);
  k_tamapply<<<dim3(8, 64, 4), 256, 0, stream>>>(Cc, Dd, attn_t, td_scale, Ee);
  // Ee -> PE (reuse PTE buffer)
  k_convT<<<dim3(162, 1, 4), 256, 0, stream>>>(Ee, PTE, 64, N2, 32, 0);
  // tam conv (stride 2) -> Rraw; BN -> PCAT1/PCAT2 channels 128-191
  k_mfconv<<<dim3(7,16,4), 256, 0, stream>>>(PTE, Wpt, Rraw, 64, 64, 1, 16, 2, 3, 1, 0, 0, 32, 32);
  bnstats(Rraw, 64, Nn, 4);
  k_bnT<<<dim3(81,1,4), 256, 0, stream>>>(Rraw, stats + 4*512, g_tam, b_tam, invc16,
                                          PCAT1, PCAT2, Nn, 192, 128);

  // PAM encoder chain
  auto pam_enc = [&](const float* xin, int slotbase){
    k_meanT<<<dim3(6, 64, 4), 256, 0, stream>>>(xin, xm);
    k_pool<<<dim3(1, 64, 4), 64, 0, stream>>>(xm, pp);
    k_pemm<<<dim3(50, 1, 4), 64, 0, stream>>>(pp, pe_w, pf);
    const int ss[4] = {1,2,3,6}; const int so[4] = {0,1,5,14};
    for (int i = 0; i < 4; ++i){
      int s2 = ss[i]*ss[i];
      float* sums = stats + (size_t)(slotbase+i)*512;
      k_bnstats<<<dim3(1, 64), 256, 0, stream>>>(pf + so[i], 4, 64, s2, 3200L, 50L, sums);
      k_bnrelu<<<dim3(1, 64, 4), 256, 0, stream>>>(pf + so[i], 64, s2, 3200L, 50L,
                                                   sums, pe_g + i*64, pe_b + i*64,
                                                   1.f/(4.f*(float)s2));
    }
    k_ytrans<<<dim3(50, 1, 4), 64, 0, stream>>>(pf, yb);
    k_pamkv<<<dim3(50, 1, 4), 128, 0, stream>>>(yb, pd_wk, pd_bk, pd_wv, pd_bv, kb, vb);
  };

  // PAM x1 -> PG -> conv2 -> PCAT1[0:64]
  pam_enc(A, 5);
  k_pamattn<<<dim3(81, 1, 4), 256, 0, stream>>>(A, kb, vb, pd_wq, pd_bq, pd_scale, PG);
  k_mfconv<<<dim3(7,16,4), 256, 0, stream>>>(PG, Wp2, Rraw, 64, 64, 1, 16, 1, 3, 1, 0, 0, 16, 16);
  bnstats(Rraw, 64, Nn, 13);
  k_bnT<<<dim3(81,1,4), 256, 0, stream>>>(Rraw, stats + 13*512, g_conv2, b_conv2, invc16,
                                          PCAT1, nullptr, Nn, 192, 0);
  // PAM x2 -> PCAT2[0:64]
  pam_enc(Bb, 9);
  k_pamattn<<<dim3(81, 1, 4), 256, 0, stream>>>(Bb, kb, vb, pd_wq, pd_bq, pd_scale, PG);
  k_mfconv<<<dim3(7,16,4), 256, 0, stream>>>(PG, Wp2, Rraw, 64, 64, 1, 16, 1, 3, 1, 0, 0, 16, 16);
  bnstats(Rraw, 64, Nn, 14);
  k_bnT<<<dim3(81,1,4), 256, 0, stream>>>(Rraw, stats + 14*512, g_conv2, b_conv2, invc16,
                                          PCAT2, nullptr, Nn, 192, 0);

  // CAM
  auto cam = [&](const float* xin, unsigned short* catp, int slot_ce, int slot_c2){
    k_tconv<<<dim3(6, 16, 4), dim3(4, 64), 0, stream>>>(xin, nullptr, 16, 16, wTce, yc,
                                                        64, 4, 16, 16, 1, 1, 0, 4, 0, 1);
    k_bnstats<<<dim3(16, 4), 256, 0, stream>>>(yc, 4, 4, Nn, 4L*Nn, (long)Nn,
                                               stats + (size_t)slot_ce*512);
    k_bnrelu<<<dim3((Nn+255)/256, 4, 4), 256, 0, stream>>>(yc, 4, Nn, 4L*Nn, (long)Nn,
                                               stats + (size_t)slot_ce*512, ce_g, ce_b, invc16);
    k_camenergy<<<dim3(1, 64, 4), 256, 0, stream>>>(xin, yc, e_cam);
    k_camapplyT<<<dim3(81, 1, 4), 256, 0, stream>>>(xin, yc, e_cam, cd_scale, PG);
    k_mfconv<<<dim3(7,16,4), 256, 0, stream>>>(PG, Wp2, Rraw, 64, 64, 1, 16, 1, 3, 1, 0, 0, 16, 16);
    bnstats(Rraw, 64, Nn, slot_c2);
    k_bnT<<<dim3(81,1,4), 256, 0, stream>>>(Rraw, stats + (size_t)slot_c2*512,
                                            g_conv2, b_conv2, invc16,
                                            catp, nullptr, Nn, 192, 64);
  };
  cam(A,  PCAT2, 15, 17);  // x1_ca -> PCAT2[64:128]
  cam(Bb, PCAT1, 16, 18);  // x2_ca -> PCAT1[64:128]

  // final cat convs -> d_out
  float* out1 = (float*)d_out;
  float* out2 = out1 + (size_t)4*256*Nn;
  k_mfconv<<<dim3(7,16,16), 256, 0, stream>>>(PCAT1, Wpc, out1, 192, 256, 4, 16, 1, 3, 1, 0, 0, 16, 16);
  bnstats(out1, 256, Nn, 19); bnrelu(out1, 256, Nn, 19, g_cat, b_cat, invc16);
  k_mfconv<<<dim3(7,16,16), 256, 0, stream>>>(PCAT2, Wpc, out2, 192, 256, 4, 16, 1, 3, 1, 0, 0, 16, 16);
  bnstats(out2, 256, Nn, 20); bnrelu(out2, 256, Nn, 20, g_cat, b_cat, invc16);
}

// Round 3
// 1789.214 us; speedup vs baseline: 4.6871x; 1.0464x over previous
//
#include <hip/hip_runtime.h>

#define HW 1296
#define HW4 324
#define Tt 16
#define T2 32
#define Nn 20736
#define N2 41472

typedef short bf16x8 __attribute__((ext_vector_type(8)));
typedef float f32x4 __attribute__((ext_vector_type(4)));

__device__ inline unsigned short f2b(float f){
  union { float f; unsigned u; } v; v.f = f;
  unsigned r = v.u + 0x7FFF + ((v.u >> 16) & 1);
  return (unsigned short)(r >> 16);
}
__device__ inline float b2f_lo(unsigned u){
  union { unsigned u; float f; } v; v.u = u << 16; return v.f;
}
__device__ inline float b2f_hi(unsigned u){
  union { unsigned u; float f; } v; v.u = u & 0xffff0000u; return v.f;
}

// ---------------- utility kernels ----------------

__global__ void k_zero(float* p, int n){
  int i = blockIdx.x*blockDim.x + threadIdx.x;
  if (i < n) p[i] = 0.f;
}

// w layout (Cout,Cin,KT) -> wT layout (KT,Cin,Cout)  (kept for ce pw conv only)
__global__ void k_wtrans(const float* __restrict__ w, float* __restrict__ wT,
                         int Cout, int Cin, int KT){
  int idx = blockIdx.x*blockDim.x + threadIdx.x;
  int tot = Cout*Cin*KT;
  if (idx >= tot) return;
  int o  = idx / (Cin*KT);
  int r  = idx % (Cin*KT);
  int i  = r / KT;
  int dt = r % KT;
  wT[((size_t)dt*Cin + i)*Cout + o] = w[idx];
}

// pack conv weights (Cout,Cin,KT) f32 -> MFMA A-frag order bf16
__global__ void k_wpack(const float* __restrict__ w, unsigned short* __restrict__ wp,
                        int Cout, int Cin, int KT){
  int e = blockIdx.x*256 + threadIdx.x;
  int tot = Cout*Cin*KT;
  if (e >= tot) return;
  int Kt32 = (Cin*KT) >> 5;
  int j    = e & 7;
  int lane = (e >> 3) & 63;
  int rest = e >> 9;
  int ks   = rest % Kt32;
  int mt   = rest / Kt32;
  int m  = mt*16 + (lane & 15);
  int k  = ks*32 + (lane >> 4)*8 + j;
  int dt = k / Cin, ci = k - dt*Cin;
  wp[e] = f2b(w[((size_t)m*Cin + ci)*KT + dt]);
}

// f32 [b][C][L] -> bf16 P-layout [b][plane][hw][C]
__global__ void k_convT(const float* __restrict__ x, unsigned short* __restrict__ Pb,
                        int C, int L, int PT, int p0){
  int n = blockIdx.x*256 + threadIdx.x;
  int b = blockIdx.z;
  const float* xb = x + (size_t)b*C*L + n;
  unsigned short* ob = Pb + ((size_t)(b*PT + p0)*1296 + (size_t)n)*C;
  for (int c0 = 0; c0 < C; c0 += 64){
    unsigned short buf[64];
    #pragma unroll
    for (int c = 0; c < 64; ++c) buf[c] = f2b(xb[(size_t)(c0 + c)*L]);
    uint4* dst = (uint4*)(ob + c0);
    #pragma unroll
    for (int w = 0; w < 8; ++w){
      uint4 v;
      v.x = (unsigned)buf[w*8+0] | ((unsigned)buf[w*8+1] << 16);
      v.y = (unsigned)buf[w*8+2] | ((unsigned)buf[w*8+3] << 16);
      v.z = (unsigned)buf[w*8+4] | ((unsigned)buf[w*8+5] << 16);
      v.w = (unsigned)buf[w*8+6] | ((unsigned)buf[w*8+7] << 16);
      dst[w] = v;
    }
  }
}

// ---------------- MFMA conv-as-GEMM ----------------
__launch_bounds__(256)
__global__ void k_mfconv(const unsigned short* __restrict__ P, const unsigned short* __restrict__ Wp,
                         float* __restrict__ out, int Cin, int Cout, int Mz,
                         int Tout, int stride, int KT, int pad, int p0, int plo, int phi, int PT)
{
  int bz = blockIdx.z; int b = bz / Mz; int mz = bz - b*Mz;
  int lane = threadIdx.x & 63;
  int tile = blockIdx.x*4 + (threadIdx.x >> 6);
  if (tile >= 27) return;
  int t = blockIdx.y;
  int col = lane & 15, grp = lane >> 4;
  int hw0 = tile*48 + col;
  int Kt32 = (KT*Cin) >> 5;
  f32x4 acc[4][3];
  #pragma unroll
  for (int i = 0; i < 4; ++i)
    #pragma unroll
    for (int j = 0; j < 3; ++j) acc[i][j] = (f32x4){0.f, 0.f, 0.f, 0.f};
  const unsigned short* wbase = Wp + ((size_t)(mz*4)*Kt32)*512 + lane*8;
  for (int dt = 0; dt < KT; ++dt){
    int p = t*stride + dt - pad + p0;
    if (p < plo || p >= phi) continue;
    const unsigned short* Pp = P + ((size_t)(b*PT + p)*1296 + hw0)*Cin + grp*8;
    int nCk = Cin >> 5;
    int ksg = (dt*Cin) >> 5;
    for (int kc = 0; kc < nCk; ++kc){
      bf16x8 bf0 = *(const bf16x8*)(Pp + (size_t)0*Cin  + kc*32);
      bf16x8 bf1 = *(const bf16x8*)(Pp + (size_t)16*Cin + kc*32);
      bf16x8 bf2 = *(const bf16x8*)(Pp + (size_t)32*Cin + kc*32);
      #pragma unroll
      for (int mf = 0; mf < 4; ++mf){
        bf16x8 af = *(const bf16x8*)(wbase + ((size_t)mf*Kt32 + ksg + kc)*512);
        acc[mf][0] = __builtin_amdgcn_mfma_f32_16x16x32_bf16(af, bf0, acc[mf][0], 0, 0, 0);
        acc[mf][1] = __builtin_amdgcn_mfma_f32_16x16x32_bf16(af, bf1, acc[mf][1], 0, 0, 0);
        acc[mf][2] = __builtin_amdgcn_mfma_f32_16x16x32_bf16(af, bf2, acc[mf][2], 0, 0, 0);
      }
    }
  }
  size_t cs = (size_t)Tout*1296;
  size_t obase = ((size_t)(b*Cout + mz*64 + grp*4))*cs + (size_t)t*1296;
  #pragma unroll
  for (int mf = 0; mf < 4; ++mf)
    #pragma unroll
    for (int f = 0; f < 3; ++f){
      int hw = tile*48 + f*16 + col;
      #pragma unroll
      for (int r = 0; r < 4; ++r)
        out[obase + (size_t)(mf*16 + r)*cs + hw] = acc[mf][f][r];
    }
}

// ---------------- naive temporal conv (kept only for ce pw 64->4) ----------------
__global__ void k_tconv(const float* __restrict__ xA, const float* __restrict__ xB,
                        int t_split, int Tpart,
                        const float* __restrict__ wT,
                        float* __restrict__ out,
                        int Cin, int Cout, int Tin, int Tout, int stride, int KT, int pad,
                        int out_cstride, int out_coff, int OC)
{
  int b  = blockIdx.z / OC;
  int oc = blockIdx.z % OC;
  int o  = oc*blockDim.x + threadIdx.x;
  int t  = blockIdx.y;
  int hw4 = blockIdx.x*blockDim.y + threadIdx.y;
  if (hw4 >= HW4) return;
  float4 acc = make_float4(0.f,0.f,0.f,0.f);
  for (int dt = 0; dt < KT; ++dt){
    int tt = t*stride + dt - pad;
    if (tt < 0 || tt >= Tin) continue;
    const float* xp = (tt < t_split) ? xA : xB;
    int tl = (tt < t_split) ? tt : (tt - t_split);
    const float4* xr = (const float4*)xp + ((size_t)b*Cin*Tpart + tl)*HW4 + hw4;
    const float* wp  = wT + (size_t)dt*Cin*Cout + o;
    size_t xstep = (size_t)Tpart*HW4;
    for (int i = 0; i < Cin; ++i){
      float4 xv = *xr;
      float  wv = *wp;
      acc.x = fmaf(wv, xv.x, acc.x);
      acc.y = fmaf(wv, xv.y, acc.y);
      acc.z = fmaf(wv, xv.z, acc.z);
      acc.w = fmaf(wv, xv.w, acc.w);
      xr += xstep; wp += Cout;
    }
  }
  float4* op = (float4*)out + ((size_t)(b*out_cstride + out_coff + o)*Tout + t)*HW4 + hw4;
  *op = acc;
}

// ---------------- BN ----------------

__global__ void k_bnstats(const float* __restrict__ x, int Bn, int Cn, int L,
                          long bstride, long cstride, float* __restrict__ sums)
{
  int c = blockIdx.y;
  int tid = threadIdx.x;
  float s = 0.f, sq = 0.f;
  int tot = Bn*L;
  for (int idx = blockIdx.x*blockDim.x + tid; idx < tot; idx += gridDim.x*blockDim.x){
    int b = idx / L; int l = idx - b*L;
    float v = x[(size_t)b*bstride + (size_t)c*cstride + l];
    s += v; sq += v*v;
  }
  __shared__ float r1[256], r2[256];
  r1[tid] = s; r2[tid] = sq; __syncthreads();
  for (int k = 128; k > 0; k >>= 1){
    if (tid < k){ r1[tid] += r1[tid+k]; r2[tid] += r2[tid+k]; }
    __syncthreads();
  }
  if (tid == 0){ atomicAdd(&sums[c], r1[0]); atomicAdd(&sums[Cn+c], r2[0]); }
}

__global__ void k_bnrelu(float* __restrict__ x, int Cn, int L, long bstride, long cstride,
                         const float* __restrict__ sums, const float* __restrict__ g,
                         const float* __restrict__ bet, float invc)
{
  int c = blockIdx.y, b = blockIdx.z;
  int l = blockIdx.x*blockDim.x + threadIdx.x;
  if (l >= L) return;
  float m  = sums[c]*invc;
  float v  = fmaxf(sums[Cn+c]*invc - m*m, 0.f);
  float sc = g[c]*rsqrtf(v + 1e-5f);
  float bb = bet[c] - m*sc;
  size_t idx = (size_t)b*bstride + (size_t)c*cstride + l;
  float val = fmaf(x[idx], sc, bb);
  x[idx] = fmaxf(val, 0.f);
}

// BN+ReLU on raw f32 [b][64][L], write bf16 transposed into P layout [b][n][outC] at coff
__global__ void k_bnT(const float* __restrict__ x, const float* __restrict__ sums,
                      const float* __restrict__ g, const float* __restrict__ bet, float invc,
                      unsigned short* __restrict__ P1, unsigned short* __restrict__ P2,
                      int L, int outC, int coff)
{
  int n = blockIdx.x*256 + threadIdx.x;
  int b = blockIdx.z;
  const float* xb = x + (size_t)b*64*L + n;
  unsigned short buf[64];
  #pragma unroll
  for (int c = 0; c < 64; ++c){
    float m  = sums[c]*invc;
    float vv = fmaxf(sums[64+c]*invc - m*m, 0.f);
    float sc = g[c]*rsqrtf(vv + 1e-5f);
    float bb = bet[c] - m*sc;
    float val = fmaxf(fmaf(xb[(size_t)c*L], sc, bb), 0.f);
    buf[c] = f2b(val);
  }
  size_t ob = ((size_t)b*L + n)*outC + coff;
  #pragma unroll
  for (int w = 0; w < 8; ++w){
    uint4 v;
    v.x = (unsigned)buf[w*8+0] | ((unsigned)buf[w*8+1] << 16);
    v.y = (unsigned)buf[w*8+2] | ((unsigned)buf[w*8+3] << 16);
    v.z = (unsigned)buf[w*8+4] | ((unsigned)buf[w*8+5] << 16);
    v.w = (unsigned)buf[w*8+6] | ((unsigned)buf[w*8+7] << 16);
    ((uint4*)(P1 + ob))[w] = v;
    if (P2) ((uint4*)(P2 + ob))[w] = v;
  }
}

// ---------------- PAM encoder ----------------

__global__ void k_meanT(const float* __restrict__ x, float* __restrict__ xm){
  int c = blockIdx.y, b = blockIdx.z;
  int hw = blockIdx.x*blockDim.x + threadIdx.x;
  if (hw >= HW) return;
  const float* xp = x + ((size_t)(b*64+c)*Tt)*HW + hw;
  float s = 0.f;
  for (int t = 0; t < Tt; ++t) s += xp[(size_t)t*HW];
  xm[(size_t)(b*64+c)*HW + hw] = s*(1.f/16.f);
}

__global__ void k_pool(const float* __restrict__ xm, float* __restrict__ pp){
  int c = blockIdx.y, b = blockIdx.z;
  int cell = threadIdx.x;
  if (cell >= 50) return;
  int s, off;
  if (cell < 1){ s=1; off=0; } else if (cell < 5){ s=2; off=1; }
  else if (cell < 14){ s=3; off=5; } else { s=6; off=14; }
  int local = cell - off, ph = local/s, pw = local%s, bh = 36/s;
  const float* xp = xm + (size_t)(b*64+c)*HW;
  float sum = 0.f;
  for (int h = ph*bh; h < (ph+1)*bh; ++h)
    for (int w = pw*bh; w < (pw+1)*bh; ++w) sum += xp[h*36 + w];
  pp[(size_t)(b*64+c)*50 + cell] = sum / (float)(bh*bh);
}

__global__ void k_pemm(const float* __restrict__ pp, const float* __restrict__ pew,
                       float* __restrict__ pf){
  int cell = blockIdx.x, b = blockIdx.z;
  int o = threadIdx.x;  // 64
  int sc;
  if (cell < 1) sc=0; else if (cell < 5) sc=1; else if (cell < 14) sc=2; else sc=3;
  const float* w = pew + (size_t)sc*4096 + o*64;
  const float* p = pp + (size_t)b*3200 + cell;
  float s = 0.f;
  for (int i = 0; i < 64; ++i) s = fmaf(w[i], p[(size_t)i*50], s);
  pf[(size_t)(b*64+o)*50 + cell] = s;
}

__global__ void k_ytrans(const float* __restrict__ pf, float* __restrict__ y){
  int k = blockIdx.x, b = blockIdx.z; int c = threadIdx.x;
  y[((size_t)b*50 + k)*64 + c] = pf[((size_t)b*64 + c)*50 + k];
}

__global__ void k_pamkv(const float* __restrict__ y, const float* __restrict__ wk,
                        const float* __restrict__ bk, const float* __restrict__ wv,
                        const float* __restrict__ bv,
                        float* __restrict__ kb, float* __restrict__ vb){
  int kk = blockIdx.x, b = blockIdx.z; int t = threadIdx.x;
  const float* yp = y + ((size_t)b*50 + kk)*64;
  if (t < 16){
    float s = bk[t]; const float* w = wk + t*64;
    for (int i = 0; i < 64; ++i) s = fmaf(w[i], yp[i], s);
    kb[((size_t)b*50 + kk)*16 + t] = s;
  } else if (t < 80){
    int c = t - 16;
    float s = bv[c]; const float* w = wv + c*64;
    for (int i = 0; i < 64; ++i) s = fmaf(w[i], yp[i], s);
    vb[((size_t)b*50 + kk)*64 + c] = s;
  }
}

__global__ void k_pamattn(const float* __restrict__ x, const float* __restrict__ kb,
                          const float* __restrict__ vb, const float* __restrict__ wq,
                          const float* __restrict__ bq, const float* __restrict__ scp,
                          unsigned short* __restrict__ Pg)
{
  __shared__ float kl[800];
  __shared__ float vl[3200];
  int b = blockIdx.z;
  int n = blockIdx.x*256 + threadIdx.x;
  for (int i = threadIdx.x; i < 800;  i += 256) kl[i] = kb[(size_t)b*800 + i];
  for (int i = threadIdx.x; i < 3200; i += 256) vl[i] = vb[(size_t)b*3200 + i];
  __syncthreads();
  float q[16];
  #pragma unroll
  for (int o = 0; o < 16; ++o) q[o] = bq[o];
  const float* xb = x + (size_t)b*64*Nn + n;
  for (int i = 0; i < 64; ++i){
    float xv = xb[(size_t)i*Nn];
    #pragma unroll
    for (int o = 0; o < 16; ++o) q[o] = fmaf(wq[o*64+i], xv, q[o]);
  }
  float lg[50]; float mx = -1e30f;
  #pragma unroll
  for (int kk = 0; kk < 50; ++kk){
    float s = 0.f;
    #pragma unroll
    for (int o = 0; o < 16; ++o) s = fmaf(q[o], kl[kk*16+o], s);
    lg[kk] = s; mx = fmaxf(mx, s);
  }
  float sum = 0.f;
  #pragma unroll
  for (int kk = 0; kk < 50; ++kk){ float p = __expf(lg[kk]-mx); lg[kk] = p; sum += p; }
  float sc = scp[0]/sum;
  unsigned short buf[64];
  #pragma unroll
  for (int c0 = 0; c0 < 64; c0 += 8){
    float a[8];
    #pragma unroll
    for (int i = 0; i < 8; ++i) a[i] = 0.f;
    #pragma unroll
    for (int kk = 0; kk < 50; ++kk){
      float4 v0 = *(const float4*)&vl[kk*64 + c0];
      float4 v1 = *(const float4*)&vl[kk*64 + c0 + 4];
      float pk = lg[kk];
      a[0] = fmaf(pk, v0.x, a[0]); a[1] = fmaf(pk, v0.y, a[1]);
      a[2] = fmaf(pk, v0.z, a[2]); a[3] = fmaf(pk, v0.w, a[3]);
      a[4] = fmaf(pk, v1.x, a[4]); a[5] = fmaf(pk, v1.y, a[5]);
      a[6] = fmaf(pk, v1.z, a[6]); a[7] = fmaf(pk, v1.w, a[7]);
    }
    #pragma unroll
    for (int i = 0; i < 8; ++i)
      buf[c0+i] = f2b(fmaf(sc, a[i], xb[(size_t)(c0+i)*Nn]));
  }
  size_t ob = ((size_t)b*Nn + n)*64;
  #pragma unroll
  for (int w = 0; w < 8; ++w){
    uint4 v;
    v.x = (unsigned)buf[w*8+0] | ((unsigned)buf[w*8+1] << 16);
    v.y = (unsigned)buf[w*8+2] | ((unsigned)buf[w*8+3] << 16);
    v.z = (unsigned)buf[w*8+4] | ((unsigned)buf[w*8+5] << 16);
    v.w = (unsigned)buf[w*8+6] | ((unsigned)buf[w*8+7] << 16);
    ((uint4*)(Pg + ob))[w] = v;
  }
}

// ---------------- CAM ----------------

__global__ void k_camenergy(const float* __restrict__ x, const float* __restrict__ yc,
                            float* __restrict__ e){
  int c = blockIdx.y, b = blockIdx.z, tid = threadIdx.x;
  const float4* x4 = (const float4*)x + (size_t)(b*64+c)*5184;
  const float4* y4 = (const float4*)yc + (size_t)b*4*5184;
  float acc[4] = {0.f,0.f,0.f,0.f};
  for (int n4 = tid; n4 < 5184; n4 += 256){
    float4 xv = x4[n4];
    for (int kk = 0; kk < 4; ++kk){
      float4 yv = y4[kk*5184 + n4];
      acc[kk] += xv.x*yv.x + xv.y*yv.y + xv.z*yv.z + xv.w*yv.w;
    }
  }
  __shared__ float red[256];
  for (int kk = 0; kk < 4; ++kk){
    red[tid] = acc[kk]; __syncthreads();
    for (int s = 128; s > 0; s >>= 1){ if (tid < s) red[tid] += red[tid+s]; __syncthreads(); }
    if (tid == 0) e[(size_t)(b*64+c)*4 + kk] = red[0];
    __syncthreads();
  }
}

__global__ void k_camapplyT(const float* __restrict__ x, const float* __restrict__ yc,
                            const float* __restrict__ e, const float* __restrict__ scp,
                            unsigned short* __restrict__ Pg){
  __shared__ float pw[64][4];
  int tid = threadIdx.x;
  int b = blockIdx.z;
  if (tid < 64){
    const float* er = e + (size_t)(b*64+tid)*4;
    float e0=er[0], e1=er[1], e2=er[2], e3=er[3];
    float mx = fmaxf(fmaxf(e0,e1), fmaxf(e2,e3));
    float z0=mx-e0, z1=mx-e1, z2=mx-e2, z3=mx-e3;
    float zm = fmaxf(fmaxf(z0,z1), fmaxf(z2,z3));
    float p0=__expf(z0-zm), p1=__expf(z1-zm), p2=__expf(z2-zm), p3=__expf(z3-zm);
    float inv = 1.f/(p0+p1+p2+p3);
    pw[tid][0]=p0*inv; pw[tid][1]=p1*inv; pw[tid][2]=p2*inv; pw[tid][3]=p3*inv;
  }
  __syncthreads();
  int n = blockIdx.x*256 + tid;
  float y0 = yc[((size_t)b*4+0)*Nn + n];
  float y1 = yc[((size_t)b*4+1)*Nn + n];
  float y2 = yc[((size_t)b*4+2)*Nn + n];
  float y3 = yc[((size_t)b*4+3)*Nn + n];
  float sc = scp[0];
  const float* xb = x + (size_t)b*64*Nn + n;
  unsigned short buf[64];
  #pragma unroll
  for (int c = 0; c < 64; ++c){
    float val = fmaf(sc, pw[c][0]*y0 + pw[c][1]*y1 + pw[c][2]*y2 + pw[c][3]*y3,
                     xb[(size_t)c*Nn]);
    buf[c] = f2b(val);
  }
  size_t ob = ((size_t)b*Nn + n)*64;
  #pragma unroll
  for (int w = 0; w < 8; ++w){
    uint4 v;
    v.x = (unsigned)buf[w*8+0] | ((unsigned)buf[w*8+1] << 16);
    v.y = (unsigned)buf[w*8+2] | ((unsigned)buf[w*8+3] << 16);
    v.z = (unsigned)buf[w*8+4] | ((unsigned)buf[w*8+5] << 16);
    v.w = (unsigned)buf[w*8+6] | ((unsigned)buf[w*8+7] << 16);
    ((uint4*)(Pg + ob))[w] = v;
  }
}

// ---------------- TAM (MFMA energy + fused apply) ----------------

// E[b][i][j] += X[i][:] . Y[j][:]  ; X,Y bf16 row-major [b][32][82944]
__launch_bounds__(256)
__global__ void k_tamenergy_mf(const unsigned short* __restrict__ X,
                               const unsigned short* __restrict__ Y,
                               float* __restrict__ E){
  int b = blockIdx.z;
  int wave = threadIdx.x >> 6, lane = threadIdx.x & 63;
  int r = lane & 15, g = lane >> 4;
  const unsigned short* Xb = X + (size_t)b*32*82944;
  const unsigned short* Yb = Y + (size_t)b*32*82944;
  f32x4 a00 = (f32x4){0.f,0.f,0.f,0.f};
  f32x4 a01 = a00, a10 = a00, a11 = a00;
  int c0 = (blockIdx.x*4 + wave)*8;     // 81 blocks * 4 waves * 8 chunks = 2592
  for (int cc = 0; cc < 8; ++cc){
    size_t k0 = (size_t)(c0 + cc)*32 + (size_t)g*8;
    bf16x8 x0 = *(const bf16x8*)(Xb + (size_t)r*82944 + k0);
    bf16x8 x1 = *(const bf16x8*)(Xb + (size_t)(r+16)*82944 + k0);
    bf16x8 y0 = *(const bf16x8*)(Yb + (size_t)r*82944 + k0);
    bf16x8 y1 = *(const bf16x8*)(Yb + (size_t)(r+16)*82944 + k0);
    a00 = __builtin_amdgcn_mfma_f32_16x16x32_bf16(x0, y0, a00, 0, 0, 0);
    a01 = __builtin_amdgcn_mfma_f32_16x16x32_bf16(x0, y1, a01, 0, 0, 0);
    a10 = __builtin_amdgcn_mfma_f32_16x16x32_bf16(x1, y0, a10, 0, 0, 0);
    a11 = __builtin_amdgcn_mfma_f32_16x16x32_bf16(x1, y1, a11, 0, 0, 0);
  }
  float* Eb = E + (size_t)b*1024;
  #pragma unroll
  for (int rr = 0; rr < 4; ++rr){
    int row = g*4 + rr;
    atomicAdd(&Eb[row*32 + r],           a00[rr]);
    atomicAdd(&Eb[row*32 + 16 + r],      a01[rr]);
    atomicAdd(&Eb[(row+16)*32 + r],      a10[rr]);
    atomicAdd(&Eb[(row+16)*32 + 16 + r], a11[rr]);
  }
}

__global__ void k_tamsoftmax(const float* __restrict__ e, float* __restrict__ at){
  int tid = threadIdx.x; if (tid >= 128) return;
  int b = tid >> 5, i = tid & 31;
  const float* er = e + ((size_t)b*32 + i)*32;
  float mx = -1e30f;
  for (int j = 0; j < 32; ++j) mx = fmaxf(mx, er[j]);
  float mn = 1e30f;
  for (int j = 0; j < 32; ++j) mn = fminf(mn, er[j]);
  float zmax = mx - mn;
  float sum = 0.f;
  float* ar = at + ((size_t)b*32 + i)*32;
  for (int j = 0; j < 32; ++j){ float p = __expf((mx - er[j]) - zmax); ar[j] = p; sum += p; }
  float inv = 1.f/sum;
  for (int j = 0; j < 32; ++j) ar[j] *= inv;
}

// out_P[b][t][hw][c] = bf16( x_f32[b][c][t*1296+hw] + sc * sum_j attn[t][j]*Y[b][j][hw][c] )
__launch_bounds__(256)
__global__ void k_tamapply_mf(const float* __restrict__ x, const unsigned short* __restrict__ Ybf,
                              const float* __restrict__ at, const float* __restrict__ scp,
                              unsigned short* __restrict__ Pout){
  __shared__ float al[1024];
  int b = blockIdx.z, tid = threadIdx.x;
  for (int i = tid; i < 1024; i += 256) al[i] = at[(size_t)b*1024 + i];
  __syncthreads();
  int n = blockIdx.x*256 + tid;            // [0, 41472)
  int t = n / 1296;
  int hw = n - t*1296;
  float sc = scp[0];
  const float* xb = x + (size_t)b*64*N2 + n;
  float acc[64];
  #pragma unroll
  for (int c = 0; c < 64; ++c) acc[c] = xb[(size_t)c*N2];
  const uint4* yb = (const uint4*)(Ybf + ((size_t)b*N2 + hw)*64);
  const float* ar = &al[t*32];
  for (int j = 0; j < 32; ++j){
    float aj = sc * ar[j];
    const uint4* yr = yb + (size_t)j*1296*8;   // 1296*64 ushorts = 1296*8 uint4
    #pragma unroll
    for (int w = 0; w < 8; ++w){
      uint4 v = yr[w];
      acc[w*8+0] = fmaf(aj, b2f_lo(v.x), acc[w*8+0]);
      acc[w*8+1] = fmaf(aj, b2f_hi(v.x), acc[w*8+1]);
      acc[w*8+2] = fmaf(aj, b2f_lo(v.y), acc[w*8+2]);
      acc[w*8+3] = fmaf(aj, b2f_hi(v.y), acc[w*8+3]);
      acc[w*8+4] = fmaf(aj, b2f_lo(v.z), acc[w*8+4]);
      acc[w*8+5] = fmaf(aj, b2f_hi(v.z), acc[w*8+5]);
      acc[w*8+6] = fmaf(aj, b2f_lo(v.w), acc[w*8+6]);
      acc[w*8+7] = fmaf(aj, b2f_hi(v.w), acc[w*8+7]);
    }
  }
  unsigned short buf[64];
  #pragma unroll
  for (int c = 0; c < 64; ++c) buf[c] = f2b(acc[c]);
  size_t ob = ((size_t)b*N2 + n)*64;
  #pragma unroll
  for (int w = 0; w < 8; ++w){
    uint4 v;
    v.x = (unsigned)buf[w*8+0] | ((unsigned)buf[w*8+1] << 16);
    v.y = (unsigned)buf[w*8+2] | ((unsigned)buf[w*8+3] << 16);
    v.z = (unsigned)buf[w*8+4] | ((unsigned)buf[w*8+5] << 16);
    v.w = (unsigned)buf[w*8+6] | ((unsigned)buf[w*8+7] << 16);
    ((uint4*)(Pout + ob))[w] = v;
  }
}

// ---------------- host ----------------

extern "C" void kernel_launch(void* const* d_in, const int* in_sizes, int n_in,
                              void* d_out, int out_size, void* d_ws, size_t ws_size,
                              hipStream_t stream) {
  const float* x1      = (const float*)d_in[0];
  const float* x2      = (const float*)d_in[1];
  const float* w_conv1 = (const float*)d_in[2];
  const float* g_conv1 = (const float*)d_in[3];
  const float* b_conv1 = (const float*)d_in[4];
  const float* w_conv2 = (const float*)d_in[5];
  const float* g_conv2 = (const float*)d_in[6];
  const float* b_conv2 = (const float*)d_in[7];
  const float* w_tam   = (const float*)d_in[8];
  const float* g_tam   = (const float*)d_in[9];
  const float* b_tam   = (const float*)d_in[10];
  const float* w_cat   = (const float*)d_in[11];
  const float* g_cat   = (const float*)d_in[12];
  const float* b_cat   = (const float*)d_in[13];
  const float* pe_w    = (const float*)d_in[14];
  const float* pe_g    = (const float*)d_in[15];
  const float* pe_b    = (const float*)d_in[16];
  const float* pd_wq   = (const float*)d_in[17];
  const float* pd_bq   = (const float*)d_in[18];
  const float* pd_wk   = (const float*)d_in[19];
  const float* pd_bk   = (const float*)d_in[20];
  const float* pd_wv   = (const float*)d_in[21];
  const float* pd_bv   = (const float*)d_in[22];
  const float* pd_scale= (const float*)d_in[23];
  const float* ce_w    = (const float*)d_in[24];
  const float* ce_g    = (const float*)d_in[25];
  const float* ce_b    = (const float*)d_in[26];
  const float* cd_scale= (const float*)d_in[27];
  const float* te_w    = (const float*)d_in[28];
  const float* te_g    = (const float*)d_in[29];
  const float* te_b    = (const float*)d_in[30];
  const float* td_scale= (const float*)d_in[31];

  float* ws = (float*)d_ws;
  size_t off = 0;
  auto alloc = [&](size_t n){ float* p = ws + off; off += (n + 3) & ~(size_t)3; return p; };
  float* stats = alloc(16384);   // 32 slots x 512
  float* e_tam = alloc(4096);    // contiguous with stats for the zeroing pass
  float* attn_t= alloc(4096);
  float* wTce  = alloc(256);
  unsigned short* Wp1  = (unsigned short*)alloc(24576);
  unsigned short* Wp2  = (unsigned short*)alloc(6144);
  unsigned short* Wpt  = (unsigned short*)alloc(6144);
  unsigned short* Wpc  = (unsigned short*)alloc(73728);
  unsigned short* Wpte = (unsigned short*)alloc(2048);
  float* xm    = alloc(331776);
  float* pp    = alloc(12800);
  float* pf    = alloc(12800);
  float* yb    = alloc(12800);
  float* kb    = alloc(3200);
  float* vb    = alloc(12800);
  float* yc    = alloc(331776);
  float* e_cam = alloc(1024);
  float* A     = alloc(5308416);   // conv1(x1) f32
  float* Bb    = alloc(5308416);   // conv1(x2) f32
  float* PTEf  = alloc(5308416);   // bf16 of BN'd xt1, [b][32][1296][64]
  float* COMB  = alloc(31850496);  // overlaid region

  // COMB overlays (float offsets):
  unsigned short* P0 = (unsigned short*)COMB;                   // [0..21.2M) input bf16
  float* Cc = COMB + 21233664;                                  // [21.2..31.85M) xt1 f32
  float* Dd = COMB;                                             // [0..10.6M) xt2 raw f32
  unsigned short* Dbf  = (unsigned short*)(COMB + 10616832);    // [10.6..15.9M) xt2 bf16
  unsigned short* PTAM = (unsigned short*)(COMB + 15925248);    // [15.9..21.2M) tam out bf16
  float* Rraw = COMB;                                           // [0..5.3M) conv raw outs
  unsigned short* PCAT1 = (unsigned short*)(COMB + 5308416);    // [5.3..13.27M)
  unsigned short* PCAT2 = (unsigned short*)(COMB + 13271040);   // [13.27..21.2M)
  unsigned short* PG    = (unsigned short*)(COMB + 21233664);   // [21.2..23.9M)
  unsigned short* PTE = (unsigned short*)PTEf;

  k_zero<<<dim3(80), 256, 0, stream>>>(stats, 20480);

  // weight prep
  k_wtrans<<<dim3(1), 256, 0, stream>>>(ce_w, wTce, 4, 64, 1);
  k_wpack<<<dim3(192), 256, 0, stream>>>(w_conv1, Wp1, 64, 256, 3);
  k_wpack<<<dim3(48),  256, 0, stream>>>(w_conv2, Wp2, 64, 64, 3);
  k_wpack<<<dim3(48),  256, 0, stream>>>(w_tam,  Wpt, 64, 64, 3);
  k_wpack<<<dim3(576), 256, 0, stream>>>(w_cat,  Wpc, 256, 192, 3);
  k_wpack<<<dim3(16),  256, 0, stream>>>(te_w,   Wpte, 64, 64, 1);

  // inputs -> P0 bf16 transposed (planes 0-15: x1, 16-31: x2)
  k_convT<<<dim3(81, 1, 4), 256, 0, stream>>>(x1, P0, 256, Nn, 32, 0);
  k_convT<<<dim3(81, 1, 4), 256, 0, stream>>>(x2, P0, 256, Nn, 32, 16);

  const float invc16 = 1.f/(4.f*20736.f);
  const float invc32 = 1.f/(4.f*41472.f);

  auto bnstats = [&](float* base, int C, int L, int slot){
    k_bnstats<<<dim3(16, C), 256, 0, stream>>>(base, 4, C, L, (long)C*L, (long)L,
                                               stats + (size_t)slot*512);
  };
  auto bnrelu = [&](float* base, int C, int L, int slot, const float* g, const float* bt,
                    float invc){
    k_bnrelu<<<dim3((L+255)/256, C, 4), 256, 0, stream>>>(base, C, L, (long)C*L, (long)L,
                                               stats + (size_t)slot*512, g, bt, invc);
  };

  // conv1 x1 -> A ; conv1 x2 -> Bb ; conv1 concat -> Cc
  k_mfconv<<<dim3(7,16,4), 256, 0, stream>>>(P0, Wp1, A, 256, 64, 1, 16, 1, 3, 1, 0, 0, 16, 32);
  bnstats(A, 64, Nn, 0); bnrelu(A, 64, Nn, 0, g_conv1, b_conv1, invc16);
  k_mfconv<<<dim3(7,16,4), 256, 0, stream>>>(P0, Wp1, Bb, 256, 64, 1, 16, 1, 3, 1, 16, 16, 32, 32);
  bnstats(Bb, 64, Nn, 1); bnrelu(Bb, 64, Nn, 1, g_conv1, b_conv1, invc16);
  k_mfconv<<<dim3(7,32,4), 256, 0, stream>>>(P0, Wp1, Cc, 256, 64, 1, 32, 1, 3, 1, 0, 0, 32, 32);
  bnstats(Cc, 64, N2, 2); bnrelu(Cc, 64, N2, 2, g_conv1, b_conv1, invc32);

  // xt2 = pw_bn_relu(xt1, te_w): Cc -> PTE -> te GEMM -> Dd raw -> (stats) -> Dbf bf16
  k_convT<<<dim3(162, 1, 4), 256, 0, stream>>>(Cc, PTE, 64, N2, 32, 0);
  k_mfconv<<<dim3(7,32,4), 256, 0, stream>>>(PTE, Wpte, Dd, 64, 64, 1, 32, 1, 1, 0, 0, 0, 32, 32);
  bnstats(Dd, 64, N2, 3);
  k_bnT<<<dim3(162,1,4), 256, 0, stream>>>(Dd, stats + 3*512, te_g, te_b, invc32,
                                           Dbf, nullptr, N2, 64, 0);

  // TAM: MFMA energy from bf16 row-major matrices, fused apply -> PTAM (bf16 P-layout)
  k_tamenergy_mf<<<dim3(81, 1, 4), 256, 0, stream>>>(PTE, Dbf, e_tam);
  k_tamsoftmax<<<dim3(1), 128, 0, stream>>>(e_tam, attn_t);
  k_tamapply_mf<<<dim3(162, 1, 4), 256, 0, stream>>>(Cc, Dbf, attn_t, td_scale, PTAM);
  // tam conv (stride 2) -> Rraw; BN -> PCAT1/PCAT2 channels 128-191
  k_mfconv<<<dim3(7,16,4), 256, 0, stream>>>(PTAM, Wpt, Rraw, 64, 64, 1, 16, 2, 3, 1, 0, 0, 32, 32);
  bnstats(Rraw, 64, Nn, 4);
  k_bnT<<<dim3(81,1,4), 256, 0, stream>>>(Rraw, stats + 4*512, g_tam, b_tam, invc16,
                                          PCAT1, PCAT2, Nn, 192, 128);

  // PAM encoder chain
  auto pam_enc = [&](const float* xin, int slotbase){
    k_meanT<<<dim3(6, 64, 4), 256, 0, stream>>>(xin, xm);
    k_pool<<<dim3(1, 64, 4), 64, 0, stream>>>(xm, pp);
    k_pemm<<<dim3(50, 1, 4), 64, 0, stream>>>(pp, pe_w, pf);
    const int ss[4] = {1,2,3,6}; const int so[4] = {0,1,5,14};
    for (int i = 0; i < 4; ++i){
      int s2 = ss[i]*ss[i];
      float* sums = stats + (size_t)(slotbase+i)*512;
      k_bnstats<<<dim3(1, 64), 256, 0, stream>>>(pf + so[i], 4, 64, s2, 3200L, 50L, sums);
      k_bnrelu<<<dim3(1, 64, 4), 256, 0, stream>>>(pf + so[i], 64, s2, 3200L, 50L,
                                                   sums, pe_g + i*64, pe_b + i*64,
                                                   1.f/(4.f*(float)s2));
    }
    k_ytrans<<<dim3(50, 1, 4), 64, 0, stream>>>(pf, yb);
    k_pamkv<<<dim3(50, 1, 4), 128, 0, stream>>>(yb, pd_wk, pd_bk, pd_wv, pd_bv, kb, vb);
  };

  // PAM x1 -> PG -> conv2 -> PCAT1[0:64]
  pam_enc(A, 5);
  k_pamattn<<<dim3(81, 1, 4), 256, 0, stream>>>(A, kb, vb, pd_wq, pd_bq, pd_scale, PG);
  k_mfconv<<<dim3(7,16,4), 256, 0, stream>>>(PG, Wp2, Rraw, 64, 64, 1, 16, 1, 3, 1, 0, 0, 16, 16);
  bnstats(Rraw, 64, Nn, 13);
  k_bnT<<<dim3(81,1,4), 256, 0, stream>>>(Rraw, stats + 13*512, g_conv2, b_conv2, invc16,
                                          PCAT1, nullptr, Nn, 192, 0);
  // PAM x2 -> PCAT2[0:64]
  pam_enc(Bb, 9);
  k_pamattn<<<dim3(81, 1, 4), 256, 0, stream>>>(Bb, kb, vb, pd_wq, pd_bq, pd_scale, PG);
  k_mfconv<<<dim3(7,16,4), 256, 0, stream>>>(PG, Wp2, Rraw, 64, 64, 1, 16, 1, 3, 1, 0, 0, 16, 16);
  bnstats(Rraw, 64, Nn, 14);
  k_bnT<<<dim3(81,1,4), 256, 0, stream>>>(Rraw, stats + 14*512, g_conv2, b_conv2, invc16,
                                          PCAT2, nullptr, Nn, 192, 0);

  // CAM
  auto cam = [&](const float* xin, unsigned short* catp, int slot_ce, int slot_c2){
    k_tconv<<<dim3(6, 16, 4), dim3(4, 64), 0, stream>>>(xin, nullptr, 16, 16, wTce, yc,
                                                        64, 4, 16, 16, 1, 1, 0, 4, 0, 1);
    k_bnstats<<<dim3(16, 4), 256, 0, stream>>>(yc, 4, 4, Nn, 4L*Nn, (long)Nn,
                                               stats + (size_t)slot_ce*512);
    k_bnrelu<<<dim3((Nn+255)/256, 4, 4), 256, 0, stream>>>(yc, 4, Nn, 4L*Nn, (long)Nn,
                                               stats + (size_t)slot_ce*512, ce_g, ce_b, invc16);
    k_camenergy<<<dim3(1, 64, 4), 256, 0, stream>>>(xin, yc, e_cam);
    k_camapplyT<<<dim3(81, 1, 4), 256, 0, stream>>>(xin, yc, e_cam, cd_scale, PG);
    k_mfconv<<<dim3(7,16,4), 256, 0, stream>>>(PG, Wp2, Rraw, 64, 64, 1, 16, 1, 3, 1, 0, 0, 16, 16);
    bnstats(Rraw, 64, Nn, slot_c2);
    k_bnT<<<dim3(81,1,4), 256, 0, stream>>>(Rraw, stats + (size_t)slot_c2*512,
                                            g_conv2, b_conv2, invc16,
                                            catp, nullptr, Nn, 192, 64);
  };
  cam(A,  PCAT2, 15, 17);  // x1_ca -> PCAT2[64:128]
  cam(Bb, PCAT1, 16, 18);  // x2_ca -> PCAT1[64:128]

  // final cat convs -> d_out
  float* out1 = (float*)d_out;
  float* out2 = out1 + (size_t)4*256*Nn;
  k_mfconv<<<dim3(7,16,16), 256, 0, stream>>>(PCAT1, Wpc, out1, 192, 256, 4, 16, 1, 3, 1, 0, 0, 16, 16);
  bnstats(out1, 256, Nn, 19); bnrelu(out1, 256, Nn, 19, g_cat, b_cat, invc16);
  k_mfconv<<<dim3(7,16,16), 256, 0, stream>>>(PCAT2, Wpc, out2, 192, 256, 4, 16, 1, 3, 1, 0, 0, 16, 16);
  bnstats(out2, 256, Nn, 20); bnrelu(out2, 256, Nn, 20, g_cat, b_cat, invc16);
}

// Round 4
// 1438.476 us; speedup vs baseline: 5.8299x; 1.2438x over previous
//
#include <hip/hip_runtime.h>

#define HW 1296
#define HW4 324
#define Tt 16
#define T2 32
#define Nn 20736
#define N2 41472

typedef short bf16x8 __attribute__((ext_vector_type(8)));
typedef float f32x4 __attribute__((ext_vector_type(4)));

__device__ inline unsigned short f2b(float f){
  union { float f; unsigned u; } v; v.f = f;
  unsigned r = v.u + 0x7FFF + ((v.u >> 16) & 1);
  return (unsigned short)(r >> 16);
}
__device__ inline float b2f_lo(unsigned u){
  union { unsigned u; float f; } v; v.u = u << 16; return v.f;
}
__device__ inline float b2f_hi(unsigned u){
  union { unsigned u; float f; } v; v.u = u & 0xffff0000u; return v.f;
}

// pack 64 floats -> 32 uints of bf16 pairs
__device__ __forceinline__ void pack_pairs(const float* a, unsigned* vals){
  #pragma unroll
  for (int i = 0; i < 32; ++i)
    vals[i] = (unsigned)f2b(a[2*i]) | ((unsigned)f2b(a[2*i+1]) << 16);
}

// LDS-transpose staged coalesced write. Block = 256 threads, each owns one row of
// 64 bf16 (32 uints in vals). Rows R0..R0+255 of a [*, outC] bf16 matrix,
// rowu4 = outC/8 (uint4 per row), cw = coff/8. lds must be >= 8448 uints.
// Includes leading AND trailing syncthreads-safe usage (syncs internally).
__device__ __forceinline__ void staged_write(unsigned* lds, int tid, const unsigned* vals,
                                             uint4* o4, size_t R0, int rowu4, int cw,
                                             uint4* o4b){
  #pragma unroll
  for (int i = 0; i < 32; ++i) lds[tid*33 + i] = vals[i];
  __syncthreads();
  #pragma unroll
  for (int k = 0; k < 8; ++k){
    int j = k*256 + tid;
    int nn = j >> 3, w = j & 7;
    int base = nn*33 + w*4;
    uint4 v;
    v.x = lds[base]; v.y = lds[base+1]; v.z = lds[base+2]; v.w = lds[base+3];
    size_t oidx = (R0 + (size_t)nn)*(size_t)rowu4 + cw + w;
    o4[oidx] = v;
    if (o4b) o4b[oidx] = v;
  }
  __syncthreads();
}

// ---------------- utility kernels ----------------

__global__ void k_zero(float* p, int n){
  int i = blockIdx.x*blockDim.x + threadIdx.x;
  if (i < n) p[i] = 0.f;
}

__global__ void k_wtrans(const float* __restrict__ w, float* __restrict__ wT,
                         int Cout, int Cin, int KT){
  int idx = blockIdx.x*blockDim.x + threadIdx.x;
  int tot = Cout*Cin*KT;
  if (idx >= tot) return;
  int o  = idx / (Cin*KT);
  int r  = idx % (Cin*KT);
  int i  = r / KT;
  int dt = r % KT;
  wT[((size_t)dt*Cin + i)*Cout + o] = w[idx];
}

// pack conv weights (Cout,Cin,KT) f32 -> MFMA A-frag order bf16
__global__ void k_wpack(const float* __restrict__ w, unsigned short* __restrict__ wp,
                        int Cout, int Cin, int KT){
  int e = blockIdx.x*256 + threadIdx.x;
  int tot = Cout*Cin*KT;
  if (e >= tot) return;
  int Kt32 = (Cin*KT) >> 5;
  int j    = e & 7;
  int lane = (e >> 3) & 63;
  int rest = e >> 9;
  int ks   = rest % Kt32;
  int mt   = rest / Kt32;
  int m  = mt*16 + (lane & 15);
  int k  = ks*32 + (lane >> 4)*8 + j;
  int dt = k / Cin, ci = k - dt*Cin;
  wp[e] = f2b(w[((size_t)m*Cin + ci)*KT + dt]);
}

// f32 [b][C][L] -> bf16 P-layout [b][plane][hw][C], staged coalesced writes
__global__ void k_convT(const float* __restrict__ x, unsigned short* __restrict__ Pb,
                        int C, int L, int PT, int p0){
  __shared__ unsigned lds[8448];
  int tid = threadIdx.x, b = blockIdx.z;
  int n0 = blockIdx.x*256, n = n0 + tid;
  const float* xb = x + (size_t)b*C*L + n;
  size_t R0 = (size_t)(b*PT + p0)*1296 + n0;
  int rowu4 = C >> 3;
  uint4* o4 = (uint4*)Pb;
  for (int c0 = 0; c0 < C; c0 += 64){
    float a[64];
    #pragma unroll
    for (int c = 0; c < 64; ++c) a[c] = xb[(size_t)(c0 + c)*L];
    unsigned vals[32];
    pack_pairs(a, vals);
    staged_write(lds, tid, vals, o4, R0, rowu4, c0 >> 3, nullptr);
  }
}

// ---------------- MFMA conv-as-GEMM ----------------
__launch_bounds__(256)
__global__ void k_mfconv(const unsigned short* __restrict__ P, const unsigned short* __restrict__ Wp,
                         float* __restrict__ out, int Cin, int Cout, int Mz,
                         int Tout, int stride, int KT, int pad, int p0, int plo, int phi, int PT)
{
  int bz = blockIdx.z; int b = bz / Mz; int mz = bz - b*Mz;
  int lane = threadIdx.x & 63;
  int tile = blockIdx.x*4 + (threadIdx.x >> 6);
  if (tile >= 27) return;
  int t = blockIdx.y;
  int col = lane & 15, grp = lane >> 4;
  int hw0 = tile*48 + col;
  int Kt32 = (KT*Cin) >> 5;
  f32x4 acc[4][3];
  #pragma unroll
  for (int i = 0; i < 4; ++i)
    #pragma unroll
    for (int j = 0; j < 3; ++j) acc[i][j] = (f32x4){0.f, 0.f, 0.f, 0.f};
  const unsigned short* wbase = Wp + ((size_t)(mz*4)*Kt32)*512 + lane*8;
  for (int dt = 0; dt < KT; ++dt){
    int p = t*stride + dt - pad + p0;
    if (p < plo || p >= phi) continue;
    const unsigned short* Pp = P + ((size_t)(b*PT + p)*1296 + hw0)*Cin + grp*8;
    int nCk = Cin >> 5;
    int ksg = (dt*Cin) >> 5;
    for (int kc = 0; kc < nCk; ++kc){
      bf16x8 bf0 = *(const bf16x8*)(Pp + (size_t)0*Cin  + kc*32);
      bf16x8 bf1 = *(const bf16x8*)(Pp + (size_t)16*Cin + kc*32);
      bf16x8 bf2 = *(const bf16x8*)(Pp + (size_t)32*Cin + kc*32);
      #pragma unroll
      for (int mf = 0; mf < 4; ++mf){
        bf16x8 af = *(const bf16x8*)(wbase + ((size_t)mf*Kt32 + ksg + kc)*512);
        acc[mf][0] = __builtin_amdgcn_mfma_f32_16x16x32_bf16(af, bf0, acc[mf][0], 0, 0, 0);
        acc[mf][1] = __builtin_amdgcn_mfma_f32_16x16x32_bf16(af, bf1, acc[mf][1], 0, 0, 0);
        acc[mf][2] = __builtin_amdgcn_mfma_f32_16x16x32_bf16(af, bf2, acc[mf][2], 0, 0, 0);
      }
    }
  }
  size_t cs = (size_t)Tout*1296;
  size_t obase = ((size_t)(b*Cout + mz*64 + grp*4))*cs + (size_t)t*1296;
  #pragma unroll
  for (int mf = 0; mf < 4; ++mf)
    #pragma unroll
    for (int f = 0; f < 3; ++f){
      int hw = tile*48 + f*16 + col;
      #pragma unroll
      for (int r = 0; r < 4; ++r)
        out[obase + (size_t)(mf*16 + r)*cs + hw] = acc[mf][f][r];
    }
}

// ---------------- naive temporal conv (kept only for ce pw 64->4) ----------------
__global__ void k_tconv(const float* __restrict__ xA, const float* __restrict__ xB,
                        int t_split, int Tpart,
                        const float* __restrict__ wT,
                        float* __restrict__ out,
                        int Cin, int Cout, int Tin, int Tout, int stride, int KT, int pad,
                        int out_cstride, int out_coff, int OC)
{
  int b  = blockIdx.z / OC;
  int oc = blockIdx.z % OC;
  int o  = oc*blockDim.x + threadIdx.x;
  int t  = blockIdx.y;
  int hw4 = blockIdx.x*blockDim.y + threadIdx.y;
  if (hw4 >= HW4) return;
  float4 acc = make_float4(0.f,0.f,0.f,0.f);
  for (int dt = 0; dt < KT; ++dt){
    int tt = t*stride + dt - pad;
    if (tt < 0 || tt >= Tin) continue;
    const float* xp = (tt < t_split) ? xA : xB;
    int tl = (tt < t_split) ? tt : (tt - t_split);
    const float4* xr = (const float4*)xp + ((size_t)b*Cin*Tpart + tl)*HW4 + hw4;
    const float* wp  = wT + (size_t)dt*Cin*Cout + o;
    size_t xstep = (size_t)Tpart*HW4;
    for (int i = 0; i < Cin; ++i){
      float4 xv = *xr;
      float  wv = *wp;
      acc.x = fmaf(wv, xv.x, acc.x);
      acc.y = fmaf(wv, xv.y, acc.y);
      acc.z = fmaf(wv, xv.z, acc.z);
      acc.w = fmaf(wv, xv.w, acc.w);
      xr += xstep; wp += Cout;
    }
  }
  float4* op = (float4*)out + ((size_t)(b*out_cstride + out_coff + o)*Tout + t)*HW4 + hw4;
  *op = acc;
}

// ---------------- BN ----------------

__global__ void k_bnstats(const float* __restrict__ x, int Bn, int Cn, int L,
                          long bstride, long cstride, float* __restrict__ sums)
{
  int c = blockIdx.y;
  int tid = threadIdx.x;
  float s = 0.f, sq = 0.f;
  int tot = Bn*L;
  for (int idx = blockIdx.x*blockDim.x + tid; idx < tot; idx += gridDim.x*blockDim.x){
    int b = idx / L; int l = idx - b*L;
    float v = x[(size_t)b*bstride + (size_t)c*cstride + l];
    s += v; sq += v*v;
  }
  __shared__ float r1[256], r2[256];
  r1[tid] = s; r2[tid] = sq; __syncthreads();
  for (int k = 128; k > 0; k >>= 1){
    if (tid < k){ r1[tid] += r1[tid+k]; r2[tid] += r2[tid+k]; }
    __syncthreads();
  }
  if (tid == 0){ atomicAdd(&sums[c], r1[0]); atomicAdd(&sums[Cn+c], r2[0]); }
}

__global__ void k_bnrelu(float* __restrict__ x, int Cn, int L, long bstride, long cstride,
                         const float* __restrict__ sums, const float* __restrict__ g,
                         const float* __restrict__ bet, float invc)
{
  int c = blockIdx.y, b = blockIdx.z;
  int l = blockIdx.x*blockDim.x + threadIdx.x;
  if (l >= L) return;
  float m  = sums[c]*invc;
  float v  = fmaxf(sums[Cn+c]*invc - m*m, 0.f);
  float sc = g[c]*rsqrtf(v + 1e-5f);
  float bb = bet[c] - m*sc;
  size_t idx = (size_t)b*bstride + (size_t)c*cstride + l;
  float val = fmaf(x[idx], sc, bb);
  x[idx] = fmaxf(val, 0.f);
}

// BN+ReLU on raw f32 [b][64][L] -> bf16 P layout rows [b][n][outC] at coff (staged writes)
__global__ void k_bnT(const float* __restrict__ x, const float* __restrict__ sums,
                      const float* __restrict__ g, const float* __restrict__ bet, float invc,
                      unsigned short* __restrict__ P1, unsigned short* __restrict__ P2,
                      int L, int outC, int coff)
{
  __shared__ unsigned lds[8448];
  int tid = threadIdx.x, b = blockIdx.z;
  int n0 = blockIdx.x*256, n = n0 + tid;
  const float* xb = x + (size_t)b*64*L + n;
  float a[64];
  #pragma unroll
  for (int c = 0; c < 64; ++c){
    float m  = sums[c]*invc;
    float vv = fmaxf(sums[64+c]*invc - m*m, 0.f);
    float sc = g[c]*rsqrtf(vv + 1e-5f);
    float bb = bet[c] - m*sc;
    a[c] = fmaxf(fmaf(xb[(size_t)c*L], sc, bb), 0.f);
  }
  unsigned vals[32];
  pack_pairs(a, vals);
  staged_write(lds, tid, vals, (uint4*)P1, (size_t)b*L + n0, outC >> 3, coff >> 3,
               P2 ? (uint4*)P2 : nullptr);
}

// ---------------- PAM encoder ----------------

__global__ void k_meanT(const float* __restrict__ x, float* __restrict__ xm){
  int c = blockIdx.y, b = blockIdx.z;
  int hw = blockIdx.x*blockDim.x + threadIdx.x;
  if (hw >= HW) return;
  const float* xp = x + ((size_t)(b*64+c)*Tt)*HW + hw;
  float s = 0.f;
  for (int t = 0; t < Tt; ++t) s += xp[(size_t)t*HW];
  xm[(size_t)(b*64+c)*HW + hw] = s*(1.f/16.f);
}

__global__ void k_pool(const float* __restrict__ xm, float* __restrict__ pp){
  int c = blockIdx.y, b = blockIdx.z;
  int cell = threadIdx.x;
  if (cell >= 50) return;
  int s, off;
  if (cell < 1){ s=1; off=0; } else if (cell < 5){ s=2; off=1; }
  else if (cell < 14){ s=3; off=5; } else { s=6; off=14; }
  int local = cell - off, ph = local/s, pw = local%s, bh = 36/s;
  const float* xp = xm + (size_t)(b*64+c)*HW;
  float sum = 0.f;
  for (int h = ph*bh; h < (ph+1)*bh; ++h)
    for (int w = pw*bh; w < (pw+1)*bh; ++w) sum += xp[h*36 + w];
  pp[(size_t)(b*64+c)*50 + cell] = sum / (float)(bh*bh);
}

__global__ void k_pemm(const float* __restrict__ pp, const float* __restrict__ pew,
                       float* __restrict__ pf){
  int cell = blockIdx.x, b = blockIdx.z;
  int o = threadIdx.x;  // 64
  int sc;
  if (cell < 1) sc=0; else if (cell < 5) sc=1; else if (cell < 14) sc=2; else sc=3;
  const float* w = pew + (size_t)sc*4096 + o*64;
  const float* p = pp + (size_t)b*3200 + cell;
  float s = 0.f;
  for (int i = 0; i < 64; ++i) s = fmaf(w[i], p[(size_t)i*50], s);
  pf[(size_t)(b*64+o)*50 + cell] = s;
}

__global__ void k_ytrans(const float* __restrict__ pf, float* __restrict__ y){
  int k = blockIdx.x, b = blockIdx.z; int c = threadIdx.x;
  y[((size_t)b*50 + k)*64 + c] = pf[((size_t)b*64 + c)*50 + k];
}

__global__ void k_pamkv(const float* __restrict__ y, const float* __restrict__ wk,
                        const float* __restrict__ bk, const float* __restrict__ wv,
                        const float* __restrict__ bv,
                        float* __restrict__ kb, float* __restrict__ vb){
  int kk = blockIdx.x, b = blockIdx.z; int t = threadIdx.x;
  const float* yp = y + ((size_t)b*50 + kk)*64;
  if (t < 16){
    float s = bk[t]; const float* w = wk + t*64;
    for (int i = 0; i < 64; ++i) s = fmaf(w[i], yp[i], s);
    kb[((size_t)b*50 + kk)*16 + t] = s;
  } else if (t < 80){
    int c = t - 16;
    float s = bv[c]; const float* w = wv + c*64;
    for (int i = 0; i < 64; ++i) s = fmaf(w[i], yp[i], s);
    vb[((size_t)b*50 + kk)*64 + c] = s;
  }
}

// KW[b][k][c] = sum_o kb[b][k][o] * wq[o][c];  sb[b][k] = sum_o kb[b][k][o]*bq[o]
__global__ void k_kw(const float* __restrict__ kb, const float* __restrict__ wq,
                     const float* __restrict__ bq,
                     float* __restrict__ KW, float* __restrict__ sb){
  int b = blockIdx.z;
  int tid = threadIdx.x;
  int c = tid & 63;
  for (int k = tid >> 6; k < 50; k += 4){
    const float* kp = kb + ((size_t)b*50 + k)*16;
    float s = 0.f;
    #pragma unroll
    for (int o = 0; o < 16; ++o) s = fmaf(kp[o], wq[o*64 + c], s);
    KW[((size_t)b*50 + k)*64 + c] = s;
  }
  if (tid < 50){
    const float* kp = kb + ((size_t)b*50 + tid)*16;
    float s = 0.f;
    #pragma unroll
    for (int o = 0; o < 16; ++o) s = fmaf(kp[o], bq[o], s);
    sb[(size_t)b*50 + tid] = s;
  }
}

// scores via KW trick; softmax; PV + residual from registers; staged bf16 write
__launch_bounds__(256, 1)
__global__ void k_pamattn(const float* __restrict__ x, const float* __restrict__ KW,
                          const float* __restrict__ sbb, const float* __restrict__ vbuf,
                          const float* __restrict__ scp, unsigned short* __restrict__ Pg)
{
  __shared__ unsigned smem_u[8448];
  float* smem = (float*)smem_u;      // [0,3200) KW ; [3200,6400) v ; [6400,6450) sb
  int b = blockIdx.z, tid = threadIdx.x;
  for (int i = tid; i < 3200; i += 256){
    smem[i]        = KW[(size_t)b*3200 + i];
    smem[3200 + i] = vbuf[(size_t)b*3200 + i];
  }
  if (tid < 50) smem[6400 + tid] = sbb[(size_t)b*50 + tid];
  __syncthreads();
  int n0 = blockIdx.x*256;
  int n = n0 + tid;
  const float* xb = x + (size_t)b*64*Nn + n;
  float xv[64];
  #pragma unroll
  for (int c = 0; c < 64; ++c) xv[c] = xb[(size_t)c*Nn];
  float s[50];
  const float4* kw4 = (const float4*)smem;
  #pragma unroll
  for (int k = 0; k < 50; ++k){
    float t = smem[6400 + k];
    #pragma unroll
    for (int c4 = 0; c4 < 16; ++c4){
      float4 kw = kw4[k*16 + c4];
      t = fmaf(xv[c4*4+0], kw.x, t);
      t = fmaf(xv[c4*4+1], kw.y, t);
      t = fmaf(xv[c4*4+2], kw.z, t);
      t = fmaf(xv[c4*4+3], kw.w, t);
    }
    s[k] = t;
  }
  float mx = -1e30f;
  #pragma unroll
  for (int k = 0; k < 50; ++k) mx = fmaxf(mx, s[k]);
  float sum = 0.f;
  #pragma unroll
  for (int k = 0; k < 50; ++k){ float p = __expf(s[k]-mx); s[k] = p; sum += p; }
  float sc = scp[0]/sum;
  const float4* vl4 = (const float4*)(smem + 3200);
  #pragma unroll
  for (int k = 0; k < 50; ++k){
    float pk = sc * s[k];
    #pragma unroll
    for (int c4 = 0; c4 < 16; ++c4){
      float4 v = vl4[k*16 + c4];
      xv[c4*4+0] = fmaf(pk, v.x, xv[c4*4+0]);
      xv[c4*4+1] = fmaf(pk, v.y, xv[c4*4+1]);
      xv[c4*4+2] = fmaf(pk, v.z, xv[c4*4+2]);
      xv[c4*4+3] = fmaf(pk, v.w, xv[c4*4+3]);
    }
  }
  __syncthreads();
  unsigned vals[32];
  pack_pairs(xv, vals);
  staged_write(smem_u, tid, vals, (uint4*)Pg, (size_t)b*Nn + n0, 8, 0, nullptr);
}

// ---------------- CAM ----------------

__global__ void k_camenergy(const float* __restrict__ x, const float* __restrict__ yc,
                            float* __restrict__ e){
  int c = blockIdx.y, b = blockIdx.z, tid = threadIdx.x;
  const float4* x4 = (const float4*)x + (size_t)(b*64+c)*5184;
  const float4* y4 = (const float4*)yc + (size_t)b*4*5184;
  float acc[4] = {0.f,0.f,0.f,0.f};
  for (int n4 = tid; n4 < 5184; n4 += 256){
    float4 xv = x4[n4];
    for (int kk = 0; kk < 4; ++kk){
      float4 yv = y4[kk*5184 + n4];
      acc[kk] += xv.x*yv.x + xv.y*yv.y + xv.z*yv.z + xv.w*yv.w;
    }
  }
  __shared__ float red[256];
  for (int kk = 0; kk < 4; ++kk){
    red[tid] = acc[kk]; __syncthreads();
    for (int s = 128; s > 0; s >>= 1){ if (tid < s) red[tid] += red[tid+s]; __syncthreads(); }
    if (tid == 0) e[(size_t)(b*64+c)*4 + kk] = red[0];
    __syncthreads();
  }
}

__global__ void k_camapplyT(const float* __restrict__ x, const float* __restrict__ yc,
                            const float* __restrict__ e, const float* __restrict__ scp,
                            unsigned short* __restrict__ Pg){
  __shared__ float pw[64][4];
  __shared__ unsigned lds[8448];
  int tid = threadIdx.x;
  int b = blockIdx.z;
  if (tid < 64){
    const float* er = e + (size_t)(b*64+tid)*4;
    float e0=er[0], e1=er[1], e2=er[2], e3=er[3];
    float mx = fmaxf(fmaxf(e0,e1), fmaxf(e2,e3));
    float z0=mx-e0, z1=mx-e1, z2=mx-e2, z3=mx-e3;
    float zm = fmaxf(fmaxf(z0,z1), fmaxf(z2,z3));
    float p0=__expf(z0-zm), p1=__expf(z1-zm), p2=__expf(z2-zm), p3=__expf(z3-zm);
    float inv = 1.f/(p0+p1+p2+p3);
    pw[tid][0]=p0*inv; pw[tid][1]=p1*inv; pw[tid][2]=p2*inv; pw[tid][3]=p3*inv;
  }
  __syncthreads();
  int n0 = blockIdx.x*256;
  int n = n0 + tid;
  float y0 = yc[((size_t)b*4+0)*Nn + n];
  float y1 = yc[((size_t)b*4+1)*Nn + n];
  float y2 = yc[((size_t)b*4+2)*Nn + n];
  float y3 = yc[((size_t)b*4+3)*Nn + n];
  float sc = scp[0];
  const float* xb = x + (size_t)b*64*Nn + n;
  float a[64];
  #pragma unroll
  for (int c = 0; c < 64; ++c){
    a[c] = fmaf(sc, pw[c][0]*y0 + pw[c][1]*y1 + pw[c][2]*y2 + pw[c][3]*y3,
                xb[(size_t)c*Nn]);
  }
  unsigned vals[32];
  pack_pairs(a, vals);
  staged_write(lds, tid, vals, (uint4*)Pg, (size_t)b*Nn + n0, 8, 0, nullptr);
}

// ---------------- TAM (MFMA energy + fused apply) ----------------

__launch_bounds__(256)
__global__ void k_tamenergy_mf(const unsigned short* __restrict__ X,
                               const unsigned short* __restrict__ Y,
                               float* __restrict__ E){
  int b = blockIdx.z;
  int wave = threadIdx.x >> 6, lane = threadIdx.x & 63;
  int r = lane & 15, g = lane >> 4;
  const unsigned short* Xb = X + (size_t)b*32*82944;
  const unsigned short* Yb = Y + (size_t)b*32*82944;
  f32x4 a00 = (f32x4){0.f,0.f,0.f,0.f};
  f32x4 a01 = a00, a10 = a00, a11 = a00;
  int c0 = (blockIdx.x*4 + wave)*8;
  for (int cc = 0; cc < 8; ++cc){
    size_t k0 = (size_t)(c0 + cc)*32 + (size_t)g*8;
    bf16x8 x0 = *(const bf16x8*)(Xb + (size_t)r*82944 + k0);
    bf16x8 x1 = *(const bf16x8*)(Xb + (size_t)(r+16)*82944 + k0);
    bf16x8 y0 = *(const bf16x8*)(Yb + (size_t)r*82944 + k0);
    bf16x8 y1 = *(const bf16x8*)(Yb + (size_t)(r+16)*82944 + k0);
    a00 = __builtin_amdgcn_mfma_f32_16x16x32_bf16(x0, y0, a00, 0, 0, 0);
    a01 = __builtin_amdgcn_mfma_f32_16x16x32_bf16(x0, y1, a01, 0, 0, 0);
    a10 = __builtin_amdgcn_mfma_f32_16x16x32_bf16(x1, y0, a10, 0, 0, 0);
    a11 = __builtin_amdgcn_mfma_f32_16x16x32_bf16(x1, y1, a11, 0, 0, 0);
  }
  float* Eb = E + (size_t)b*1024;
  #pragma unroll
  for (int rr = 0; rr < 4; ++rr){
    int row = g*4 + rr;
    atomicAdd(&Eb[row*32 + r],           a00[rr]);
    atomicAdd(&Eb[row*32 + 16 + r],      a01[rr]);
    atomicAdd(&Eb[(row+16)*32 + r],      a10[rr]);
    atomicAdd(&Eb[(row+16)*32 + 16 + r], a11[rr]);
  }
}

__global__ void k_tamsoftmax(const float* __restrict__ e, float* __restrict__ at){
  int tid = threadIdx.x; if (tid >= 128) return;
  int b = tid >> 5, i = tid & 31;
  const float* er = e + ((size_t)b*32 + i)*32;
  float mx = -1e30f;
  for (int j = 0; j < 32; ++j) mx = fmaxf(mx, er[j]);
  float mn = 1e30f;
  for (int j = 0; j < 32; ++j) mn = fminf(mn, er[j]);
  float zmax = mx - mn;
  float sum = 0.f;
  float* ar = at + ((size_t)b*32 + i)*32;
  for (int j = 0; j < 32; ++j){ float p = __expf((mx - er[j]) - zmax); ar[j] = p; sum += p; }
  float inv = 1.f/sum;
  for (int j = 0; j < 32; ++j) ar[j] *= inv;
}

__launch_bounds__(256)
__global__ void k_tamapply_mf(const float* __restrict__ x, const unsigned short* __restrict__ Ybf,
                              const float* __restrict__ at, const float* __restrict__ scp,
                              unsigned short* __restrict__ Pout){
  __shared__ float al[1024];
  __shared__ unsigned lds[8448];
  int b = blockIdx.z, tid = threadIdx.x;
  for (int i = tid; i < 1024; i += 256) al[i] = at[(size_t)b*1024 + i];
  __syncthreads();
  int n0 = blockIdx.x*256;
  int n = n0 + tid;
  int t = n / 1296;
  int hw = n - t*1296;
  float sc = scp[0];
  const float* xb = x + (size_t)b*64*N2 + n;
  float acc[64];
  #pragma unroll
  for (int c = 0; c < 64; ++c) acc[c] = xb[(size_t)c*N2];
  const uint4* yb = (const uint4*)(Ybf + ((size_t)b*N2 + hw)*64);
  const float* ar = &al[t*32];
  for (int j = 0; j < 32; ++j){
    float aj = sc * ar[j];
    const uint4* yr = yb + (size_t)j*1296*8;
    #pragma unroll
    for (int w = 0; w < 8; ++w){
      uint4 v = yr[w];
      acc[w*8+0] = fmaf(aj, b2f_lo(v.x), acc[w*8+0]);
      acc[w*8+1] = fmaf(aj, b2f_hi(v.x), acc[w*8+1]);
      acc[w*8+2] = fmaf(aj, b2f_lo(v.y), acc[w*8+2]);
      acc[w*8+3] = fmaf(aj, b2f_hi(v.y), acc[w*8+3]);
      acc[w*8+4] = fmaf(aj, b2f_lo(v.z), acc[w*8+4]);
      acc[w*8+5] = fmaf(aj, b2f_hi(v.z), acc[w*8+5]);
      acc[w*8+6] = fmaf(aj, b2f_lo(v.w), acc[w*8+6]);
      acc[w*8+7] = fmaf(aj, b2f_hi(v.w), acc[w*8+7]);
    }
  }
  unsigned vals[32];
  pack_pairs(acc, vals);
  staged_write(lds, tid, vals, (uint4*)Pout, (size_t)b*N2 + n0, 8, 0, nullptr);
}

// ---------------- host ----------------

extern "C" void kernel_launch(void* const* d_in, const int* in_sizes, int n_in,
                              void* d_out, int out_size, void* d_ws, size_t ws_size,
                              hipStream_t stream) {
  const float* x1      = (const float*)d_in[0];
  const float* x2      = (const float*)d_in[1];
  const float* w_conv1 = (const float*)d_in[2];
  const float* g_conv1 = (const float*)d_in[3];
  const float* b_conv1 = (const float*)d_in[4];
  const float* w_conv2 = (const float*)d_in[5];
  const float* g_conv2 = (const float*)d_in[6];
  const float* b_conv2 = (const float*)d_in[7];
  const float* w_tam   = (const float*)d_in[8];
  const float* g_tam   = (const float*)d_in[9];
  const float* b_tam   = (const float*)d_in[10];
  const float* w_cat   = (const float*)d_in[11];
  const float* g_cat   = (const float*)d_in[12];
  const float* b_cat   = (const float*)d_in[13];
  const float* pe_w    = (const float*)d_in[14];
  const float* pe_g    = (const float*)d_in[15];
  const float* pe_b    = (const float*)d_in[16];
  const float* pd_wq   = (const float*)d_in[17];
  const float* pd_bq   = (const float*)d_in[18];
  const float* pd_wk   = (const float*)d_in[19];
  const float* pd_bk   = (const float*)d_in[20];
  const float* pd_wv   = (const float*)d_in[21];
  const float* pd_bv   = (const float*)d_in[22];
  const float* pd_scale= (const float*)d_in[23];
  const float* ce_w    = (const float*)d_in[24];
  const float* ce_g    = (const float*)d_in[25];
  const float* ce_b    = (const float*)d_in[26];
  const float* cd_scale= (const float*)d_in[27];
  const float* te_w    = (const float*)d_in[28];
  const float* te_g    = (const float*)d_in[29];
  const float* te_b    = (const float*)d_in[30];
  const float* td_scale= (const float*)d_in[31];

  float* ws = (float*)d_ws;
  size_t off = 0;
  auto alloc = [&](size_t n){ float* p = ws + off; off += (n + 3) & ~(size_t)3; return p; };
  float* stats = alloc(16384);
  float* e_tam = alloc(4096);
  float* attn_t= alloc(4096);
  float* wTce  = alloc(256);
  unsigned short* Wp1  = (unsigned short*)alloc(24576);
  unsigned short* Wp2  = (unsigned short*)alloc(6144);
  unsigned short* Wpt  = (unsigned short*)alloc(6144);
  unsigned short* Wpc  = (unsigned short*)alloc(73728);
  unsigned short* Wpte = (unsigned short*)alloc(2048);
  float* xm    = alloc(331776);
  float* pp    = alloc(12800);
  float* pf    = alloc(12800);
  float* yb    = alloc(12800);
  float* kb    = alloc(3200);
  float* vb    = alloc(12800);
  float* KWb   = alloc(12800);
  float* sbb   = alloc(256);
  float* yc    = alloc(331776);
  float* e_cam = alloc(1024);
  float* A     = alloc(5308416);   // conv1(x1) f32
  float* Bb    = alloc(5308416);   // conv1(x2) f32
  float* PTEf  = alloc(5308416);   // bf16 of BN'd xt1, [b][32][1296][64]
  float* COMB  = alloc(31850496);  // overlaid region

  // COMB overlays (float offsets):
  unsigned short* P0 = (unsigned short*)COMB;                   // [0..21.2M) input bf16
  float* Cc = COMB + 21233664;                                  // [21.2..31.85M) xt1 f32
  float* Dd = COMB;                                             // [0..10.6M) xt2 raw f32
  unsigned short* Dbf  = (unsigned short*)(COMB + 10616832);    // [10.6..15.9M) xt2 bf16
  unsigned short* PTAM = (unsigned short*)(COMB + 15925248);    // [15.9..21.2M) tam out bf16
  float* Rraw = COMB;                                           // [0..5.3M) conv raw outs
  unsigned short* PCAT1 = (unsigned short*)(COMB + 5308416);    // [5.3..13.27M)
  unsigned short* PCAT2 = (unsigned short*)(COMB + 13271040);   // [13.27..21.2M)
  unsigned short* PG    = (unsigned short*)(COMB + 21233664);   // [21.2..23.9M)
  unsigned short* PTE = (unsigned short*)PTEf;

  k_zero<<<dim3(80), 256, 0, stream>>>(stats, 20480);

  // weight prep
  k_wtrans<<<dim3(1), 256, 0, stream>>>(ce_w, wTce, 4, 64, 1);
  k_wpack<<<dim3(192), 256, 0, stream>>>(w_conv1, Wp1, 64, 256, 3);
  k_wpack<<<dim3(48),  256, 0, stream>>>(w_conv2, Wp2, 64, 64, 3);
  k_wpack<<<dim3(48),  256, 0, stream>>>(w_tam,  Wpt, 64, 64, 3);
  k_wpack<<<dim3(576), 256, 0, stream>>>(w_cat,  Wpc, 256, 192, 3);
  k_wpack<<<dim3(16),  256, 0, stream>>>(te_w,   Wpte, 64, 64, 1);

  // inputs -> P0 bf16 transposed (planes 0-15: x1, 16-31: x2)
  k_convT<<<dim3(81, 1, 4), 256, 0, stream>>>(x1, P0, 256, Nn, 32, 0);
  k_convT<<<dim3(81, 1, 4), 256, 0, stream>>>(x2, P0, 256, Nn, 32, 16);

  const float invc16 = 1.f/(4.f*20736.f);
  const float invc32 = 1.f/(4.f*41472.f);

  auto bnstats = [&](float* base, int C, int L, int slot){
    k_bnstats<<<dim3(16, C), 256, 0, stream>>>(base, 4, C, L, (long)C*L, (long)L,
                                               stats + (size_t)slot*512);
  };
  auto bnrelu = [&](float* base, int C, int L, int slot, const float* g, const float* bt,
                    float invc){
    k_bnrelu<<<dim3((L+255)/256, C, 4), 256, 0, stream>>>(base, C, L, (long)C*L, (long)L,
                                               stats + (size_t)slot*512, g, bt, invc);
  };

  // conv1 x1 -> A ; conv1 x2 -> Bb ; conv1 concat -> Cc
  k_mfconv<<<dim3(7,16,4), 256, 0, stream>>>(P0, Wp1, A, 256, 64, 1, 16, 1, 3, 1, 0, 0, 16, 32);
  bnstats(A, 64, Nn, 0); bnrelu(A, 64, Nn, 0, g_conv1, b_conv1, invc16);
  k_mfconv<<<dim3(7,16,4), 256, 0, stream>>>(P0, Wp1, Bb, 256, 64, 1, 16, 1, 3, 1, 16, 16, 32, 32);
  bnstats(Bb, 64, Nn, 1); bnrelu(Bb, 64, Nn, 1, g_conv1, b_conv1, invc16);
  k_mfconv<<<dim3(7,32,4), 256, 0, stream>>>(P0, Wp1, Cc, 256, 64, 1, 32, 1, 3, 1, 0, 0, 32, 32);
  bnstats(Cc, 64, N2, 2); bnrelu(Cc, 64, N2, 2, g_conv1, b_conv1, invc32);

  // xt2 = pw_bn_relu(xt1, te_w): Cc -> PTE -> te GEMM -> Dd raw -> Dbf bf16
  k_convT<<<dim3(162, 1, 4), 256, 0, stream>>>(Cc, PTE, 64, N2, 32, 0);
  k_mfconv<<<dim3(7,32,4), 256, 0, stream>>>(PTE, Wpte, Dd, 64, 64, 1, 32, 1, 1, 0, 0, 0, 32, 32);
  bnstats(Dd, 64, N2, 3);
  k_bnT<<<dim3(162,1,4), 256, 0, stream>>>(Dd, stats + 3*512, te_g, te_b, invc32,
                                           Dbf, nullptr, N2, 64, 0);

  // TAM
  k_tamenergy_mf<<<dim3(81, 1, 4), 256, 0, stream>>>(PTE, Dbf, e_tam);
  k_tamsoftmax<<<dim3(1), 128, 0, stream>>>(e_tam, attn_t);
  k_tamapply_mf<<<dim3(162, 1, 4), 256, 0, stream>>>(Cc, Dbf, attn_t, td_scale, PTAM);
  k_mfconv<<<dim3(7,16,4), 256, 0, stream>>>(PTAM, Wpt, Rraw, 64, 64, 1, 16, 2, 3, 1, 0, 0, 32, 32);
  bnstats(Rraw, 64, Nn, 4);
  k_bnT<<<dim3(81,1,4), 256, 0, stream>>>(Rraw, stats + 4*512, g_tam, b_tam, invc16,
                                          PCAT1, PCAT2, Nn, 192, 128);

  // PAM encoder chain
  auto pam_enc = [&](const float* xin, int slotbase){
    k_meanT<<<dim3(6, 64, 4), 256, 0, stream>>>(xin, xm);
    k_pool<<<dim3(1, 64, 4), 64, 0, stream>>>(xm, pp);
    k_pemm<<<dim3(50, 1, 4), 64, 0, stream>>>(pp, pe_w, pf);
    const int ss[4] = {1,2,3,6}; const int so[4] = {0,1,5,14};
    for (int i = 0; i < 4; ++i){
      int s2 = ss[i]*ss[i];
      float* sums = stats + (size_t)(slotbase+i)*512;
      k_bnstats<<<dim3(1, 64), 256, 0, stream>>>(pf + so[i], 4, 64, s2, 3200L, 50L, sums);
      k_bnrelu<<<dim3(1, 64, 4), 256, 0, stream>>>(pf + so[i], 64, s2, 3200L, 50L,
                                                   sums, pe_g + i*64, pe_b + i*64,
                                                   1.f/(4.f*(float)s2));
    }
    k_ytrans<<<dim3(50, 1, 4), 64, 0, stream>>>(pf, yb);
    k_pamkv<<<dim3(50, 1, 4), 128, 0, stream>>>(yb, pd_wk, pd_bk, pd_wv, pd_bv, kb, vb);
    k_kw<<<dim3(1, 1, 4), 256, 0, stream>>>(kb, pd_wq, pd_bq, KWb, sbb);
  };

  // PAM x1 -> PG -> conv2 -> PCAT1[0:64]
  pam_enc(A, 5);
  k_pamattn<<<dim3(81, 1, 4), 256, 0, stream>>>(A, KWb, sbb, vb, pd_scale, PG);
  k_mfconv<<<dim3(7,16,4), 256, 0, stream>>>(PG, Wp2, Rraw, 64, 64, 1, 16, 1, 3, 1, 0, 0, 16, 16);
  bnstats(Rraw, 64, Nn, 13);
  k_bnT<<<dim3(81,1,4), 256, 0, stream>>>(Rraw, stats + 13*512, g_conv2, b_conv2, invc16,
                                          PCAT1, nullptr, Nn, 192, 0);
  // PAM x2 -> PCAT2[0:64]
  pam_enc(Bb, 9);
  k_pamattn<<<dim3(81, 1, 4), 256, 0, stream>>>(Bb, KWb, sbb, vb, pd_scale, PG);
  k_mfconv<<<dim3(7,16,4), 256, 0, stream>>>(PG, Wp2, Rraw, 64, 64, 1, 16, 1, 3, 1, 0, 0, 16, 16);
  bnstats(Rraw, 64, Nn, 14);
  k_bnT<<<dim3(81,1,4), 256, 0, stream>>>(Rraw, stats + 14*512, g_conv2, b_conv2, invc16,
                                          PCAT2, nullptr, Nn, 192, 0);

  // CAM
  auto cam = [&](const float* xin, unsigned short* catp, int slot_ce, int slot_c2){
    k_tconv<<<dim3(6, 16, 4), dim3(4, 64), 0, stream>>>(xin, nullptr, 16, 16, wTce, yc,
                                                        64, 4, 16, 16, 1, 1, 0, 4, 0, 1);
    k_bnstats<<<dim3(16, 4), 256, 0, stream>>>(yc, 4, 4, Nn, 4L*Nn, (long)Nn,
                                               stats + (size_t)slot_ce*512);
    k_bnrelu<<<dim3((Nn+255)/256, 4, 4), 256, 0, stream>>>(yc, 4, Nn, 4L*Nn, (long)Nn,
                                               stats + (size_t)slot_ce*512, ce_g, ce_b, invc16);
    k_camenergy<<<dim3(1, 64, 4), 256, 0, stream>>>(xin, yc, e_cam);
    k_camapplyT<<<dim3(81, 1, 4), 256, 0, stream>>>(xin, yc, e_cam, cd_scale, PG);
    k_mfconv<<<dim3(7,16,4), 256, 0, stream>>>(PG, Wp2, Rraw, 64, 64, 1, 16, 1, 3, 1, 0, 0, 16, 16);
    bnstats(Rraw, 64, Nn, slot_c2);
    k_bnT<<<dim3(81,1,4), 256, 0, stream>>>(Rraw, stats + (size_t)slot_c2*512,
                                            g_conv2, b_conv2, invc16,
                                            catp, nullptr, Nn, 192, 64);
  };
  cam(A,  PCAT2, 15, 17);  // x1_ca -> PCAT2[64:128]
  cam(Bb, PCAT1, 16, 18);  // x2_ca -> PCAT1[64:128]

  // final cat convs -> d_out
  float* out1 = (float*)d_out;
  float* out2 = out1 + (size_t)4*256*Nn;
  k_mfconv<<<dim3(7,16,16), 256, 0, stream>>>(PCAT1, Wpc, out1, 192, 256, 4, 16, 1, 3, 1, 0, 0, 16, 16);
  bnstats(out1, 256, Nn, 19); bnrelu(out1, 256, Nn, 19, g_cat, b_cat, invc16);
  k_mfconv<<<dim3(7,16,16), 256, 0, stream>>>(PCAT2, Wpc, out2, 192, 256, 4, 16, 1, 3, 1, 0, 0, 16, 16);
  bnstats(out2, 256, Nn, 20); bnrelu(out2, 256, Nn, 20, g_cat, b_cat, invc16);
}

// Round 5
// 1375.505 us; speedup vs baseline: 6.0968x; 1.0458x over previous
//
#include <hip/hip_runtime.h>

#define HW 1296
#define HW4 324
#define Tt 16
#define T2 32
#define Nn 20736
#define N2 41472
#define TAPAD 72

typedef short bf16x8 __attribute__((ext_vector_type(8)));
typedef float f32x4 __attribute__((ext_vector_type(4)));

__device__ inline unsigned short f2b(float f){
  union { float f; unsigned u; } v; v.f = f;
  unsigned r = v.u + 0x7FFF + ((v.u >> 16) & 1);
  return (unsigned short)(r >> 16);
}
__device__ inline float b2f_lo(unsigned u){
  union { unsigned u; float f; } v; v.u = u << 16; return v.f;
}
__device__ inline float b2f_hi(unsigned u){
  union { unsigned u; float f; } v; v.u = u & 0xffff0000u; return v.f;
}

// pack 64 floats -> 32 uints of bf16 pairs
__device__ __forceinline__ void pack_pairs(const float* a, unsigned* vals){
  #pragma unroll
  for (int i = 0; i < 32; ++i)
    vals[i] = (unsigned)f2b(a[2*i]) | ((unsigned)f2b(a[2*i+1]) << 16);
}

// LDS-transpose staged coalesced write (256 threads, each owns a 64-bf16 row)
__device__ __forceinline__ void staged_write(unsigned* lds, int tid, const unsigned* vals,
                                             uint4* o4, size_t R0, int rowu4, int cw,
                                             uint4* o4b){
  #pragma unroll
  for (int i = 0; i < 32; ++i) lds[tid*33 + i] = vals[i];
  __syncthreads();
  #pragma unroll
  for (int k = 0; k < 8; ++k){
    int j = k*256 + tid;
    int nn = j >> 3, w = j & 7;
    int base = nn*33 + w*4;
    uint4 v;
    v.x = lds[base]; v.y = lds[base+1]; v.z = lds[base+2]; v.w = lds[base+3];
    size_t oidx = (R0 + (size_t)nn)*(size_t)rowu4 + cw + w;
    o4[oidx] = v;
    if (o4b) o4b[oidx] = v;
  }
  __syncthreads();
}

// ---------------- utility kernels ----------------

__global__ void k_zero(float* p, int n){
  int i = blockIdx.x*blockDim.x + threadIdx.x;
  if (i < n) p[i] = 0.f;
}

__global__ void k_wtrans(const float* __restrict__ w, float* __restrict__ wT,
                         int Cout, int Cin, int KT){
  int idx = blockIdx.x*blockDim.x + threadIdx.x;
  int tot = Cout*Cin*KT;
  if (idx >= tot) return;
  int o  = idx / (Cin*KT);
  int r  = idx % (Cin*KT);
  int i  = r / KT;
  int dt = r % KT;
  wT[((size_t)dt*Cin + i)*Cout + o] = w[idx];
}

// pack conv weights (Cout,Cin,KT) f32 -> MFMA A-frag order bf16
__global__ void k_wpack(const float* __restrict__ w, unsigned short* __restrict__ wp,
                        int Cout, int Cin, int KT){
  int e = blockIdx.x*256 + threadIdx.x;
  int tot = Cout*Cin*KT;
  if (e >= tot) return;
  int Kt32 = (Cin*KT) >> 5;
  int j    = e & 7;
  int lane = (e >> 3) & 63;
  int rest = e >> 9;
  int ks   = rest % Kt32;
  int mt   = rest / Kt32;
  int m  = mt*16 + (lane & 15);
  int k  = ks*32 + (lane >> 4)*8 + j;
  int dt = k / Cin, ci = k - dt*Cin;
  wp[e] = f2b(w[((size_t)m*Cin + ci)*KT + dt]);
}

// f32 [b][C][L] -> bf16 P-layout [b][plane][hw][C], staged coalesced writes
__global__ void k_convT(const float* __restrict__ x, unsigned short* __restrict__ Pb,
                        int C, int L, int PT, int p0){
  __shared__ unsigned lds[8448];
  int tid = threadIdx.x, b = blockIdx.z;
  int n0 = blockIdx.x*256, n = n0 + tid;
  const float* xb = x + (size_t)b*C*L + n;
  size_t R0 = (size_t)(b*PT + p0)*1296 + n0;
  int rowu4 = C >> 3;
  uint4* o4 = (uint4*)Pb;
  for (int c0 = 0; c0 < C; c0 += 64){
    float a[64];
    #pragma unroll
    for (int c = 0; c < 64; ++c) a[c] = xb[(size_t)(c0 + c)*L];
    unsigned vals[32];
    pack_pairs(a, vals);
    staged_write(lds, tid, vals, o4, R0, rowu4, c0 >> 3, nullptr);
  }
}

// ---------------- MFMA conv-as-GEMM ----------------
__launch_bounds__(256)
__global__ void k_mfconv(const unsigned short* __restrict__ P, const unsigned short* __restrict__ Wp,
                         float* __restrict__ out, int Cin, int Cout, int Mz,
                         int Tout, int stride, int KT, int pad, int p0, int plo, int phi, int PT)
{
  int bz = blockIdx.z; int b = bz / Mz; int mz = bz - b*Mz;
  int lane = threadIdx.x & 63;
  int tile = blockIdx.x*4 + (threadIdx.x >> 6);
  if (tile >= 27) return;
  int t = blockIdx.y;
  int col = lane & 15, grp = lane >> 4;
  int hw0 = tile*48 + col;
  int Kt32 = (KT*Cin) >> 5;
  f32x4 acc[4][3];
  #pragma unroll
  for (int i = 0; i < 4; ++i)
    #pragma unroll
    for (int j = 0; j < 3; ++j) acc[i][j] = (f32x4){0.f, 0.f, 0.f, 0.f};
  const unsigned short* wbase = Wp + ((size_t)(mz*4)*Kt32)*512 + lane*8;
  for (int dt = 0; dt < KT; ++dt){
    int p = t*stride + dt - pad + p0;
    if (p < plo || p >= phi) continue;
    const unsigned short* Pp = P + ((size_t)(b*PT + p)*1296 + hw0)*Cin + grp*8;
    int nCk = Cin >> 5;
    int ksg = (dt*Cin) >> 5;
    for (int kc = 0; kc < nCk; ++kc){
      bf16x8 bf0 = *(const bf16x8*)(Pp + (size_t)0*Cin  + kc*32);
      bf16x8 bf1 = *(const bf16x8*)(Pp + (size_t)16*Cin + kc*32);
      bf16x8 bf2 = *(const bf16x8*)(Pp + (size_t)32*Cin + kc*32);
      #pragma unroll
      for (int mf = 0; mf < 4; ++mf){
        bf16x8 af = *(const bf16x8*)(wbase + ((size_t)mf*Kt32 + ksg + kc)*512);
        acc[mf][0] = __builtin_amdgcn_mfma_f32_16x16x32_bf16(af, bf0, acc[mf][0], 0, 0, 0);
        acc[mf][1] = __builtin_amdgcn_mfma_f32_16x16x32_bf16(af, bf1, acc[mf][1], 0, 0, 0);
        acc[mf][2] = __builtin_amdgcn_mfma_f32_16x16x32_bf16(af, bf2, acc[mf][2], 0, 0, 0);
      }
    }
  }
  size_t cs = (size_t)Tout*1296;
  size_t obase = ((size_t)(b*Cout + mz*64 + grp*4))*cs + (size_t)t*1296;
  #pragma unroll
  for (int mf = 0; mf < 4; ++mf)
    #pragma unroll
    for (int f = 0; f < 3; ++f){
      int hw = tile*48 + f*16 + col;
      #pragma unroll
      for (int r = 0; r < 4; ++r)
        out[obase + (size_t)(mf*16 + r)*cs + hw] = acc[mf][f][r];
    }
}

// ---------------- naive temporal conv (kept only for ce pw 64->4) ----------------
__global__ void k_tconv(const float* __restrict__ xA, const float* __restrict__ xB,
                        int t_split, int Tpart,
                        const float* __restrict__ wT,
                        float* __restrict__ out,
                        int Cin, int Cout, int Tin, int Tout, int stride, int KT, int pad,
                        int out_cstride, int out_coff, int OC)
{
  int b  = blockIdx.z / OC;
  int oc = blockIdx.z % OC;
  int o  = oc*blockDim.x + threadIdx.x;
  int t  = blockIdx.y;
  int hw4 = blockIdx.x*blockDim.y + threadIdx.y;
  if (hw4 >= HW4) return;
  float4 acc = make_float4(0.f,0.f,0.f,0.f);
  for (int dt = 0; dt < KT; ++dt){
    int tt = t*stride + dt - pad;
    if (tt < 0 || tt >= Tin) continue;
    const float* xp = (tt < t_split) ? xA : xB;
    int tl = (tt < t_split) ? tt : (tt - t_split);
    const float4* xr = (const float4*)xp + ((size_t)b*Cin*Tpart + tl)*HW4 + hw4;
    const float* wp  = wT + (size_t)dt*Cin*Cout + o;
    size_t xstep = (size_t)Tpart*HW4;
    for (int i = 0; i < Cin; ++i){
      float4 xv = *xr;
      float  wv = *wp;
      acc.x = fmaf(wv, xv.x, acc.x);
      acc.y = fmaf(wv, xv.y, acc.y);
      acc.z = fmaf(wv, xv.z, acc.z);
      acc.w = fmaf(wv, xv.w, acc.w);
      xr += xstep; wp += Cout;
    }
  }
  float4* op = (float4*)out + ((size_t)(b*out_cstride + out_coff + o)*Tout + t)*HW4 + hw4;
  *op = acc;
}

// ---------------- BN ----------------

__global__ void k_bnstats(const float* __restrict__ x, int Bn, int Cn, int L,
                          long bstride, long cstride, float* __restrict__ sums)
{
  int c = blockIdx.y;
  int tid = threadIdx.x;
  float s = 0.f, sq = 0.f;
  int tot = Bn*L;
  for (int idx = blockIdx.x*blockDim.x + tid; idx < tot; idx += gridDim.x*blockDim.x){
    int b = idx / L; int l = idx - b*L;
    float v = x[(size_t)b*bstride + (size_t)c*cstride + l];
    s += v; sq += v*v;
  }
  __shared__ float r1[256], r2[256];
  r1[tid] = s; r2[tid] = sq; __syncthreads();
  for (int k = 128; k > 0; k >>= 1){
    if (tid < k){ r1[tid] += r1[tid+k]; r2[tid] += r2[tid+k]; }
    __syncthreads();
  }
  if (tid == 0){ atomicAdd(&sums[c], r1[0]); atomicAdd(&sums[Cn+c], r2[0]); }
}

__global__ void k_bnrelu(float* __restrict__ x, int Cn, int L, long bstride, long cstride,
                         const float* __restrict__ sums, const float* __restrict__ g,
                         const float* __restrict__ bet, float invc)
{
  int c = blockIdx.y, b = blockIdx.z;
  int l = blockIdx.x*blockDim.x + threadIdx.x;
  if (l >= L) return;
  float m  = sums[c]*invc;
  float v  = fmaxf(sums[Cn+c]*invc - m*m, 0.f);
  float sc = g[c]*rsqrtf(v + 1e-5f);
  float bb = bet[c] - m*sc;
  size_t idx = (size_t)b*bstride + (size_t)c*cstride + l;
  float val = fmaf(x[idx], sc, bb);
  x[idx] = fmaxf(val, 0.f);
}

// BN+ReLU on raw f32 [b][64][L] -> bf16 P layout rows [b][n][outC] at coff (staged writes)
__global__ void k_bnT(const float* __restrict__ x, const float* __restrict__ sums,
                      const float* __restrict__ g, const float* __restrict__ bet, float invc,
                      unsigned short* __restrict__ P1, unsigned short* __restrict__ P2,
                      int L, int outC, int coff)
{
  __shared__ unsigned lds[8448];
  int tid = threadIdx.x, b = blockIdx.z;
  int n0 = blockIdx.x*256, n = n0 + tid;
  const float* xb = x + (size_t)b*64*L + n;
  float a[64];
  #pragma unroll
  for (int c = 0; c < 64; ++c){
    float m  = sums[c]*invc;
    float vv = fmaxf(sums[64+c]*invc - m*m, 0.f);
    float sc = g[c]*rsqrtf(vv + 1e-5f);
    float bb = bet[c] - m*sc;
    a[c] = fmaxf(fmaf(xb[(size_t)c*L], sc, bb), 0.f);
  }
  unsigned vals[32];
  pack_pairs(a, vals);
  staged_write(lds, tid, vals, (uint4*)P1, (size_t)b*L + n0, outC >> 3, coff >> 3,
               P2 ? (uint4*)P2 : nullptr);
}

// ---------------- PAM encoder ----------------

__global__ void k_meanT(const float* __restrict__ x, float* __restrict__ xm){
  int c = blockIdx.y, b = blockIdx.z;
  int hw = blockIdx.x*blockDim.x + threadIdx.x;
  if (hw >= HW) return;
  const float* xp = x + ((size_t)(b*64+c)*Tt)*HW + hw;
  float s = 0.f;
  for (int t = 0; t < Tt; ++t) s += xp[(size_t)t*HW];
  xm[(size_t)(b*64+c)*HW + hw] = s*(1.f/16.f);
}

__global__ void k_pool(const float* __restrict__ xm, float* __restrict__ pp){
  int c = blockIdx.y, b = blockIdx.z;
  int cell = threadIdx.x;
  if (cell >= 50) return;
  int s, off;
  if (cell < 1){ s=1; off=0; } else if (cell < 5){ s=2; off=1; }
  else if (cell < 14){ s=3; off=5; } else { s=6; off=14; }
  int local = cell - off, ph = local/s, pw = local%s, bh = 36/s;
  const float* xp = xm + (size_t)(b*64+c)*HW;
  float sum = 0.f;
  for (int h = ph*bh; h < (ph+1)*bh; ++h)
    for (int w = pw*bh; w < (pw+1)*bh; ++w) sum += xp[h*36 + w];
  pp[(size_t)(b*64+c)*50 + cell] = sum / (float)(bh*bh);
}

__global__ void k_pemm(const float* __restrict__ pp, const float* __restrict__ pew,
                       float* __restrict__ pf){
  int cell = blockIdx.x, b = blockIdx.z;
  int o = threadIdx.x;  // 64
  int sc;
  if (cell < 1) sc=0; else if (cell < 5) sc=1; else if (cell < 14) sc=2; else sc=3;
  const float* w = pew + (size_t)sc*4096 + o*64;
  const float* p = pp + (size_t)b*3200 + cell;
  float s = 0.f;
  for (int i = 0; i < 64; ++i) s = fmaf(w[i], p[(size_t)i*50], s);
  pf[(size_t)(b*64+o)*50 + cell] = s;
}

__global__ void k_ytrans(const float* __restrict__ pf, float* __restrict__ y){
  int k = blockIdx.x, b = blockIdx.z; int c = threadIdx.x;
  y[((size_t)b*50 + k)*64 + c] = pf[((size_t)b*64 + c)*50 + k];
}

__global__ void k_pamkv(const float* __restrict__ y, const float* __restrict__ wk,
                        const float* __restrict__ bk, const float* __restrict__ wv,
                        const float* __restrict__ bv,
                        float* __restrict__ kb, float* __restrict__ vb){
  int kk = blockIdx.x, b = blockIdx.z; int t = threadIdx.x;
  const float* yp = y + ((size_t)b*50 + kk)*64;
  if (t < 16){
    float s = bk[t]; const float* w = wk + t*64;
    for (int i = 0; i < 64; ++i) s = fmaf(w[i], yp[i], s);
    kb[((size_t)b*50 + kk)*16 + t] = s;
  } else if (t < 80){
    int c = t - 16;
    float s = bv[c]; const float* w = wv + c*64;
    for (int i = 0; i < 64; ++i) s = fmaf(w[i], yp[i], s);
    vb[((size_t)b*50 + kk)*64 + c] = s;
  }
}

// KW[b][k][c] = sum_o kb[b][k][o] * wq[o][c];  sb[b][k] = sum_o kb[b][k][o]*bq[o]
__global__ void k_kw(const float* __restrict__ kb, const float* __restrict__ wq,
                     const float* __restrict__ bq,
                     float* __restrict__ KW, float* __restrict__ sb){
  int b = blockIdx.z;
  int tid = threadIdx.x;
  int c = tid & 63;
  for (int k = tid >> 6; k < 50; k += 4){
    const float* kp = kb + ((size_t)b*50 + k)*16;
    float s = 0.f;
    #pragma unroll
    for (int o = 0; o < 16; ++o) s = fmaf(kp[o], wq[o*64 + c], s);
    KW[((size_t)b*50 + k)*64 + c] = s;
  }
  if (tid < 50){
    const float* kp = kb + ((size_t)b*50 + tid)*16;
    float s = 0.f;
    #pragma unroll
    for (int o = 0; o < 16; ++o) s = fmaf(kp[o], bq[o], s);
    sb[(size_t)b*50 + tid] = s;
  }
}

// scores via KW trick; softmax; PV + residual from registers; staged bf16 write
__launch_bounds__(256, 1)
__global__ void k_pamattn(const float* __restrict__ x, const float* __restrict__ KW,
                          const float* __restrict__ sbb, const float* __restrict__ vbuf,
                          const float* __restrict__ scp, unsigned short* __restrict__ Pg)
{
  __shared__ unsigned smem_u[8448];
  float* smem = (float*)smem_u;      // [0,3200) KW ; [3200,6400) v ; [6400,6450) sb
  int b = blockIdx.z, tid = threadIdx.x;
  for (int i = tid; i < 3200; i += 256){
    smem[i]        = KW[(size_t)b*3200 + i];
    smem[3200 + i] = vbuf[(size_t)b*3200 + i];
  }
  if (tid < 50) smem[6400 + tid] = sbb[(size_t)b*50 + tid];
  __syncthreads();
  int n0 = blockIdx.x*256;
  int n = n0 + tid;
  const float* xb = x + (size_t)b*64*Nn + n;
  float xv[64];
  #pragma unroll
  for (int c = 0; c < 64; ++c) xv[c] = xb[(size_t)c*Nn];
  float s[50];
  const float4* kw4 = (const float4*)smem;
  #pragma unroll
  for (int k = 0; k < 50; ++k){
    float t = smem[6400 + k];
    #pragma unroll
    for (int c4 = 0; c4 < 16; ++c4){
      float4 kw = kw4[k*16 + c4];
      t = fmaf(xv[c4*4+0], kw.x, t);
      t = fmaf(xv[c4*4+1], kw.y, t);
      t = fmaf(xv[c4*4+2], kw.z, t);
      t = fmaf(xv[c4*4+3], kw.w, t);
    }
    s[k] = t;
  }
  float mx = -1e30f;
  #pragma unroll
  for (int k = 0; k < 50; ++k) mx = fmaxf(mx, s[k]);
  float sum = 0.f;
  #pragma unroll
  for (int k = 0; k < 50; ++k){ float p = __expf(s[k]-mx); s[k] = p; sum += p; }
  float sc = scp[0]/sum;
  const float4* vl4 = (const float4*)(smem + 3200);
  #pragma unroll
  for (int k = 0; k < 50; ++k){
    float pk = sc * s[k];
    #pragma unroll
    for (int c4 = 0; c4 < 16; ++c4){
      float4 v = vl4[k*16 + c4];
      xv[c4*4+0] = fmaf(pk, v.x, xv[c4*4+0]);
      xv[c4*4+1] = fmaf(pk, v.y, xv[c4*4+1]);
      xv[c4*4+2] = fmaf(pk, v.z, xv[c4*4+2]);
      xv[c4*4+3] = fmaf(pk, v.w, xv[c4*4+3]);
    }
  }
  __syncthreads();
  unsigned vals[32];
  pack_pairs(xv, vals);
  staged_write(smem_u, tid, vals, (uint4*)Pg, (size_t)b*Nn + n0, 8, 0, nullptr);
}

// ---------------- CAM ----------------

// e[(b*64+c)*4+ks] += sum over n-chunk of x[c][n]*y[ks][n]  (e pre-zeroed)
__global__ void k_camenergy2(const float* __restrict__ x, const float* __restrict__ yc,
                             float* __restrict__ e){
  __shared__ float yl[4][256];
  int b = blockIdx.z, tid = threadIdx.x;
  int n0 = blockIdx.x*256;
  #pragma unroll
  for (int k = 0; k < 4; ++k)
    yl[k][tid] = yc[((size_t)b*4+k)*Nn + n0 + tid];
  __syncthreads();
  int c = tid & 63, ks = tid >> 6;
  const float* xr = x + (size_t)(b*64+c)*Nn + n0;
  const float* yr = yl[ks];
  float acc = 0.f;
  #pragma unroll 8
  for (int i = 0; i < 256; ++i) acc = fmaf(xr[i], yr[i], acc);
  atomicAdd(&e[((size_t)(b*64)+c)*4 + ks], acc);
}

__global__ void k_camapplyT(const float* __restrict__ x, const float* __restrict__ yc,
                            const float* __restrict__ e, const float* __restrict__ scp,
                            unsigned short* __restrict__ Pg){
  __shared__ float pw[64][4];
  __shared__ unsigned lds[8448];
  int tid = threadIdx.x;
  int b = blockIdx.z;
  if (tid < 64){
    const float* er = e + (size_t)(b*64+tid)*4;
    float e0=er[0], e1=er[1], e2=er[2], e3=er[3];
    float mx = fmaxf(fmaxf(e0,e1), fmaxf(e2,e3));
    float z0=mx-e0, z1=mx-e1, z2=mx-e2, z3=mx-e3;
    float zm = fmaxf(fmaxf(z0,z1), fmaxf(z2,z3));
    float p0=__expf(z0-zm), p1=__expf(z1-zm), p2=__expf(z2-zm), p3=__expf(z3-zm);
    float inv = 1.f/(p0+p1+p2+p3);
    pw[tid][0]=p0*inv; pw[tid][1]=p1*inv; pw[tid][2]=p2*inv; pw[tid][3]=p3*inv;
  }
  __syncthreads();
  int n0 = blockIdx.x*256;
  int n = n0 + tid;
  float y0 = yc[((size_t)b*4+0)*Nn + n];
  float y1 = yc[((size_t)b*4+1)*Nn + n];
  float y2 = yc[((size_t)b*4+2)*Nn + n];
  float y3 = yc[((size_t)b*4+3)*Nn + n];
  float sc = scp[0];
  const float* xb = x + (size_t)b*64*Nn + n;
  float a[64];
  #pragma unroll
  for (int c = 0; c < 64; ++c){
    a[c] = fmaf(sc, pw[c][0]*y0 + pw[c][1]*y1 + pw[c][2]*y2 + pw[c][3]*y3,
                xb[(size_t)c*Nn]);
  }
  unsigned vals[32];
  pack_pairs(a, vals);
  staged_write(lds, tid, vals, (uint4*)Pg, (size_t)b*Nn + n0, 8, 0, nullptr);
}

// ---------------- TAM (MFMA energy + LDS-tiled apply) ----------------

__launch_bounds__(256)
__global__ void k_tamenergy_mf(const unsigned short* __restrict__ X,
                               const unsigned short* __restrict__ Y,
                               float* __restrict__ E){
  int b = blockIdx.z;
  int wave = threadIdx.x >> 6, lane = threadIdx.x & 63;
  int r = lane & 15, g = lane >> 4;
  const unsigned short* Xb = X + (size_t)b*32*82944;
  const unsigned short* Yb = Y + (size_t)b*32*82944;
  f32x4 a00 = (f32x4){0.f,0.f,0.f,0.f};
  f32x4 a01 = a00, a10 = a00, a11 = a00;
  int c0 = (blockIdx.x*4 + wave)*8;
  for (int cc = 0; cc < 8; ++cc){
    size_t k0 = (size_t)(c0 + cc)*32 + (size_t)g*8;
    bf16x8 x0 = *(const bf16x8*)(Xb + (size_t)r*82944 + k0);
    bf16x8 x1 = *(const bf16x8*)(Xb + (size_t)(r+16)*82944 + k0);
    bf16x8 y0 = *(const bf16x8*)(Yb + (size_t)r*82944 + k0);
    bf16x8 y1 = *(const bf16x8*)(Yb + (size_t)(r+16)*82944 + k0);
    a00 = __builtin_amdgcn_mfma_f32_16x16x32_bf16(x0, y0, a00, 0, 0, 0);
    a01 = __builtin_amdgcn_mfma_f32_16x16x32_bf16(x0, y1, a01, 0, 0, 0);
    a10 = __builtin_amdgcn_mfma_f32_16x16x32_bf16(x1, y0, a10, 0, 0, 0);
    a11 = __builtin_amdgcn_mfma_f32_16x16x32_bf16(x1, y1, a11, 0, 0, 0);
  }
  float* Eb = E + (size_t)b*1024;
  #pragma unroll
  for (int rr = 0; rr < 4; ++rr){
    int row = g*4 + rr;
    atomicAdd(&Eb[row*32 + r],           a00[rr]);
    atomicAdd(&Eb[row*32 + 16 + r],      a01[rr]);
    atomicAdd(&Eb[(row+16)*32 + r],      a10[rr]);
    atomicAdd(&Eb[(row+16)*32 + 16 + r], a11[rr]);
  }
}

__global__ void k_tamsoftmax(const float* __restrict__ e, float* __restrict__ at){
  int tid = threadIdx.x; if (tid >= 128) return;
  int b = tid >> 5, i = tid & 31;
  const float* er = e + ((size_t)b*32 + i)*32;
  float mx = -1e30f;
  for (int j = 0; j < 32; ++j) mx = fmaxf(mx, er[j]);
  float mn = 1e30f;
  for (int j = 0; j < 32; ++j) mn = fminf(mn, er[j]);
  float zmax = mx - mn;
  float sum = 0.f;
  float* ar = at + ((size_t)b*32 + i)*32;
  for (int j = 0; j < 32; ++j){ float p = __expf((mx - er[j]) - zmax); ar[j] = p; sum += p; }
  float inv = 1.f/sum;
  for (int j = 0; j < 32; ++j) ar[j] *= inv;
}

// out_P[n][c] = bf16( X_P[n][c] + sc * sum_j attn[t][j]*Y[j][hw][c] ), n = t*1296+hw
// Y tile (all 32 j x 8 hw x 64 c) staged in LDS with 144B padded rows (conflict-free).
__launch_bounds__(256)
__global__ void k_tamapply_mf(const unsigned short* __restrict__ Xbf,
                              const unsigned short* __restrict__ Ybf,
                              const float* __restrict__ at, const float* __restrict__ scp,
                              unsigned short* __restrict__ Pout){
  __shared__ unsigned short yl[32*8*TAPAD];
  __shared__ float al[1024];
  int b = blockIdx.z, tid = threadIdx.x;
  int hw0 = blockIdx.x*8;
  for (int i = tid; i < 1024; i += 256) al[i] = at[(size_t)b*1024 + i];
  const uint4* src = (const uint4*)Ybf + (size_t)b*N2*8;
  #pragma unroll
  for (int it = 0; it < 8; ++it){
    int idx = it*256 + tid;
    int j = idx >> 6, rem = idx & 63, h = rem >> 3, w = rem & 7;
    uint4 v = src[(size_t)(j*1296 + hw0 + h)*8 + w];
    *(uint4*)&yl[(j*8+h)*TAPAD + w*8] = v;
  }
  __syncthreads();
  int t = tid >> 3, h = tid & 7;
  int n = t*1296 + hw0 + h;
  float sc = scp[0];
  const uint4* xr = (const uint4*)Xbf + ((size_t)b*N2 + n)*8;
  float acc[64];
  #pragma unroll
  for (int w = 0; w < 8; ++w){
    uint4 v = xr[w];
    acc[w*8+0] = b2f_lo(v.x); acc[w*8+1] = b2f_hi(v.x);
    acc[w*8+2] = b2f_lo(v.y); acc[w*8+3] = b2f_hi(v.y);
    acc[w*8+4] = b2f_lo(v.z); acc[w*8+5] = b2f_hi(v.z);
    acc[w*8+6] = b2f_lo(v.w); acc[w*8+7] = b2f_hi(v.w);
  }
  const float* ar = &al[t*32];
  for (int j = 0; j < 32; ++j){
    float aj = sc * ar[j];
    const uint4* yr = (const uint4*)&yl[(j*8+h)*TAPAD];
    #pragma unroll
    for (int w = 0; w < 8; ++w){
      uint4 v = yr[w];
      acc[w*8+0] = fmaf(aj, b2f_lo(v.x), acc[w*8+0]);
      acc[w*8+1] = fmaf(aj, b2f_hi(v.x), acc[w*8+1]);
      acc[w*8+2] = fmaf(aj, b2f_lo(v.y), acc[w*8+2]);
      acc[w*8+3] = fmaf(aj, b2f_hi(v.y), acc[w*8+3]);
      acc[w*8+4] = fmaf(aj, b2f_lo(v.z), acc[w*8+4]);
      acc[w*8+5] = fmaf(aj, b2f_hi(v.z), acc[w*8+5]);
      acc[w*8+6] = fmaf(aj, b2f_lo(v.w), acc[w*8+6]);
      acc[w*8+7] = fmaf(aj, b2f_hi(v.w), acc[w*8+7]);
    }
  }
  uint4* orow = (uint4*)Pout + ((size_t)b*N2 + n)*8;
  #pragma unroll
  for (int w = 0; w < 8; ++w){
    uint4 v;
    v.x = (unsigned)f2b(acc[w*8+0]) | ((unsigned)f2b(acc[w*8+1]) << 16);
    v.y = (unsigned)f2b(acc[w*8+2]) | ((unsigned)f2b(acc[w*8+3]) << 16);
    v.z = (unsigned)f2b(acc[w*8+4]) | ((unsigned)f2b(acc[w*8+5]) << 16);
    v.w = (unsigned)f2b(acc[w*8+6]) | ((unsigned)f2b(acc[w*8+7]) << 16);
    orow[w] = v;
  }
}

// ---------------- host ----------------

extern "C" void kernel_launch(void* const* d_in, const int* in_sizes, int n_in,
                              void* d_out, int out_size, void* d_ws, size_t ws_size,
                              hipStream_t stream) {
  const float* x1      = (const float*)d_in[0];
  const float* x2      = (const float*)d_in[1];
  const float* w_conv1 = (const float*)d_in[2];
  const float* g_conv1 = (const float*)d_in[3];
  const float* b_conv1 = (const float*)d_in[4];
  const float* w_conv2 = (const float*)d_in[5];
  const float* g_conv2 = (const float*)d_in[6];
  const float* b_conv2 = (const float*)d_in[7];
  const float* w_tam   = (const float*)d_in[8];
  const float* g_tam   = (const float*)d_in[9];
  const float* b_tam   = (const float*)d_in[10];
  const float* w_cat   = (const float*)d_in[11];
  const float* g_cat   = (const float*)d_in[12];
  const float* b_cat   = (const float*)d_in[13];
  const float* pe_w    = (const float*)d_in[14];
  const float* pe_g    = (const float*)d_in[15];
  const float* pe_b    = (const float*)d_in[16];
  const float* pd_wq   = (const float*)d_in[17];
  const float* pd_bq   = (const float*)d_in[18];
  const float* pd_wk   = (const float*)d_in[19];
  const float* pd_bk   = (const float*)d_in[20];
  const float* pd_wv   = (const float*)d_in[21];
  const float* pd_bv   = (const float*)d_in[22];
  const float* pd_scale= (const float*)d_in[23];
  const float* ce_w    = (const float*)d_in[24];
  const float* ce_g    = (const float*)d_in[25];
  const float* ce_b    = (const float*)d_in[26];
  const float* cd_scale= (const float*)d_in[27];
  const float* te_w    = (const float*)d_in[28];
  const float* te_g    = (const float*)d_in[29];
  const float* te_b    = (const float*)d_in[30];
  const float* td_scale= (const float*)d_in[31];

  float* ws = (float*)d_ws;
  size_t off = 0;
  auto alloc = [&](size_t n){ float* p = ws + off; off += (n + 3) & ~(size_t)3; return p; };
  float* stats = alloc(16384);   // 32 slots x 512
  float* e_tam = alloc(4096);
  float* e_cam = alloc(2048);    // two slots (atomic-accumulated, zeroed up front)
  float* attn_t= alloc(4096);
  float* wTce  = alloc(256);
  unsigned short* Wp1  = (unsigned short*)alloc(24576);
  unsigned short* Wp2  = (unsigned short*)alloc(6144);
  unsigned short* Wpt  = (unsigned short*)alloc(6144);
  unsigned short* Wpc  = (unsigned short*)alloc(73728);
  unsigned short* Wpte = (unsigned short*)alloc(2048);
  float* xm    = alloc(331776);
  float* pp    = alloc(12800);
  float* pf    = alloc(12800);
  float* yb    = alloc(12800);
  float* kb    = alloc(3200);
  float* vb    = alloc(12800);
  float* KWb   = alloc(12800);
  float* sbb   = alloc(256);
  float* yc    = alloc(331776);
  float* A     = alloc(5308416);   // conv1(x1) f32
  float* Bb    = alloc(5308416);   // conv1(x2) f32
  float* PTEf  = alloc(5308416);   // bf16 of BN'd xt1, [b][32][1296][64]
  float* COMB  = alloc(31850496);  // overlaid region

  // COMB overlays (float offsets):
  unsigned short* P0 = (unsigned short*)COMB;                   // [0..21.2M) input bf16
  float* Cc = COMB + 21233664;                                  // [21.2..31.85M) xt1 raw f32
  float* Dd = COMB;                                             // [0..10.6M) xt2 raw f32
  unsigned short* Dbf  = (unsigned short*)(COMB + 10616832);    // [10.6..15.9M) xt2 bf16
  unsigned short* PTAM = (unsigned short*)(COMB + 15925248);    // [15.9..21.2M) tam out bf16
  float* Rraw = COMB;                                           // [0..5.3M) conv raw outs
  unsigned short* PCAT1 = (unsigned short*)(COMB + 5308416);    // [5.3..13.27M)
  unsigned short* PCAT2 = (unsigned short*)(COMB + 13271040);   // [13.27..21.2M)
  unsigned short* PG    = (unsigned short*)(COMB + 21233664);   // [21.2..23.9M)
  unsigned short* PTE = (unsigned short*)PTEf;

  // zero stats + e_tam + e_cam (contiguous 22528 floats)
  k_zero<<<dim3(88), 256, 0, stream>>>(stats, 22528);

  // weight prep
  k_wtrans<<<dim3(1), 256, 0, stream>>>(ce_w, wTce, 4, 64, 1);
  k_wpack<<<dim3(192), 256, 0, stream>>>(w_conv1, Wp1, 64, 256, 3);
  k_wpack<<<dim3(48),  256, 0, stream>>>(w_conv2, Wp2, 64, 64, 3);
  k_wpack<<<dim3(48),  256, 0, stream>>>(w_tam,  Wpt, 64, 64, 3);
  k_wpack<<<dim3(576), 256, 0, stream>>>(w_cat,  Wpc, 256, 192, 3);
  k_wpack<<<dim3(16),  256, 0, stream>>>(te_w,   Wpte, 64, 64, 1);

  // inputs -> P0 bf16 transposed (planes 0-15: x1, 16-31: x2)
  k_convT<<<dim3(81, 1, 4), 256, 0, stream>>>(x1, P0, 256, Nn, 32, 0);
  k_convT<<<dim3(81, 1, 4), 256, 0, stream>>>(x2, P0, 256, Nn, 32, 16);

  const float invc16 = 1.f/(4.f*20736.f);
  const float invc32 = 1.f/(4.f*41472.f);

  auto bnstats = [&](float* base, int C, int L, int slot){
    k_bnstats<<<dim3(16, C), 256, 0, stream>>>(base, 4, C, L, (long)C*L, (long)L,
                                               stats + (size_t)slot*512);
  };
  auto bnrelu = [&](float* base, int C, int L, int slot, const float* g, const float* bt,
                    float invc){
    k_bnrelu<<<dim3((L+255)/256, C, 4), 256, 0, stream>>>(base, C, L, (long)C*L, (long)L,
                                               stats + (size_t)slot*512, g, bt, invc);
  };

  // conv1 x1 -> A ; conv1 x2 -> Bb ; conv1 concat -> Cc (raw)
  k_mfconv<<<dim3(7,16,4), 256, 0, stream>>>(P0, Wp1, A, 256, 64, 1, 16, 1, 3, 1, 0, 0, 16, 32);
  bnstats(A, 64, Nn, 0); bnrelu(A, 64, Nn, 0, g_conv1, b_conv1, invc16);
  k_mfconv<<<dim3(7,16,4), 256, 0, stream>>>(P0, Wp1, Bb, 256, 64, 1, 16, 1, 3, 1, 16, 16, 32, 32);
  bnstats(Bb, 64, Nn, 1); bnrelu(Bb, 64, Nn, 1, g_conv1, b_conv1, invc16);
  k_mfconv<<<dim3(7,32,4), 256, 0, stream>>>(P0, Wp1, Cc, 256, 64, 1, 32, 1, 3, 1, 0, 0, 32, 32);
  bnstats(Cc, 64, N2, 2);
  // BN+ReLU fused into bf16 transpose: raw Cc -> PTE (no separate f32 bnrelu pass)
  k_bnT<<<dim3(162,1,4), 256, 0, stream>>>(Cc, stats + 2*512, g_conv1, b_conv1, invc32,
                                           PTE, nullptr, N2, 64, 0);

  // xt2 = pw_bn_relu(xt1, te_w): PTE -> te GEMM -> Dd raw -> Dbf bf16
  k_mfconv<<<dim3(7,32,4), 256, 0, stream>>>(PTE, Wpte, Dd, 64, 64, 1, 32, 1, 1, 0, 0, 0, 32, 32);
  bnstats(Dd, 64, N2, 3);
  k_bnT<<<dim3(162,1,4), 256, 0, stream>>>(Dd, stats + 3*512, te_g, te_b, invc32,
                                           Dbf, nullptr, N2, 64, 0);

  // TAM
  k_tamenergy_mf<<<dim3(81, 1, 4), 256, 0, stream>>>(PTE, Dbf, e_tam);
  k_tamsoftmax<<<dim3(1), 128, 0, stream>>>(e_tam, attn_t);
  k_tamapply_mf<<<dim3(162, 1, 4), 256, 0, stream>>>(PTE, Dbf, attn_t, td_scale, PTAM);
  k_mfconv<<<dim3(7,16,4), 256, 0, stream>>>(PTAM, Wpt, Rraw, 64, 64, 1, 16, 2, 3, 1, 0, 0, 32, 32);
  bnstats(Rraw, 64, Nn, 4);
  k_bnT<<<dim3(81,1,4), 256, 0, stream>>>(Rraw, stats + 4*512, g_tam, b_tam, invc16,
                                          PCAT1, PCAT2, Nn, 192, 128);

  // PAM encoder chain
  auto pam_enc = [&](const float* xin, int slotbase){
    k_meanT<<<dim3(6, 64, 4), 256, 0, stream>>>(xin, xm);
    k_pool<<<dim3(1, 64, 4), 64, 0, stream>>>(xm, pp);
    k_pemm<<<dim3(50, 1, 4), 64, 0, stream>>>(pp, pe_w, pf);
    const int ss[4] = {1,2,3,6}; const int so[4] = {0,1,5,14};
    for (int i = 0; i < 4; ++i){
      int s2 = ss[i]*ss[i];
      float* sums = stats + (size_t)(slotbase+i)*512;
      k_bnstats<<<dim3(1, 64), 256, 0, stream>>>(pf + so[i], 4, 64, s2, 3200L, 50L, sums);
      k_bnrelu<<<dim3(1, 64, 4), 256, 0, stream>>>(pf + so[i], 64, s2, 3200L, 50L,
                                                   sums, pe_g + i*64, pe_b + i*64,
                                                   1.f/(4.f*(float)s2));
    }
    k_ytrans<<<dim3(50, 1, 4), 64, 0, stream>>>(pf, yb);
    k_pamkv<<<dim3(50, 1, 4), 128, 0, stream>>>(yb, pd_wk, pd_bk, pd_wv, pd_bv, kb, vb);
    k_kw<<<dim3(1, 1, 4), 256, 0, stream>>>(kb, pd_wq, pd_bq, KWb, sbb);
  };

  // PAM x1 -> PG -> conv2 -> PCAT1[0:64]
  pam_enc(A, 5);
  k_pamattn<<<dim3(81, 1, 4), 256, 0, stream>>>(A, KWb, sbb, vb, pd_scale, PG);
  k_mfconv<<<dim3(7,16,4), 256, 0, stream>>>(PG, Wp2, Rraw, 64, 64, 1, 16, 1, 3, 1, 0, 0, 16, 16);
  bnstats(Rraw, 64, Nn, 13);
  k_bnT<<<dim3(81,1,4), 256, 0, stream>>>(Rraw, stats + 13*512, g_conv2, b_conv2, invc16,
                                          PCAT1, nullptr, Nn, 192, 0);
  // PAM x2 -> PCAT2[0:64]
  pam_enc(Bb, 9);
  k_pamattn<<<dim3(81, 1, 4), 256, 0, stream>>>(Bb, KWb, sbb, vb, pd_scale, PG);
  k_mfconv<<<dim3(7,16,4), 256, 0, stream>>>(PG, Wp2, Rraw, 64, 64, 1, 16, 1, 3, 1, 0, 0, 16, 16);
  bnstats(Rraw, 64, Nn, 14);
  k_bnT<<<dim3(81,1,4), 256, 0, stream>>>(Rraw, stats + 14*512, g_conv2, b_conv2, invc16,
                                          PCAT2, nullptr, Nn, 192, 0);

  // CAM
  auto cam = [&](const float* xin, unsigned short* catp, float* ecam,
                 int slot_ce, int slot_c2){
    k_tconv<<<dim3(6, 16, 4), dim3(4, 64), 0, stream>>>(xin, nullptr, 16, 16, wTce, yc,
                                                        64, 4, 16, 16, 1, 1, 0, 4, 0, 1);
    k_bnstats<<<dim3(16, 4), 256, 0, stream>>>(yc, 4, 4, Nn, 4L*Nn, (long)Nn,
                                               stats + (size_t)slot_ce*512);
    k_bnrelu<<<dim3((Nn+255)/256, 4, 4), 256, 0, stream>>>(yc, 4, Nn, 4L*Nn, (long)Nn,
                                               stats + (size_t)slot_ce*512, ce_g, ce_b, invc16);
    k_camenergy2<<<dim3(81, 1, 4), 256, 0, stream>>>(xin, yc, ecam);
    k_camapplyT<<<dim3(81, 1, 4), 256, 0, stream>>>(xin, yc, ecam, cd_scale, PG);
    k_mfconv<<<dim3(7,16,4), 256, 0, stream>>>(PG, Wp2, Rraw, 64, 64, 1, 16, 1, 3, 1, 0, 0, 16, 16);
    bnstats(Rraw, 64, Nn, slot_c2);
    k_bnT<<<dim3(81,1,4), 256, 0, stream>>>(Rraw, stats + (size_t)slot_c2*512,
                                            g_conv2, b_conv2, invc16,
                                            catp, nullptr, Nn, 192, 64);
  };
  cam(A,  PCAT2, e_cam,        15, 17);  // x1_ca -> PCAT2[64:128]
  cam(Bb, PCAT1, e_cam + 1024, 16, 18);  // x2_ca -> PCAT1[64:128]

  // final cat convs -> d_out
  float* out1 = (float*)d_out;
  float* out2 = out1 + (size_t)4*256*Nn;
  k_mfconv<<<dim3(7,16,16), 256, 0, stream>>>(PCAT1, Wpc, out1, 192, 256, 4, 16, 1, 3, 1, 0, 0, 16, 16);
  bnstats(out1, 256, Nn, 19); bnrelu(out1, 256, Nn, 19, g_cat, b_cat, invc16);
  k_mfconv<<<dim3(7,16,16), 256, 0, stream>>>(PCAT2, Wpc, out2, 192, 256, 4, 16, 1, 3, 1, 0, 0, 16, 16);
  bnstats(out2, 256, Nn, 20); bnrelu(out2, 256, Nn, 20, g_cat, b_cat, invc16);
}

// Round 6
// 1315.634 us; speedup vs baseline: 6.3743x; 1.0455x over previous
//
#include <hip/hip_runtime.h>

#define HW 1296
#define Tt 16
#define T2 32
#define Nn 20736
#define N2 41472
#define TAPAD 72

typedef short bf16x8 __attribute__((ext_vector_type(8)));
typedef float f32x4 __attribute__((ext_vector_type(4)));

__device__ inline unsigned short f2b(float f){
  union { float f; unsigned u; } v; v.f = f;
  unsigned r = v.u + 0x7FFF + ((v.u >> 16) & 1);
  return (unsigned short)(r >> 16);
}
__device__ inline float b2f_lo(unsigned u){
  union { unsigned u; float f; } v; v.u = u << 16; return v.f;
}
__device__ inline float b2f_hi(unsigned u){
  union { unsigned u; float f; } v; v.u = u & 0xffff0000u; return v.f;
}

__device__ __forceinline__ void pack_pairs(const float* a, unsigned* vals){
  #pragma unroll
  for (int i = 0; i < 32; ++i)
    vals[i] = (unsigned)f2b(a[2*i]) | ((unsigned)f2b(a[2*i+1]) << 16);
}

// LDS-transpose staged coalesced write (256 threads, each owns a 64-bf16 row)
__device__ __forceinline__ void staged_write(unsigned* lds, int tid, const unsigned* vals,
                                             uint4* o4, size_t R0, int rowu4, int cw,
                                             uint4* o4b){
  #pragma unroll
  for (int i = 0; i < 32; ++i) lds[tid*33 + i] = vals[i];
  __syncthreads();
  #pragma unroll
  for (int k = 0; k < 8; ++k){
    int j = k*256 + tid;
    int nn = j >> 3, w = j & 7;
    int base = nn*33 + w*4;
    uint4 v;
    v.x = lds[base]; v.y = lds[base+1]; v.z = lds[base+2]; v.w = lds[base+3];
    size_t oidx = (R0 + (size_t)nn)*(size_t)rowu4 + cw + w;
    o4[oidx] = v;
    if (o4b) o4b[oidx] = v;
  }
  __syncthreads();
}

// ---------------- utility ----------------

__global__ void k_zero(float* p, int n){
  int i = blockIdx.x*blockDim.x + threadIdx.x;
  if (i < n) p[i] = 0.f;
}

__device__ __forceinline__ void wpack_one(int e, const float* w, unsigned short* wp,
                                          int Cout, int Cin, int KT){
  int Kt32 = (Cin*KT) >> 5;
  int j    = e & 7;
  int lane = (e >> 3) & 63;
  int rest = e >> 9;
  int ks   = rest % Kt32;
  int mt   = rest / Kt32;
  int m  = mt*16 + (lane & 15);
  int k  = ks*32 + (lane >> 4)*8 + j;
  int dt = k / Cin, ci = k - dt*Cin;
  wp[e] = f2b(w[((size_t)m*Cin + ci)*KT + dt]);
}

// all weight prep in one kernel
__global__ void k_wprep(const float* w1, const float* w2, const float* wt,
                        const float* wc, const float* wte, const float* wce,
                        unsigned short* Wp1, unsigned short* Wp2, unsigned short* Wpt,
                        unsigned short* Wpc, unsigned short* Wpte, float* wTce){
  int idx = blockIdx.x*256 + threadIdx.x;
  if (idx < 49152){ wpack_one(idx, w1, Wp1, 64, 256, 3); return; }
  idx -= 49152;
  if (idx < 12288){ wpack_one(idx, w2, Wp2, 64, 64, 3); return; }
  idx -= 12288;
  if (idx < 12288){ wpack_one(idx, wt, Wpt, 64, 64, 3); return; }
  idx -= 12288;
  if (idx < 147456){ wpack_one(idx, wc, Wpc, 256, 192, 3); return; }
  idx -= 147456;
  if (idx < 4096){ wpack_one(idx, wte, Wpte, 64, 64, 1); return; }
  idx -= 4096;
  if (idx < 256){  // ce wtrans: (4,64,1) -> wT[i*4+o]
    int o = idx / 64, i = idx % 64;
    wTce[i*4 + o] = wce[idx];
  }
}

// f32 [b][C][L] -> bf16 P-layout [b][plane][hw][C]
__global__ void k_convT(const float* __restrict__ x, unsigned short* __restrict__ Pb,
                        int C, int L, int PT, int p0){
  __shared__ unsigned lds[8448];
  int tid = threadIdx.x, b = blockIdx.z;
  int n0 = blockIdx.x*256, n = n0 + tid;
  const float* xb = x + (size_t)b*C*L + n;
  size_t R0 = (size_t)(b*PT + p0)*1296 + n0;
  int rowu4 = C >> 3;
  uint4* o4 = (uint4*)Pb;
  for (int c0 = 0; c0 < C; c0 += 64){
    float a[64];
    #pragma unroll
    for (int c = 0; c < 64; ++c) a[c] = xb[(size_t)(c0 + c)*L];
    unsigned vals[32];
    pack_pairs(a, vals);
    staged_write(lds, tid, vals, o4, R0, rowu4, c0 >> 3, nullptr);
  }
}

// ---------------- MFMA conv-as-GEMM with fused BN-stats ----------------
__launch_bounds__(256)
__global__ void k_mfconv(const unsigned short* __restrict__ P, const unsigned short* __restrict__ Wp,
                         float* __restrict__ out, int Cin, int Cout, int Mz,
                         int Tout, int stride, int KT, int pad, int p0, int plo, int phi, int PT,
                         float* __restrict__ sums)
{
  __shared__ float sred[2][4][4][16];
  int bz = blockIdx.z; int b = bz / Mz; int mz = bz - b*Mz;
  int lane = threadIdx.x & 63;
  int wave = threadIdx.x >> 6;
  int tile = blockIdx.x*4 + wave;
  bool valid = (tile < 27);
  int t = blockIdx.y;
  int col = lane & 15, grp = lane >> 4;
  int Kt32 = (KT*Cin) >> 5;
  f32x4 acc[4][3];
  #pragma unroll
  for (int i = 0; i < 4; ++i)
    #pragma unroll
    for (int j = 0; j < 3; ++j) acc[i][j] = (f32x4){0.f, 0.f, 0.f, 0.f};
  if (valid){
    int hw0 = tile*48 + col;
    const unsigned short* wbase = Wp + ((size_t)(mz*4)*Kt32)*512 + lane*8;
    for (int dt = 0; dt < KT; ++dt){
      int p = t*stride + dt - pad + p0;
      if (p < plo || p >= phi) continue;
      const unsigned short* Pp = P + ((size_t)(b*PT + p)*1296 + hw0)*Cin + grp*8;
      int nCk = Cin >> 5;
      int ksg = (dt*Cin) >> 5;
      for (int kc = 0; kc < nCk; ++kc){
        bf16x8 bf0 = *(const bf16x8*)(Pp + (size_t)0*Cin  + kc*32);
        bf16x8 bf1 = *(const bf16x8*)(Pp + (size_t)16*Cin + kc*32);
        bf16x8 bf2 = *(const bf16x8*)(Pp + (size_t)32*Cin + kc*32);
        #pragma unroll
        for (int mf = 0; mf < 4; ++mf){
          bf16x8 af = *(const bf16x8*)(wbase + ((size_t)mf*Kt32 + ksg + kc)*512);
          acc[mf][0] = __builtin_amdgcn_mfma_f32_16x16x32_bf16(af, bf0, acc[mf][0], 0, 0, 0);
          acc[mf][1] = __builtin_amdgcn_mfma_f32_16x16x32_bf16(af, bf1, acc[mf][1], 0, 0, 0);
          acc[mf][2] = __builtin_amdgcn_mfma_f32_16x16x32_bf16(af, bf2, acc[mf][2], 0, 0, 0);
        }
      }
    }
    size_t cs = (size_t)Tout*1296;
    size_t obase = ((size_t)(b*Cout + mz*64 + grp*4))*cs + (size_t)t*1296;
    #pragma unroll
    for (int mf = 0; mf < 4; ++mf)
      #pragma unroll
      for (int f = 0; f < 3; ++f){
        int hw = tile*48 + f*16 + col;
        #pragma unroll
        for (int r = 0; r < 4; ++r)
          out[obase + (size_t)(mf*16 + r)*cs + hw] = acc[mf][f][r];
      }
  }
  // fused BN-stats epilogue
  float s[16], q[16];
  #pragma unroll
  for (int mf = 0; mf < 4; ++mf)
    #pragma unroll
    for (int r = 0; r < 4; ++r){
      float v0 = acc[mf][0][r], v1 = acc[mf][1][r], v2 = acc[mf][2][r];
      s[mf*4+r] = v0 + v1 + v2;
      q[mf*4+r] = v0*v0 + v1*v1 + v2*v2;
    }
  #pragma unroll
  for (int m = 1; m <= 8; m <<= 1){
    #pragma unroll
    for (int j = 0; j < 16; ++j){
      s[j] += __shfl_xor(s[j], m);
      q[j] += __shfl_xor(q[j], m);
    }
  }
  if (col == 0){
    #pragma unroll
    for (int j = 0; j < 16; ++j){
      sred[0][wave][grp][j] = s[j];
      sred[1][wave][grp][j] = q[j];
    }
  }
  __syncthreads();
  int tid = threadIdx.x;
  if (tid < 128){
    int stat = tid >> 6, ch = tid & 63;
    int rr = ch & 3, gg = (ch >> 2) & 3, mm = ch >> 4;
    int j = mm*4 + rr;
    float v = sred[stat][0][gg][j] + sred[stat][1][gg][j]
            + sred[stat][2][gg][j] + sred[stat][3][gg][j];
    atomicAdd(&sums[stat*Cout + mz*64 + ch], v);
  }
}

// ---------------- naive temporal conv (ce pw 64->4) ----------------
__global__ void k_tconv(const float* __restrict__ xA,
                        const float* __restrict__ wT,
                        float* __restrict__ out,
                        int Cin, int Cout, int Tin)
{
  int b  = blockIdx.z;
  int o  = threadIdx.x;  // 4
  int t  = blockIdx.y;
  int hw4 = blockIdx.x*blockDim.y + threadIdx.y;
  if (hw4 >= 324) return;
  float4 acc = make_float4(0.f,0.f,0.f,0.f);
  const float4* xr = (const float4*)xA + ((size_t)b*Cin*Tin + t)*324 + hw4;
  const float* wp  = wT + o;
  size_t xstep = (size_t)Tin*324;
  for (int i = 0; i < Cin; ++i){
    float4 xv = *xr;
    float  wv = *wp;
    acc.x = fmaf(wv, xv.x, acc.x);
    acc.y = fmaf(wv, xv.y, acc.y);
    acc.z = fmaf(wv, xv.z, acc.z);
    acc.w = fmaf(wv, xv.w, acc.w);
    xr += xstep; wp += Cout;
  }
  float4* op = (float4*)out + ((size_t)(b*Cout + o)*Tin + t)*324 + hw4;
  *op = acc;
}

// ---------------- BN ----------------

__global__ void k_bnstats(const float* __restrict__ x, int Bn, int Cn, int L,
                          long bstride, long cstride, float* __restrict__ sums)
{
  int c = blockIdx.y;
  int tid = threadIdx.x;
  float s = 0.f, sq = 0.f;
  int tot = Bn*L;
  for (int idx = blockIdx.x*blockDim.x + tid; idx < tot; idx += gridDim.x*blockDim.x){
    int b = idx / L; int l = idx - b*L;
    float v = x[(size_t)b*bstride + (size_t)c*cstride + l];
    s += v; sq += v*v;
  }
  __shared__ float r1[256], r2[256];
  r1[tid] = s; r2[tid] = sq; __syncthreads();
  for (int k = 128; k > 0; k >>= 1){
    if (tid < k){ r1[tid] += r1[tid+k]; r2[tid] += r2[tid+k]; }
    __syncthreads();
  }
  if (tid == 0){ atomicAdd(&sums[c], r1[0]); atomicAdd(&sums[Cn+c], r2[0]); }
}

// single-plane stats: z=0 -> (A, t=15) into s22 ; z=1 -> (B, t=0) into s23
__global__ void k_planestats(const float* __restrict__ A, const float* __restrict__ B,
                             float* __restrict__ s22, float* __restrict__ s23){
  int which = blockIdx.z, c = blockIdx.y, tid = threadIdx.x;
  const float* src = which ? B : A;
  int toff = which ? 0 : 15;
  float* dst = which ? s23 : s22;
  float s = 0.f, q = 0.f;
  for (int idx = tid; idx < 4*1296; idx += 256){
    int b = idx / 1296, hw = idx - b*1296;
    float v = src[(((size_t)b*64 + c)*16 + toff)*1296 + hw];
    s += v; q += v*v;
  }
  __shared__ float r1[256], r2[256];
  r1[tid] = s; r2[tid] = q; __syncthreads();
  for (int k = 128; k > 0; k >>= 1){
    if (tid < k){ r1[tid] += r1[tid+k]; r2[tid] += r2[tid+k]; }
    __syncthreads();
  }
  if (tid == 0){ dst[c] = r1[0]; dst[64 + c] = r2[0]; }
}

// slot2 = slot0 + slot1 - slot22 - slot23 + slot21
__global__ void k_combine(float* stats){
  int i = threadIdx.x;
  if (i < 128)
    stats[2*512 + i] = stats[0*512 + i] + stats[1*512 + i]
                     - stats[22*512 + i] - stats[23*512 + i] + stats[21*512 + i];
}

__global__ void k_bnrelu(float* __restrict__ x, int Cn, int L, long bstride, long cstride,
                         const float* __restrict__ sums, const float* __restrict__ g,
                         const float* __restrict__ bet, float invc)
{
  int c = blockIdx.y, b = blockIdx.z;
  int l = blockIdx.x*blockDim.x + threadIdx.x;
  if (l >= L) return;
  float m  = sums[c]*invc;
  float v  = fmaxf(sums[Cn+c]*invc - m*m, 0.f);
  float sc = g[c]*rsqrtf(v + 1e-5f);
  float bb = bet[c] - m*sc;
  size_t idx = (size_t)b*bstride + (size_t)c*cstride + l;
  float val = fmaf(x[idx], sc, bb);
  x[idx] = fmaxf(val, 0.f);
}

// BN+ReLU in place over [b][64][16][1296] AND write T-mean to xm (fuses meanT)
__global__ void k_bnrelu_mean(float* __restrict__ x, const float* __restrict__ sums,
                              const float* __restrict__ g, const float* __restrict__ bet,
                              float invc, float* __restrict__ xm)
{
  int hw = blockIdx.x*256 + threadIdx.x;
  if (hw >= 1296) return;
  int c = blockIdx.y, b = blockIdx.z;
  float m  = sums[c]*invc;
  float v  = fmaxf(sums[64+c]*invc - m*m, 0.f);
  float sc = g[c]*rsqrtf(v + 1e-5f);
  float bb = bet[c] - m*sc;
  float* xb = x + ((size_t)(b*64 + c)*16)*1296 + hw;
  float s = 0.f;
  #pragma unroll
  for (int t = 0; t < 16; ++t){
    float val = fmaxf(fmaf(xb[(size_t)t*1296], sc, bb), 0.f);
    xb[(size_t)t*1296] = val;
    s += val;
  }
  xm[((size_t)b*64 + c)*1296 + hw] = s*(1.f/16.f);
}

// BN+ReLU on raw f32 [b][64][L] -> bf16 P layout rows [b][n][outC] at coff
__global__ void k_bnT(const float* __restrict__ x, const float* __restrict__ sums,
                      const float* __restrict__ g, const float* __restrict__ bet, float invc,
                      unsigned short* __restrict__ P1, unsigned short* __restrict__ P2,
                      int L, int outC, int coff)
{
  __shared__ unsigned lds[8448];
  int tid = threadIdx.x, b = blockIdx.z;
  int n0 = blockIdx.x*256, n = n0 + tid;
  const float* xb = x + (size_t)b*64*L + n;
  float a[64];
  #pragma unroll
  for (int c = 0; c < 64; ++c){
    float m  = sums[c]*invc;
    float vv = fmaxf(sums[64+c]*invc - m*m, 0.f);
    float sc = g[c]*rsqrtf(vv + 1e-5f);
    float bb = bet[c] - m*sc;
    a[c] = fmaxf(fmaf(xb[(size_t)c*L], sc, bb), 0.f);
  }
  unsigned vals[32];
  pack_pairs(a, vals);
  staged_write(lds, tid, vals, (uint4*)P1, (size_t)b*L + n0, outC >> 3, coff >> 3,
               P2 ? (uint4*)P2 : nullptr);
}

// composed-concat BN+ReLU -> bf16 PTE [b][n][64]; sources A(t<15), Mb(t=15,16), B(t>16)
__global__ void k_bnT_cc(const float* __restrict__ A, const float* __restrict__ M,
                         const float* __restrict__ B, const float* __restrict__ sums,
                         const float* __restrict__ g, const float* __restrict__ bet,
                         float invc, unsigned short* __restrict__ P1)
{
  __shared__ unsigned lds[8448];
  int tid = threadIdx.x, b = blockIdx.z;
  int n0 = blockIdx.x*256, n = n0 + tid;
  int t = n / 1296, hw = n - t*1296;
  const float* src; size_t cstride;
  if (t < 15){ src = A + ((size_t)(b*64)*16 + t)*1296 + hw; cstride = (size_t)16*1296; }
  else if (t < 17){ src = M + ((size_t)(b*64)*2 + (t-15))*1296 + hw; cstride = (size_t)2*1296; }
  else { src = B + ((size_t)(b*64)*16 + (t-16))*1296 + hw; cstride = (size_t)16*1296; }
  float a[64];
  #pragma unroll
  for (int c = 0; c < 64; ++c){
    float m  = sums[c]*invc;
    float vv = fmaxf(sums[64+c]*invc - m*m, 0.f);
    float sc = g[c]*rsqrtf(vv + 1e-5f);
    float bb = bet[c] - m*sc;
    a[c] = fmaxf(fmaf(src[c*cstride], sc, bb), 0.f);
  }
  unsigned vals[32];
  pack_pairs(a, vals);
  staged_write(lds, tid, vals, (uint4*)P1, (size_t)b*N2 + n0, 8, 0, nullptr);
}

// ---------------- PAM ----------------

// adaptive pools of xm -> pp_t[b][cell][c]
__global__ void k_pool(const float* __restrict__ xm, float* __restrict__ pp_t){
  int c = blockIdx.y, b = blockIdx.z;
  int cell = threadIdx.x;
  if (cell >= 50) return;
  int s, off;
  if (cell < 1){ s=1; off=0; } else if (cell < 5){ s=2; off=1; }
  else if (cell < 14){ s=3; off=5; } else { s=6; off=14; }
  int local = cell - off, ph = local/s, pw = local%s, bh = 36/s;
  const float* xp = xm + (size_t)(b*64+c)*HW;
  float sum = 0.f;
  for (int h = ph*bh; h < (ph+1)*bh; ++h)
    for (int w = pw*bh; w < (pw+1)*bh; ++w) sum += xp[h*36 + w];
  pp_t[((size_t)b*50 + cell)*64 + c] = sum / (float)(bh*bh);
}

// fused PAM encoder: pemm + per-scale BN/ReLU + K/V/KW/sb  (single block, all batches)
__launch_bounds__(256)
__global__ void k_pamenc(const float* __restrict__ pp_t,
                         const float* __restrict__ pe_w, const float* __restrict__ pe_g,
                         const float* __restrict__ pe_b,
                         const float* __restrict__ wk, const float* __restrict__ bk,
                         const float* __restrict__ wv, const float* __restrict__ bv,
                         const float* __restrict__ wq, const float* __restrict__ bq,
                         float* __restrict__ vb, float* __restrict__ KW,
                         float* __restrict__ sb)
{
  __shared__ float pf[12800];    // [b][c][cell]
  __shared__ float kbl[3200];    // [b][k][o16]
  int tid = threadIdx.x;
  int o = tid & 63, b = tid >> 6;
  // (a) pemm
  {
    float acc[50];
    #pragma unroll
    for (int k = 0; k < 50; ++k) acc[k] = 0.f;
    const float* pr0 = pp_t + (size_t)b*50*64;
    for (int i = 0; i < 64; ++i){
      float w0 = pe_w[0*4096 + o*64 + i];
      float w1 = pe_w[1*4096 + o*64 + i];
      float w2 = pe_w[2*4096 + o*64 + i];
      float w3 = pe_w[3*4096 + o*64 + i];
      const float* pr = pr0 + i;
      acc[0] = fmaf(w0, pr[0], acc[0]);
      #pragma unroll
      for (int cell = 1; cell < 5; ++cell)  acc[cell] = fmaf(w1, pr[cell*64], acc[cell]);
      #pragma unroll
      for (int cell = 5; cell < 14; ++cell) acc[cell] = fmaf(w2, pr[cell*64], acc[cell]);
      #pragma unroll
      for (int cell = 14; cell < 50; ++cell)acc[cell] = fmaf(w3, pr[cell*64], acc[cell]);
    }
    #pragma unroll
    for (int k = 0; k < 50; ++k) pf[(b*64 + o)*50 + k] = acc[k];
  }
  __syncthreads();
  // (b) BN per scale group; thread = (oc = tid&63, grp = tid>>6)
  {
    const int ss2[4] = {1,4,9,36};
    const int soff[4] = {0,1,5,14};
    int grp = tid >> 6, oc = tid & 63;
    int s2 = ss2[grp], off = soff[grp];
    float s = 0.f, q = 0.f;
    for (int bb = 0; bb < 4; ++bb)
      for (int j = 0; j < s2; ++j){
        float v = pf[(bb*64 + oc)*50 + off + j];
        s += v; q += v*v;
      }
    float invc = 1.f/(4.f*(float)s2);
    float m = s*invc;
    float var = fmaxf(q*invc - m*m, 0.f);
    float sc = pe_g[grp*64 + oc]*rsqrtf(var + 1e-5f);
    float sh = pe_b[grp*64 + oc] - m*sc;
    for (int bb = 0; bb < 4; ++bb)
      for (int j = 0; j < s2; ++j){
        int idx = (bb*64 + oc)*50 + off + j;
        pf[idx] = fmaxf(fmaf(pf[idx], sc, sh), 0.f);
      }
  }
  __syncthreads();
  // (c) kb[b][k][o16]
  for (int u = tid; u < 3200; u += 256){
    int b2 = u / 800, rem = u - b2*800;
    int k = rem >> 4, o2 = rem & 15;
    float val = bk[o2];
    for (int c = 0; c < 64; ++c)
      val = fmaf(wk[o2*64 + c], pf[(b2*64 + c)*50 + k], val);
    kbl[u] = val;
  }
  __syncthreads();
  // (d) vb[b][k][c]
  for (int u = tid; u < 12800; u += 256){
    int b2 = u / 3200, rem = u - b2*3200;
    int k = rem >> 6, c = rem & 63;
    float val = bv[c];
    for (int i = 0; i < 64; ++i)
      val = fmaf(wv[c*64 + i], pf[(b2*64 + i)*50 + k], val);
    vb[u] = val;
  }
  // (e) KW[b][k][c] and sb[b][k]
  for (int u = tid; u < 12800; u += 256){
    int b2 = u / 3200, rem = u - b2*3200;
    int k = rem >> 6, c = rem & 63;
    const float* kp = &kbl[(b2*50 + k)*16];
    float val = 0.f;
    #pragma unroll
    for (int o2 = 0; o2 < 16; ++o2)
      val = fmaf(kp[o2], wq[o2*64 + c], val);
    KW[u] = val;
  }
  for (int u = tid; u < 200; u += 256){
    const float* kp = &kbl[u*16];
    float val = 0.f;
    #pragma unroll
    for (int o2 = 0; o2 < 16; ++o2) val = fmaf(kp[o2], bq[o2], val);
    sb[u] = val;
  }
}

// scores via KW trick; softmax; PV + residual; staged bf16 write
__launch_bounds__(256, 1)
__global__ void k_pamattn(const float* __restrict__ x, const float* __restrict__ KW,
                          const float* __restrict__ sbb, const float* __restrict__ vbuf,
                          const float* __restrict__ scp, unsigned short* __restrict__ Pg)
{
  __shared__ unsigned smem_u[8448];
  float* smem = (float*)smem_u;      // [0,3200) KW ; [3200,6400) v ; [6400,6450) sb
  int b = blockIdx.z, tid = threadIdx.x;
  for (int i = tid; i < 3200; i += 256){
    smem[i]        = KW[(size_t)b*3200 + i];
    smem[3200 + i] = vbuf[(size_t)b*3200 + i];
  }
  if (tid < 50) smem[6400 + tid] = sbb[(size_t)b*50 + tid];
  __syncthreads();
  int n0 = blockIdx.x*256;
  int n = n0 + tid;
  const float* xb = x + (size_t)b*64*Nn + n;
  float xv[64];
  #pragma unroll
  for (int c = 0; c < 64; ++c) xv[c] = xb[(size_t)c*Nn];
  float s[50];
  const float4* kw4 = (const float4*)smem;
  #pragma unroll
  for (int k = 0; k < 50; ++k){
    float t = smem[6400 + k];
    #pragma unroll
    for (int c4 = 0; c4 < 16; ++c4){
      float4 kw = kw4[k*16 + c4];
      t = fmaf(xv[c4*4+0], kw.x, t);
      t = fmaf(xv[c4*4+1], kw.y, t);
      t = fmaf(xv[c4*4+2], kw.z, t);
      t = fmaf(xv[c4*4+3], kw.w, t);
    }
    s[k] = t;
  }
  float mx = -1e30f;
  #pragma unroll
  for (int k = 0; k < 50; ++k) mx = fmaxf(mx, s[k]);
  float sum = 0.f;
  #pragma unroll
  for (int k = 0; k < 50; ++k){ float p = __expf(s[k]-mx); s[k] = p; sum += p; }
  float sc = scp[0]/sum;
  const float4* vl4 = (const float4*)(smem + 3200);
  #pragma unroll
  for (int k = 0; k < 50; ++k){
    float pk = sc * s[k];
    #pragma unroll
    for (int c4 = 0; c4 < 16; ++c4){
      float4 v = vl4[k*16 + c4];
      xv[c4*4+0] = fmaf(pk, v.x, xv[c4*4+0]);
      xv[c4*4+1] = fmaf(pk, v.y, xv[c4*4+1]);
      xv[c4*4+2] = fmaf(pk, v.z, xv[c4*4+2]);
      xv[c4*4+3] = fmaf(pk, v.w, xv[c4*4+3]);
    }
  }
  __syncthreads();
  unsigned vals[32];
  pack_pairs(xv, vals);
  staged_write(smem_u, tid, vals, (uint4*)Pg, (size_t)b*Nn + n0, 8, 0, nullptr);
}

// ---------------- CAM ----------------

__global__ void k_camenergy2(const float* __restrict__ x, const float* __restrict__ yc,
                             float* __restrict__ e){
  __shared__ float yl[4][256];
  int b = blockIdx.z, tid = threadIdx.x;
  int n0 = blockIdx.x*256;
  #pragma unroll
  for (int k = 0; k < 4; ++k)
    yl[k][tid] = yc[((size_t)b*4+k)*Nn + n0 + tid];
  __syncthreads();
  int c = tid & 63, ks = tid >> 6;
  const float* xr = x + (size_t)(b*64+c)*Nn + n0;
  const float* yr = yl[ks];
  float acc = 0.f;
  #pragma unroll 8
  for (int i = 0; i < 256; ++i) acc = fmaf(xr[i], yr[i], acc);
  atomicAdd(&e[((size_t)(b*64)+c)*4 + ks], acc);
}

__global__ void k_camapplyT(const float* __restrict__ x, const float* __restrict__ yc,
                            const float* __restrict__ e, const float* __restrict__ scp,
                            unsigned short* __restrict__ Pg){
  __shared__ float pw[64][4];
  __shared__ unsigned lds[8448];
  int tid = threadIdx.x;
  int b = blockIdx.z;
  if (tid < 64){
    const float* er = e + (size_t)(b*64+tid)*4;
    float e0=er[0], e1=er[1], e2=er[2], e3=er[3];
    float mx = fmaxf(fmaxf(e0,e1), fmaxf(e2,e3));
    float z0=mx-e0, z1=mx-e1, z2=mx-e2, z3=mx-e3;
    float zm = fmaxf(fmaxf(z0,z1), fmaxf(z2,z3));
    float p0=__expf(z0-zm), p1=__expf(z1-zm), p2=__expf(z2-zm), p3=__expf(z3-zm);
    float inv = 1.f/(p0+p1+p2+p3);
    pw[tid][0]=p0*inv; pw[tid][1]=p1*inv; pw[tid][2]=p2*inv; pw[tid][3]=p3*inv;
  }
  __syncthreads();
  int n0 = blockIdx.x*256;
  int n = n0 + tid;
  float y0 = yc[((size_t)b*4+0)*Nn + n];
  float y1 = yc[((size_t)b*4+1)*Nn + n];
  float y2 = yc[((size_t)b*4+2)*Nn + n];
  float y3 = yc[((size_t)b*4+3)*Nn + n];
  float sc = scp[0];
  const float* xb = x + (size_t)b*64*Nn + n;
  float a[64];
  #pragma unroll
  for (int c = 0; c < 64; ++c){
    a[c] = fmaf(sc, pw[c][0]*y0 + pw[c][1]*y1 + pw[c][2]*y2 + pw[c][3]*y3,
                xb[(size_t)c*Nn]);
  }
  unsigned vals[32];
  pack_pairs(a, vals);
  staged_write(lds, tid, vals, (uint4*)Pg, (size_t)b*Nn + n0, 8, 0, nullptr);
}

// ---------------- TAM ----------------

__launch_bounds__(256)
__global__ void k_tamenergy_mf(const unsigned short* __restrict__ X,
                               const unsigned short* __restrict__ Y,
                               float* __restrict__ E){
  int b = blockIdx.z;
  int wave = threadIdx.x >> 6, lane = threadIdx.x & 63;
  int r = lane & 15, g = lane >> 4;
  const unsigned short* Xb = X + (size_t)b*32*82944;
  const unsigned short* Yb = Y + (size_t)b*32*82944;
  f32x4 a00 = (f32x4){0.f,0.f,0.f,0.f};
  f32x4 a01 = a00, a10 = a00, a11 = a00;
  int c0 = (blockIdx.x*4 + wave)*8;
  for (int cc = 0; cc < 8; ++cc){
    size_t k0 = (size_t)(c0 + cc)*32 + (size_t)g*8;
    bf16x8 x0 = *(const bf16x8*)(Xb + (size_t)r*82944 + k0);
    bf16x8 x1 = *(const bf16x8*)(Xb + (size_t)(r+16)*82944 + k0);
    bf16x8 y0 = *(const bf16x8*)(Yb + (size_t)r*82944 + k0);
    bf16x8 y1 = *(const bf16x8*)(Yb + (size_t)(r+16)*82944 + k0);
    a00 = __builtin_amdgcn_mfma_f32_16x16x32_bf16(x0, y0, a00, 0, 0, 0);
    a01 = __builtin_amdgcn_mfma_f32_16x16x32_bf16(x0, y1, a01, 0, 0, 0);
    a10 = __builtin_amdgcn_mfma_f32_16x16x32_bf16(x1, y0, a10, 0, 0, 0);
    a11 = __builtin_amdgcn_mfma_f32_16x16x32_bf16(x1, y1, a11, 0, 0, 0);
  }
  float* Eb = E + (size_t)b*1024;
  #pragma unroll
  for (int rr = 0; rr < 4; ++rr){
    int row = g*4 + rr;
    atomicAdd(&Eb[row*32 + r],           a00[rr]);
    atomicAdd(&Eb[row*32 + 16 + r],      a01[rr]);
    atomicAdd(&Eb[(row+16)*32 + r],      a10[rr]);
    atomicAdd(&Eb[(row+16)*32 + 16 + r], a11[rr]);
  }
}

// inline softmax + LDS-tiled apply -> bf16 P-layout
__launch_bounds__(256)
__global__ void k_tamapply_mf(const unsigned short* __restrict__ Xbf,
                              const unsigned short* __restrict__ Ybf,
                              const float* __restrict__ e, const float* __restrict__ scp,
                              unsigned short* __restrict__ Pout){
  __shared__ unsigned short yl[32*8*TAPAD];
  __shared__ float al[1024];
  int b = blockIdx.z, tid = threadIdx.x;
  int hw0 = blockIdx.x*8;
  if (tid < 32){
    const float* er = e + (size_t)b*1024 + tid*32;
    float mx = -1e30f, mn = 1e30f;
    for (int j = 0; j < 32; ++j){ mx = fmaxf(mx, er[j]); mn = fminf(mn, er[j]); }
    float zmax = mx - mn;
    float sum = 0.f;
    for (int j = 0; j < 32; ++j){
      float p = __expf((mx - er[j]) - zmax);
      al[tid*32 + j] = p; sum += p;
    }
    float inv = 1.f/sum;
    for (int j = 0; j < 32; ++j) al[tid*32 + j] *= inv;
  }
  const uint4* src = (const uint4*)Ybf + (size_t)b*N2*8;
  #pragma unroll
  for (int it = 0; it < 8; ++it){
    int idx = it*256 + tid;
    int j = idx >> 6, rem = idx & 63, h = rem >> 3, w = rem & 7;
    uint4 v = src[(size_t)(j*1296 + hw0 + h)*8 + w];
    *(uint4*)&yl[(j*8+h)*TAPAD + w*8] = v;
  }
  __syncthreads();
  int t = tid >> 3, h = tid & 7;
  int n = t*1296 + hw0 + h;
  float sc = scp[0];
  const uint4* xr = (const uint4*)Xbf + ((size_t)b*N2 + n)*8;
  float acc[64];
  #pragma unroll
  for (int w = 0; w < 8; ++w){
    uint4 v = xr[w];
    acc[w*8+0] = b2f_lo(v.x); acc[w*8+1] = b2f_hi(v.x);
    acc[w*8+2] = b2f_lo(v.y); acc[w*8+3] = b2f_hi(v.y);
    acc[w*8+4] = b2f_lo(v.z); acc[w*8+5] = b2f_hi(v.z);
    acc[w*8+6] = b2f_lo(v.w); acc[w*8+7] = b2f_hi(v.w);
  }
  const float* ar = &al[t*32];
  for (int j = 0; j < 32; ++j){
    float aj = sc * ar[j];
    const uint4* yr = (const uint4*)&yl[(j*8+h)*TAPAD];
    #pragma unroll
    for (int w = 0; w < 8; ++w){
      uint4 v = yr[w];
      acc[w*8+0] = fmaf(aj, b2f_lo(v.x), acc[w*8+0]);
      acc[w*8+1] = fmaf(aj, b2f_hi(v.x), acc[w*8+1]);
      acc[w*8+2] = fmaf(aj, b2f_lo(v.y), acc[w*8+2]);
      acc[w*8+3] = fmaf(aj, b2f_hi(v.y), acc[w*8+3]);
      acc[w*8+4] = fmaf(aj, b2f_lo(v.z), acc[w*8+4]);
      acc[w*8+5] = fmaf(aj, b2f_hi(v.z), acc[w*8+5]);
      acc[w*8+6] = fmaf(aj, b2f_lo(v.w), acc[w*8+6]);
      acc[w*8+7] = fmaf(aj, b2f_hi(v.w), acc[w*8+7]);
    }
  }
  uint4* orow = (uint4*)Pout + ((size_t)b*N2 + n)*8;
  #pragma unroll
  for (int w = 0; w < 8; ++w){
    uint4 v;
    v.x = (unsigned)f2b(acc[w*8+0]) | ((unsigned)f2b(acc[w*8+1]) << 16);
    v.y = (unsigned)f2b(acc[w*8+2]) | ((unsigned)f2b(acc[w*8+3]) << 16);
    v.z = (unsigned)f2b(acc[w*8+4]) | ((unsigned)f2b(acc[w*8+5]) << 16);
    v.w = (unsigned)f2b(acc[w*8+6]) | ((unsigned)f2b(acc[w*8+7]) << 16);
    orow[w] = v;
  }
}

// ---------------- host ----------------

extern "C" void kernel_launch(void* const* d_in, const int* in_sizes, int n_in,
                              void* d_out, int out_size, void* d_ws, size_t ws_size,
                              hipStream_t stream) {
  const float* x1      = (const float*)d_in[0];
  const float* x2      = (const float*)d_in[1];
  const float* w_conv1 = (const float*)d_in[2];
  const float* g_conv1 = (const float*)d_in[3];
  const float* b_conv1 = (const float*)d_in[4];
  const float* w_conv2 = (const float*)d_in[5];
  const float* g_conv2 = (const float*)d_in[6];
  const float* b_conv2 = (const float*)d_in[7];
  const float* w_tam   = (const float*)d_in[8];
  const float* g_tam   = (const float*)d_in[9];
  const float* b_tam   = (const float*)d_in[10];
  const float* w_cat   = (const float*)d_in[11];
  const float* g_cat   = (const float*)d_in[12];
  const float* b_cat   = (const float*)d_in[13];
  const float* pe_w    = (const float*)d_in[14];
  const float* pe_g    = (const float*)d_in[15];
  const float* pe_b    = (const float*)d_in[16];
  const float* pd_wq   = (const float*)d_in[17];
  const float* pd_bq   = (const float*)d_in[18];
  const float* pd_wk   = (const float*)d_in[19];
  const float* pd_bk   = (const float*)d_in[20];
  const float* pd_wv   = (const float*)d_in[21];
  const float* pd_bv   = (const float*)d_in[22];
  const float* pd_scale= (const float*)d_in[23];
  const float* ce_w    = (const float*)d_in[24];
  const float* ce_g    = (const float*)d_in[25];
  const float* ce_b    = (const float*)d_in[26];
  const float* cd_scale= (const float*)d_in[27];
  const float* te_w    = (const float*)d_in[28];
  const float* te_g    = (const float*)d_in[29];
  const float* te_b    = (const float*)d_in[30];
  const float* td_scale= (const float*)d_in[31];

  float* ws = (float*)d_ws;
  size_t off = 0;
  auto alloc = [&](size_t n){ float* p = ws + off; off += (n + 3) & ~(size_t)3; return p; };
  float* stats = alloc(16384);   // 32 slots x 512
  float* e_tam = alloc(4096);
  float* e_cam = alloc(2048);
  float* wTce  = alloc(256);
  unsigned short* Wp1  = (unsigned short*)alloc(24576);
  unsigned short* Wp2  = (unsigned short*)alloc(6144);
  unsigned short* Wpt  = (unsigned short*)alloc(6144);
  unsigned short* Wpc  = (unsigned short*)alloc(73728);
  unsigned short* Wpte = (unsigned short*)alloc(2048);
  float* xm    = alloc(331776);
  float* pp_t  = alloc(12800);
  float* vb    = alloc(12800);
  float* KWb   = alloc(12800);
  float* sbb   = alloc(256);
  float* yc    = alloc(331776);
  float* Mb    = alloc(663552);    // concat boundary planes t=15,16 raw
  float* A     = alloc(5308416);   // conv1(x1) raw->BN'd f32
  float* Bb    = alloc(5308416);   // conv1(x2)
  float* PTEf  = alloc(5308416);   // bf16 BN'd xt1 [b][32][1296][64]
  float* COMB  = alloc(31850496);  // overlaid region

  // COMB overlays (float offsets):
  unsigned short* P0 = (unsigned short*)COMB;                   // [0..21.2M)f input bf16
  float* Dd = COMB;                                             // [0..10.6M) xt2 raw f32
  unsigned short* Dbf  = (unsigned short*)(COMB + 10616832);    // [10.6..15.9M)
  unsigned short* PTAM = (unsigned short*)(COMB + 15925248);    // [15.9..21.2M)
  float* Rraw = COMB;                                           // [0..5.3M) conv raw outs
  unsigned short* PCAT1 = (unsigned short*)(COMB + 5308416);    // [5.3..13.27M)
  unsigned short* PCAT2 = (unsigned short*)(COMB + 13271040);   // [13.27..21.2M)
  unsigned short* PG    = (unsigned short*)(COMB + 21233664);   // [21.2..23.9M)
  unsigned short* PTE = (unsigned short*)PTEf;

  const float invc16 = 1.f/(4.f*20736.f);
  const float invc32 = 1.f/(4.f*41472.f);

  // zero stats + e_tam + e_cam (contiguous 22528 floats)
  k_zero<<<dim3(88), 256, 0, stream>>>(stats, 22528);
  // all weight prep (one kernel)
  k_wprep<<<dim3(881), 256, 0, stream>>>(w_conv1, w_conv2, w_tam, w_cat, te_w, ce_w,
                                         Wp1, Wp2, Wpt, Wpc, Wpte, wTce);
  // inputs -> P0 bf16 (planes 0-15: x1, 16-31: x2)
  k_convT<<<dim3(81, 1, 4), 256, 0, stream>>>(x1, P0, 256, Nn, 32, 0);
  k_convT<<<dim3(81, 1, 4), 256, 0, stream>>>(x2, P0, 256, Nn, 32, 16);

  // conv1 raw: A (slot0), B (slot1), boundary planes Mb (slot21 = m15+m16)
  k_mfconv<<<dim3(7,16,4), 256, 0, stream>>>(P0, Wp1, A,  256, 64, 1, 16, 1, 3, 1, 0, 0, 16, 32, stats + 0*512);
  k_mfconv<<<dim3(7,16,4), 256, 0, stream>>>(P0, Wp1, Bb, 256, 64, 1, 16, 1, 3, 1, 16, 16, 32, 32, stats + 1*512);
  k_mfconv<<<dim3(7,2,4),  256, 0, stream>>>(P0, Wp1, Mb, 256, 64, 1, 2, 1, 3, 1, 15, 0, 32, 32, stats + 21*512);
  // compose concat stats: slot2 = slot0+slot1-A15-B0+Mb
  k_planestats<<<dim3(1,64,2), 256, 0, stream>>>(A, Bb, stats + 22*512, stats + 23*512);
  k_combine<<<dim3(1), 128, 0, stream>>>(stats);
  // BN'd concat bf16 -> PTE (reads RAW A/Mb/B)
  k_bnT_cc<<<dim3(162,1,4), 256, 0, stream>>>(A, Mb, Bb, stats + 2*512,
                                              g_conv1, b_conv1, invc32, PTE);

  // xt2 = pw_bn_relu(xt1, te_w)
  k_mfconv<<<dim3(7,32,4), 256, 0, stream>>>(PTE, Wpte, Dd, 64, 64, 1, 32, 1, 1, 0, 0, 0, 32, 32, stats + 3*512);
  k_bnT<<<dim3(162,1,4), 256, 0, stream>>>(Dd, stats + 3*512, te_g, te_b, invc32,
                                           Dbf, nullptr, N2, 64, 0);

  // TAM
  k_tamenergy_mf<<<dim3(81, 1, 4), 256, 0, stream>>>(PTE, Dbf, e_tam);
  k_tamapply_mf<<<dim3(162, 1, 4), 256, 0, stream>>>(PTE, Dbf, e_tam, td_scale, PTAM);
  k_mfconv<<<dim3(7,16,4), 256, 0, stream>>>(PTAM, Wpt, Rraw, 64, 64, 1, 16, 2, 3, 1, 0, 0, 32, 32, stats + 4*512);
  k_bnT<<<dim3(81,1,4), 256, 0, stream>>>(Rraw, stats + 4*512, g_tam, b_tam, invc16,
                                          PCAT1, PCAT2, Nn, 192, 128);

  auto pam = [&](float* xin, unsigned short* catp, int slot_c2){
    k_pool<<<dim3(1, 64, 4), 64, 0, stream>>>(xm, pp_t);
    k_pamenc<<<dim3(1), 256, 0, stream>>>(pp_t, pe_w, pe_g, pe_b,
                                          pd_wk, pd_bk, pd_wv, pd_bv, pd_wq, pd_bq,
                                          vb, KWb, sbb);
    k_pamattn<<<dim3(81, 1, 4), 256, 0, stream>>>(xin, KWb, sbb, vb, pd_scale, PG);
    k_mfconv<<<dim3(7,16,4), 256, 0, stream>>>(PG, Wp2, Rraw, 64, 64, 1, 16, 1, 3, 1, 0, 0, 16, 16, stats + (size_t)slot_c2*512);
    k_bnT<<<dim3(81,1,4), 256, 0, stream>>>(Rraw, stats + (size_t)slot_c2*512,
                                            g_conv2, b_conv2, invc16, catp, nullptr, Nn, 192, 0);
  };
  auto cam = [&](const float* xin, unsigned short* catp, float* ecam,
                 int slot_ce, int slot_c2){
    k_tconv<<<dim3(6, 16, 4), dim3(4, 64), 0, stream>>>(xin, wTce, yc, 64, 4, 16);
    k_bnstats<<<dim3(16, 4), 256, 0, stream>>>(yc, 4, 4, Nn, 4L*Nn, (long)Nn,
                                               stats + (size_t)slot_ce*512);
    k_bnrelu<<<dim3((Nn+255)/256, 4, 4), 256, 0, stream>>>(yc, 4, Nn, 4L*Nn, (long)Nn,
                                               stats + (size_t)slot_ce*512, ce_g, ce_b, invc16);
    k_camenergy2<<<dim3(81, 1, 4), 256, 0, stream>>>(xin, yc, ecam);
    k_camapplyT<<<dim3(81, 1, 4), 256, 0, stream>>>(xin, yc, ecam, cd_scale, PG);
    k_mfconv<<<dim3(7,16,4), 256, 0, stream>>>(PG, Wp2, Rraw, 64, 64, 1, 16, 1, 3, 1, 0, 0, 16, 16, stats + (size_t)slot_c2*512);
    k_bnT<<<dim3(81,1,4), 256, 0, stream>>>(Rraw, stats + (size_t)slot_c2*512,
                                            g_conv2, b_conv2, invc16, catp, nullptr, Nn, 192, 64);
  };

  // x1 branch: BN A in place + T-mean (fused), then PAM & CAM
  k_bnrelu_mean<<<dim3(6,64,4), 256, 0, stream>>>(A, stats + 0*512, g_conv1, b_conv1,
                                                  invc16, xm);
  pam(A, PCAT1, 13);
  cam(A, PCAT2, e_cam, 15, 17);
  // x2 branch
  k_bnrelu_mean<<<dim3(6,64,4), 256, 0, stream>>>(Bb, stats + 1*512, g_conv1, b_conv1,
                                                  invc16, xm);
  pam(Bb, PCAT2, 14);
  cam(Bb, PCAT1, e_cam + 1024, 16, 18);

  // final cat convs -> d_out
  float* out1 = (float*)d_out;
  float* out2 = out1 + (size_t)4*256*Nn;
  k_mfconv<<<dim3(7,16,16), 256, 0, stream>>>(PCAT1, Wpc, out1, 192, 256, 4, 16, 1, 3, 1, 0, 0, 16, 16, stats + 19*512);
  k_bnrelu<<<dim3((Nn+255)/256, 256, 4), 256, 0, stream>>>(out1, 256, Nn, 256L*Nn, (long)Nn,
                                             stats + 19*512, g_cat, b_cat, invc16);
  k_mfconv<<<dim3(7,16,16), 256, 0, stream>>>(PCAT2, Wpc, out2, 192, 256, 4, 16, 1, 3, 1, 0, 0, 16, 16, stats + 20*512);
  k_bnrelu<<<dim3((Nn+255)/256, 256, 4), 256, 0, stream>>>(out2, 256, Nn, 256L*Nn, (long)Nn,
                                             stats + 20*512, g_cat, b_cat, invc16);
}

// Round 7
// 1136.938 us; speedup vs baseline: 7.3761x; 1.1572x over previous
//
#include <hip/hip_runtime.h>

#define HW 1296
#define Tt 16
#define T2 32
#define Nn 20736
#define N2 41472
#define TAPAD 72

typedef short bf16x8 __attribute__((ext_vector_type(8)));
typedef float f32x4 __attribute__((ext_vector_type(4)));

__device__ inline unsigned short f2b(float f){
  union { float f; unsigned u; } v; v.f = f;
  unsigned r = v.u + 0x7FFF + ((v.u >> 16) & 1);
  return (unsigned short)(r >> 16);
}
__device__ inline float b2f_lo(unsigned u){
  union { unsigned u; float f; } v; v.u = u << 16; return v.f;
}
__device__ inline float b2f_hi(unsigned u){
  union { unsigned u; float f; } v; v.u = u & 0xffff0000u; return v.f;
}

__device__ __forceinline__ void pack_pairs(const float* a, unsigned* vals){
  #pragma unroll
  for (int i = 0; i < 32; ++i)
    vals[i] = (unsigned)f2b(a[2*i]) | ((unsigned)f2b(a[2*i+1]) << 16);
}

// LDS-transpose staged coalesced write (256 threads, each owns a 64-bf16 row)
__device__ __forceinline__ void staged_write(unsigned* lds, int tid, const unsigned* vals,
                                             uint4* o4, size_t R0, int rowu4, int cw,
                                             uint4* o4b){
  #pragma unroll
  for (int i = 0; i < 32; ++i) lds[tid*33 + i] = vals[i];
  __syncthreads();
  #pragma unroll
  for (int k = 0; k < 8; ++k){
    int j = k*256 + tid;
    int nn = j >> 3, w = j & 7;
    int base = nn*33 + w*4;
    uint4 v;
    v.x = lds[base]; v.y = lds[base+1]; v.z = lds[base+2]; v.w = lds[base+3];
    size_t oidx = (R0 + (size_t)nn)*(size_t)rowu4 + cw + w;
    o4[oidx] = v;
    if (o4b) o4b[oidx] = v;
  }
  __syncthreads();
}

// ---------------- utility ----------------

__global__ void k_zero(float* p, int n){
  int i = blockIdx.x*blockDim.x + threadIdx.x;
  if (i < n) p[i] = 0.f;
}

__device__ __forceinline__ void wpack_one(int e, const float* w, unsigned short* wp,
                                          int Cout, int Cin, int KT){
  int Kt32 = (Cin*KT) >> 5;
  int j    = e & 7;
  int lane = (e >> 3) & 63;
  int rest = e >> 9;
  int ks   = rest % Kt32;
  int mt   = rest / Kt32;
  int m  = mt*16 + (lane & 15);
  int k  = ks*32 + (lane >> 4)*8 + j;
  int dt = k / Cin, ci = k - dt*Cin;
  wp[e] = f2b(w[((size_t)m*Cin + ci)*KT + dt]);
}

__global__ void k_wprep(const float* w1, const float* w2, const float* wt,
                        const float* wc, const float* wte, const float* wce,
                        unsigned short* Wp1, unsigned short* Wp2, unsigned short* Wpt,
                        unsigned short* Wpc, unsigned short* Wpte, float* wTce){
  int idx = blockIdx.x*256 + threadIdx.x;
  if (idx < 49152){ wpack_one(idx, w1, Wp1, 64, 256, 3); return; }
  idx -= 49152;
  if (idx < 12288){ wpack_one(idx, w2, Wp2, 64, 64, 3); return; }
  idx -= 12288;
  if (idx < 12288){ wpack_one(idx, wt, Wpt, 64, 64, 3); return; }
  idx -= 12288;
  if (idx < 147456){ wpack_one(idx, wc, Wpc, 256, 192, 3); return; }
  idx -= 147456;
  if (idx < 4096){ wpack_one(idx, wte, Wpte, 64, 64, 1); return; }
  idx -= 4096;
  if (idx < 256){
    int o = idx / 64, i = idx % 64;
    wTce[i*4 + o] = wce[idx];
  }
}

// f32 [b][C][L] -> bf16 P-layout [b][plane][hw][C]
__global__ void k_convT(const float* __restrict__ x, unsigned short* __restrict__ Pb,
                        int C, int L, int PT, int p0){
  __shared__ unsigned lds[8448];
  int tid = threadIdx.x, b = blockIdx.z;
  int n0 = blockIdx.x*256, n = n0 + tid;
  const float* xb = x + (size_t)b*C*L + n;
  size_t R0 = (size_t)(b*PT + p0)*1296 + n0;
  int rowu4 = C >> 3;
  uint4* o4 = (uint4*)Pb;
  for (int c0 = 0; c0 < C; c0 += 64){
    float a[64];
    #pragma unroll
    for (int c = 0; c < 64; ++c) a[c] = xb[(size_t)(c0 + c)*L];
    unsigned vals[32];
    pack_pairs(a, vals);
    staged_write(lds, tid, vals, o4, R0, rowu4, c0 >> 3, nullptr);
  }
}

// ---------------- MFMA conv-as-GEMM with fused BN-stats ----------------
__launch_bounds__(256)
__global__ void k_mfconv(const unsigned short* __restrict__ P, const unsigned short* __restrict__ Wp,
                         float* __restrict__ out, int Cin, int Cout, int Mz,
                         int Tout, int stride, int KT, int pad, int p0, int plo, int phi, int PT,
                         float* __restrict__ sums)
{
  __shared__ float sred[2][4][4][16];
  int bz = blockIdx.z; int b = bz / Mz; int mz = bz - b*Mz;
  int lane = threadIdx.x & 63;
  int wave = threadIdx.x >> 6;
  int tile = blockIdx.x*4 + wave;
  bool valid = (tile < 27);
  int t = blockIdx.y;
  int col = lane & 15, grp = lane >> 4;
  int Kt32 = (KT*Cin) >> 5;
  f32x4 acc[4][3];
  #pragma unroll
  for (int i = 0; i < 4; ++i)
    #pragma unroll
    for (int j = 0; j < 3; ++j) acc[i][j] = (f32x4){0.f, 0.f, 0.f, 0.f};
  if (valid){
    int hw0 = tile*48 + col;
    const unsigned short* wbase = Wp + ((size_t)(mz*4)*Kt32)*512 + lane*8;
    for (int dt = 0; dt < KT; ++dt){
      int p = t*stride + dt - pad + p0;
      if (p < plo || p >= phi) continue;
      const unsigned short* Pp = P + ((size_t)(b*PT + p)*1296 + hw0)*Cin + grp*8;
      int nCk = Cin >> 5;
      int ksg = (dt*Cin) >> 5;
      for (int kc = 0; kc < nCk; ++kc){
        bf16x8 bf0 = *(const bf16x8*)(Pp + (size_t)0*Cin  + kc*32);
        bf16x8 bf1 = *(const bf16x8*)(Pp + (size_t)16*Cin + kc*32);
        bf16x8 bf2 = *(const bf16x8*)(Pp + (size_t)32*Cin + kc*32);
        #pragma unroll
        for (int mf = 0; mf < 4; ++mf){
          bf16x8 af = *(const bf16x8*)(wbase + ((size_t)mf*Kt32 + ksg + kc)*512);
          acc[mf][0] = __builtin_amdgcn_mfma_f32_16x16x32_bf16(af, bf0, acc[mf][0], 0, 0, 0);
          acc[mf][1] = __builtin_amdgcn_mfma_f32_16x16x32_bf16(af, bf1, acc[mf][1], 0, 0, 0);
          acc[mf][2] = __builtin_amdgcn_mfma_f32_16x16x32_bf16(af, bf2, acc[mf][2], 0, 0, 0);
        }
      }
    }
    size_t cs = (size_t)Tout*1296;
    size_t obase = ((size_t)(b*Cout + mz*64 + grp*4))*cs + (size_t)t*1296;
    #pragma unroll
    for (int mf = 0; mf < 4; ++mf)
      #pragma unroll
      for (int f = 0; f < 3; ++f){
        int hw = tile*48 + f*16 + col;
        #pragma unroll
        for (int r = 0; r < 4; ++r)
          out[obase + (size_t)(mf*16 + r)*cs + hw] = acc[mf][f][r];
      }
  }
  float s[16], q[16];
  #pragma unroll
  for (int mf = 0; mf < 4; ++mf)
    #pragma unroll
    for (int r = 0; r < 4; ++r){
      float v0 = acc[mf][0][r], v1 = acc[mf][1][r], v2 = acc[mf][2][r];
      s[mf*4+r] = v0 + v1 + v2;
      q[mf*4+r] = v0*v0 + v1*v1 + v2*v2;
    }
  #pragma unroll
  for (int m = 1; m <= 8; m <<= 1){
    #pragma unroll
    for (int j = 0; j < 16; ++j){
      s[j] += __shfl_xor(s[j], m);
      q[j] += __shfl_xor(q[j], m);
    }
  }
  if (col == 0){
    #pragma unroll
    for (int j = 0; j < 16; ++j){
      sred[0][wave][grp][j] = s[j];
      sred[1][wave][grp][j] = q[j];
    }
  }
  __syncthreads();
  int tid = threadIdx.x;
  if (tid < 128){
    int stat = tid >> 6, ch = tid & 63;
    int rr = ch & 3, gg = (ch >> 2) & 3, mm = ch >> 4;
    int j = mm*4 + rr;
    float v = sred[stat][0][gg][j] + sred[stat][1][gg][j]
            + sred[stat][2][gg][j] + sred[stat][3][gg][j];
    atomicAdd(&sums[stat*Cout + mz*64 + ch], v);
  }
}

// ---------------- naive temporal conv (ce pw 64->4) ----------------
__global__ void k_tconv(const float* __restrict__ xA,
                        const float* __restrict__ wT,
                        float* __restrict__ out,
                        int Cin, int Cout, int Tin)
{
  int b  = blockIdx.z;
  int o  = threadIdx.x;  // 4
  int t  = blockIdx.y;
  int hw4 = blockIdx.x*blockDim.y + threadIdx.y;
  if (hw4 >= 324) return;
  float4 acc = make_float4(0.f,0.f,0.f,0.f);
  const float4* xr = (const float4*)xA + ((size_t)b*Cin*Tin + t)*324 + hw4;
  const float* wp  = wT + o;
  size_t xstep = (size_t)Tin*324;
  for (int i = 0; i < Cin; ++i){
    float4 xv = *xr;
    float  wv = *wp;
    acc.x = fmaf(wv, xv.x, acc.x);
    acc.y = fmaf(wv, xv.y, acc.y);
    acc.z = fmaf(wv, xv.z, acc.z);
    acc.w = fmaf(wv, xv.w, acc.w);
    xr += xstep; wp += Cout;
  }
  float4* op = (float4*)out + ((size_t)(b*Cout + o)*Tin + t)*324 + hw4;
  *op = acc;
}

// ---------------- BN ----------------

__global__ void k_bnstats(const float* __restrict__ x, int Bn, int Cn, int L,
                          long bstride, long cstride, float* __restrict__ sums)
{
  int c = blockIdx.y;
  int tid = threadIdx.x;
  float s = 0.f, sq = 0.f;
  int tot = Bn*L;
  for (int idx = blockIdx.x*blockDim.x + tid; idx < tot; idx += gridDim.x*blockDim.x){
    int b = idx / L; int l = idx - b*L;
    float v = x[(size_t)b*bstride + (size_t)c*cstride + l];
    s += v; sq += v*v;
  }
  __shared__ float r1[256], r2[256];
  r1[tid] = s; r2[tid] = sq; __syncthreads();
  for (int k = 128; k > 0; k >>= 1){
    if (tid < k){ r1[tid] += r1[tid+k]; r2[tid] += r2[tid+k]; }
    __syncthreads();
  }
  if (tid == 0){ atomicAdd(&sums[c], r1[0]); atomicAdd(&sums[Cn+c], r2[0]); }
}

// single-plane stats: z=0 -> (A, t=15) into s22 ; z=1 -> (B, t=0) into s23
__global__ void k_planestats(const float* __restrict__ A, const float* __restrict__ B,
                             float* __restrict__ s22, float* __restrict__ s23){
  int which = blockIdx.z, c = blockIdx.y, tid = threadIdx.x;
  const float* src = which ? B : A;
  int toff = which ? 0 : 15;
  float* dst = which ? s23 : s22;
  float s = 0.f, q = 0.f;
  for (int idx = tid; idx < 4*1296; idx += 256){
    int b = idx / 1296, hw = idx - b*1296;
    float v = src[(((size_t)b*64 + c)*16 + toff)*1296 + hw];
    s += v; q += v*v;
  }
  __shared__ float r1[256], r2[256];
  r1[tid] = s; r2[tid] = q; __syncthreads();
  for (int k = 128; k > 0; k >>= 1){
    if (tid < k){ r1[tid] += r1[tid+k]; r2[tid] += r2[tid+k]; }
    __syncthreads();
  }
  if (tid == 0){ dst[c] = r1[0]; dst[64 + c] = r2[0]; }
}

__global__ void k_combine(float* stats){
  int i = threadIdx.x;
  if (i < 128)
    stats[2*512 + i] = stats[0*512 + i] + stats[1*512 + i]
                     - stats[22*512 + i] - stats[23*512 + i] + stats[21*512 + i];
}

__global__ void k_bnrelu(float* __restrict__ x, int Cn, int L, long bstride, long cstride,
                         const float* __restrict__ sums, const float* __restrict__ g,
                         const float* __restrict__ bet, float invc)
{
  int c = blockIdx.y, b = blockIdx.z;
  int l = blockIdx.x*blockDim.x + threadIdx.x;
  if (l >= L) return;
  float m  = sums[c]*invc;
  float v  = fmaxf(sums[Cn+c]*invc - m*m, 0.f);
  float sc = g[c]*rsqrtf(v + 1e-5f);
  float bb = bet[c] - m*sc;
  size_t idx = (size_t)b*bstride + (size_t)c*cstride + l;
  float val = fmaf(x[idx], sc, bb);
  x[idx] = fmaxf(val, 0.f);
}

// BN+ReLU in place over [b][64][16][1296] AND write T-mean to xm
__global__ void k_bnrelu_mean(float* __restrict__ x, const float* __restrict__ sums,
                              const float* __restrict__ g, const float* __restrict__ bet,
                              float invc, float* __restrict__ xm)
{
  int hw = blockIdx.x*256 + threadIdx.x;
  if (hw >= 1296) return;
  int c = blockIdx.y, b = blockIdx.z;
  float m  = sums[c]*invc;
  float v  = fmaxf(sums[64+c]*invc - m*m, 0.f);
  float sc = g[c]*rsqrtf(v + 1e-5f);
  float bb = bet[c] - m*sc;
  float* xb = x + ((size_t)(b*64 + c)*16)*1296 + hw;
  float s = 0.f;
  #pragma unroll
  for (int t = 0; t < 16; ++t){
    float val = fmaxf(fmaf(xb[(size_t)t*1296], sc, bb), 0.f);
    xb[(size_t)t*1296] = val;
    s += val;
  }
  xm[((size_t)b*64 + c)*1296 + hw] = s*(1.f/16.f);
}

// BN+ReLU on raw f32 [b][64][L] -> bf16 P layout rows [b][n][outC] at coff
__global__ void k_bnT(const float* __restrict__ x, const float* __restrict__ sums,
                      const float* __restrict__ g, const float* __restrict__ bet, float invc,
                      unsigned short* __restrict__ P1, unsigned short* __restrict__ P2,
                      int L, int outC, int coff)
{
  __shared__ unsigned lds[8448];
  int tid = threadIdx.x, b = blockIdx.z;
  int n0 = blockIdx.x*256, n = n0 + tid;
  const float* xb = x + (size_t)b*64*L + n;
  float a[64];
  #pragma unroll
  for (int c = 0; c < 64; ++c){
    float m  = sums[c]*invc;
    float vv = fmaxf(sums[64+c]*invc - m*m, 0.f);
    float sc = g[c]*rsqrtf(vv + 1e-5f);
    float bb = bet[c] - m*sc;
    a[c] = fmaxf(fmaf(xb[(size_t)c*L], sc, bb), 0.f);
  }
  unsigned vals[32];
  pack_pairs(a, vals);
  staged_write(lds, tid, vals, (uint4*)P1, (size_t)b*L + n0, outC >> 3, coff >> 3,
               P2 ? (uint4*)P2 : nullptr);
}

// composed-concat BN+ReLU -> bf16 PTE [b][n][64]
__global__ void k_bnT_cc(const float* __restrict__ A, const float* __restrict__ M,
                         const float* __restrict__ B, const float* __restrict__ sums,
                         const float* __restrict__ g, const float* __restrict__ bet,
                         float invc, unsigned short* __restrict__ P1)
{
  __shared__ unsigned lds[8448];
  int tid = threadIdx.x, b = blockIdx.z;
  int n0 = blockIdx.x*256, n = n0 + tid;
  int t = n / 1296, hw = n - t*1296;
  const float* src; size_t cstride;
  if (t < 15){ src = A + ((size_t)(b*64)*16 + t)*1296 + hw; cstride = (size_t)16*1296; }
  else if (t < 17){ src = M + ((size_t)(b*64)*2 + (t-15))*1296 + hw; cstride = (size_t)2*1296; }
  else { src = B + ((size_t)(b*64)*16 + (t-16))*1296 + hw; cstride = (size_t)16*1296; }
  float a[64];
  #pragma unroll
  for (int c = 0; c < 64; ++c){
    float m  = sums[c]*invc;
    float vv = fmaxf(sums[64+c]*invc - m*m, 0.f);
    float sc = g[c]*rsqrtf(vv + 1e-5f);
    float bb = bet[c] - m*sc;
    a[c] = fmaxf(fmaf(src[c*cstride], sc, bb), 0.f);
  }
  unsigned vals[32];
  pack_pairs(a, vals);
  staged_write(lds, tid, vals, (uint4*)P1, (size_t)b*N2 + n0, 8, 0, nullptr);
}

// ---------------- PAM ----------------

// adaptive pools of xm -> pp_t[b][cell][c]
__global__ void k_pool(const float* __restrict__ xm, float* __restrict__ pp_t){
  int c = blockIdx.y, b = blockIdx.z;
  int cell = threadIdx.x;
  if (cell >= 50) return;
  int s, off;
  if (cell < 1){ s=1; off=0; } else if (cell < 5){ s=2; off=1; }
  else if (cell < 14){ s=3; off=5; } else { s=6; off=14; }
  int local = cell - off, ph = local/s, pw = local%s, bh = 36/s;
  const float* xp = xm + (size_t)(b*64+c)*HW;
  float sum = 0.f;
  for (int h = ph*bh; h < (ph+1)*bh; ++h)
    for (int w = pw*bh; w < (pw+1)*bh; ++w) sum += xp[h*36 + w];
  pp_t[((size_t)b*50 + cell)*64 + c] = sum / (float)(bh*bh);
}

// parallel PAM encoder stage 1: pemm + BN partial sums (block = (cell, b), 64 thr)
__global__ void k_pamenc1(const float* __restrict__ pp_t, const float* __restrict__ pe_w,
                          float* __restrict__ pf, float* __restrict__ sl){
  int cell = blockIdx.x, b = blockIdx.z;
  int o = threadIdx.x;
  int grp = (cell < 1) ? 0 : (cell < 5) ? 1 : (cell < 14) ? 2 : 3;
  const float* w = pe_w + (size_t)grp*4096 + o*64;
  const float* p = pp_t + ((size_t)b*50 + cell)*64;
  float s = 0.f;
  #pragma unroll
  for (int i = 0; i < 64; ++i) s = fmaf(w[i], p[i], s);
  pf[((size_t)b*64 + o)*50 + cell] = s;
  atomicAdd(&sl[grp*128 + o], s);
  atomicAdd(&sl[grp*128 + 64 + o], s*s);
}

// stage 2: BN finalize + ReLU; kb, vb, KW, sb  (block = (k, b), 128 thr)
__launch_bounds__(128)
__global__ void k_pamenc2(const float* __restrict__ pf, const float* __restrict__ sl,
                          const float* __restrict__ pe_g, const float* __restrict__ pe_b,
                          const float* __restrict__ wk, const float* __restrict__ bk,
                          const float* __restrict__ wv, const float* __restrict__ bv,
                          const float* __restrict__ wq, const float* __restrict__ bq,
                          float* __restrict__ vb, float* __restrict__ KW,
                          float* __restrict__ sb)
{
  __shared__ float yk[64];
  __shared__ float kbl[16];
  int k = blockIdx.x, b = blockIdx.z;
  int tid = threadIdx.x;
  int grp = (k < 1) ? 0 : (k < 5) ? 1 : (k < 14) ? 2 : 3;
  const float ss2[4] = {1.f, 4.f, 9.f, 36.f};
  if (tid < 64){
    float invc = 1.f/(4.f*ss2[grp]);
    float m = sl[grp*128 + tid]*invc;
    float var = fmaxf(sl[grp*128 + 64 + tid]*invc - m*m, 0.f);
    float sc = pe_g[grp*64 + tid]*rsqrtf(var + 1e-5f);
    float sh = pe_b[grp*64 + tid] - m*sc;
    yk[tid] = fmaxf(fmaf(pf[((size_t)b*64 + tid)*50 + k], sc, sh), 0.f);
  }
  __syncthreads();
  if (tid < 16){
    float s = bk[tid];
    #pragma unroll
    for (int c = 0; c < 64; ++c) s = fmaf(wk[tid*64 + c], yk[c], s);
    kbl[tid] = s;
  } else if (tid < 80){
    int c = tid - 16;
    float s = bv[c];
    #pragma unroll
    for (int i = 0; i < 64; ++i) s = fmaf(wv[c*64 + i], yk[i], s);
    vb[((size_t)b*50 + k)*64 + c] = s;
  }
  __syncthreads();
  if (tid < 64){
    float s = 0.f;
    #pragma unroll
    for (int o = 0; o < 16; ++o) s = fmaf(kbl[o], wq[o*64 + tid], s);
    KW[((size_t)b*50 + k)*64 + tid] = s;
  } else if (tid == 64){
    float s = 0.f;
    #pragma unroll
    for (int o = 0; o < 16; ++o) s = fmaf(kbl[o], bq[o], s);
    sb[(size_t)b*50 + k] = s;
  }
}

// scores via KW trick; softmax; PV + residual; staged bf16 write
__launch_bounds__(256, 1)
__global__ void k_pamattn(const float* __restrict__ x, const float* __restrict__ KW,
                          const float* __restrict__ sbb, const float* __restrict__ vbuf,
                          const float* __restrict__ scp, unsigned short* __restrict__ Pg)
{
  __shared__ unsigned smem_u[8448];
  float* smem = (float*)smem_u;
  int b = blockIdx.z, tid = threadIdx.x;
  for (int i = tid; i < 3200; i += 256){
    smem[i]        = KW[(size_t)b*3200 + i];
    smem[3200 + i] = vbuf[(size_t)b*3200 + i];
  }
  if (tid < 50) smem[6400 + tid] = sbb[(size_t)b*50 + tid];
  __syncthreads();
  int n0 = blockIdx.x*256;
  int n = n0 + tid;
  const float* xb = x + (size_t)b*64*Nn + n;
  float xv[64];
  #pragma unroll
  for (int c = 0; c < 64; ++c) xv[c] = xb[(size_t)c*Nn];
  float s[50];
  const float4* kw4 = (const float4*)smem;
  #pragma unroll
  for (int k = 0; k < 50; ++k){
    float t = smem[6400 + k];
    #pragma unroll
    for (int c4 = 0; c4 < 16; ++c4){
      float4 kw = kw4[k*16 + c4];
      t = fmaf(xv[c4*4+0], kw.x, t);
      t = fmaf(xv[c4*4+1], kw.y, t);
      t = fmaf(xv[c4*4+2], kw.z, t);
      t = fmaf(xv[c4*4+3], kw.w, t);
    }
    s[k] = t;
  }
  float mx = -1e30f;
  #pragma unroll
  for (int k = 0; k < 50; ++k) mx = fmaxf(mx, s[k]);
  float sum = 0.f;
  #pragma unroll
  for (int k = 0; k < 50; ++k){ float p = __expf(s[k]-mx); s[k] = p; sum += p; }
  float sc = scp[0]/sum;
  const float4* vl4 = (const float4*)(smem + 3200);
  #pragma unroll
  for (int k = 0; k < 50; ++k){
    float pk = sc * s[k];
    #pragma unroll
    for (int c4 = 0; c4 < 16; ++c4){
      float4 v = vl4[k*16 + c4];
      xv[c4*4+0] = fmaf(pk, v.x, xv[c4*4+0]);
      xv[c4*4+1] = fmaf(pk, v.y, xv[c4*4+1]);
      xv[c4*4+2] = fmaf(pk, v.z, xv[c4*4+2]);
      xv[c4*4+3] = fmaf(pk, v.w, xv[c4*4+3]);
    }
  }
  __syncthreads();
  unsigned vals[32];
  pack_pairs(xv, vals);
  staged_write(smem_u, tid, vals, (uint4*)Pg, (size_t)b*Nn + n0, 8, 0, nullptr);
}

// ---------------- CAM ----------------

__global__ void k_camenergy2(const float* __restrict__ x, const float* __restrict__ yc,
                             float* __restrict__ e){
  __shared__ float yl[4][256];
  int b = blockIdx.z, tid = threadIdx.x;
  int n0 = blockIdx.x*256;
  #pragma unroll
  for (int k = 0; k < 4; ++k)
    yl[k][tid] = yc[((size_t)b*4+k)*Nn + n0 + tid];
  __syncthreads();
  int c = tid & 63, ks = tid >> 6;
  const float* xr = x + (size_t)(b*64+c)*Nn + n0;
  const float* yr = yl[ks];
  float acc = 0.f;
  #pragma unroll 8
  for (int i = 0; i < 256; ++i) acc = fmaf(xr[i], yr[i], acc);
  atomicAdd(&e[((size_t)(b*64)+c)*4 + ks], acc);
}

__global__ void k_camapplyT(const float* __restrict__ x, const float* __restrict__ yc,
                            const float* __restrict__ e, const float* __restrict__ scp,
                            unsigned short* __restrict__ Pg){
  __shared__ float pw[64][4];
  __shared__ unsigned lds[8448];
  int tid = threadIdx.x;
  int b = blockIdx.z;
  if (tid < 64){
    const float* er = e + (size_t)(b*64+tid)*4;
    float e0=er[0], e1=er[1], e2=er[2], e3=er[3];
    float mx = fmaxf(fmaxf(e0,e1), fmaxf(e2,e3));
    float z0=mx-e0, z1=mx-e1, z2=mx-e2, z3=mx-e3;
    float zm = fmaxf(fmaxf(z0,z1), fmaxf(z2,z3));
    float p0=__expf(z0-zm), p1=__expf(z1-zm), p2=__expf(z2-zm), p3=__expf(z3-zm);
    float inv = 1.f/(p0+p1+p2+p3);
    pw[tid][0]=p0*inv; pw[tid][1]=p1*inv; pw[tid][2]=p2*inv; pw[tid][3]=p3*inv;
  }
  __syncthreads();
  int n0 = blockIdx.x*256;
  int n = n0 + tid;
  float y0 = yc[((size_t)b*4+0)*Nn + n];
  float y1 = yc[((size_t)b*4+1)*Nn + n];
  float y2 = yc[((size_t)b*4+2)*Nn + n];
  float y3 = yc[((size_t)b*4+3)*Nn + n];
  float sc = scp[0];
  const float* xb = x + (size_t)b*64*Nn + n;
  float a[64];
  #pragma unroll
  for (int c = 0; c < 64; ++c){
    a[c] = fmaf(sc, pw[c][0]*y0 + pw[c][1]*y1 + pw[c][2]*y2 + pw[c][3]*y3,
                xb[(size_t)c*Nn]);
  }
  unsigned vals[32];
  pack_pairs(a, vals);
  staged_write(lds, tid, vals, (uint4*)Pg, (size_t)b*Nn + n0, 8, 0, nullptr);
}

// ---------------- TAM ----------------

__launch_bounds__(256)
__global__ void k_tamenergy_mf(const unsigned short* __restrict__ X,
                               const unsigned short* __restrict__ Y,
                               float* __restrict__ E){
  int b = blockIdx.z;
  int wave = threadIdx.x >> 6, lane = threadIdx.x & 63;
  int r = lane & 15, g = lane >> 4;
  const unsigned short* Xb = X + (size_t)b*32*82944;
  const unsigned short* Yb = Y + (size_t)b*32*82944;
  f32x4 a00 = (f32x4){0.f,0.f,0.f,0.f};
  f32x4 a01 = a00, a10 = a00, a11 = a00;
  int c0 = (blockIdx.x*4 + wave)*8;
  for (int cc = 0; cc < 8; ++cc){
    size_t k0 = (size_t)(c0 + cc)*32 + (size_t)g*8;
    bf16x8 x0 = *(const bf16x8*)(Xb + (size_t)r*82944 + k0);
    bf16x8 x1 = *(const bf16x8*)(Xb + (size_t)(r+16)*82944 + k0);
    bf16x8 y0 = *(const bf16x8*)(Yb + (size_t)r*82944 + k0);
    bf16x8 y1 = *(const bf16x8*)(Yb + (size_t)(r+16)*82944 + k0);
    a00 = __builtin_amdgcn_mfma_f32_16x16x32_bf16(x0, y0, a00, 0, 0, 0);
    a01 = __builtin_amdgcn_mfma_f32_16x16x32_bf16(x0, y1, a01, 0, 0, 0);
    a10 = __builtin_amdgcn_mfma_f32_16x16x32_bf16(x1, y0, a10, 0, 0, 0);
    a11 = __builtin_amdgcn_mfma_f32_16x16x32_bf16(x1, y1, a11, 0, 0, 0);
  }
  float* Eb = E + (size_t)b*1024;
  #pragma unroll
  for (int rr = 0; rr < 4; ++rr){
    int row = g*4 + rr;
    atomicAdd(&Eb[row*32 + r],           a00[rr]);
    atomicAdd(&Eb[row*32 + 16 + r],      a01[rr]);
    atomicAdd(&Eb[(row+16)*32 + r],      a10[rr]);
    atomicAdd(&Eb[(row+16)*32 + 16 + r], a11[rr]);
  }
}

// inline softmax + LDS-tiled apply -> bf16 P-layout
__launch_bounds__(256)
__global__ void k_tamapply_mf(const unsigned short* __restrict__ Xbf,
                              const unsigned short* __restrict__ Ybf,
                              const float* __restrict__ e, const float* __restrict__ scp,
                              unsigned short* __restrict__ Pout){
  __shared__ unsigned short yl[32*8*TAPAD];
  __shared__ float al[1024];
  int b = blockIdx.z, tid = threadIdx.x;
  int hw0 = blockIdx.x*8;
  if (tid < 32){
    const float* er = e + (size_t)b*1024 + tid*32;
    float mx = -1e30f, mn = 1e30f;
    for (int j = 0; j < 32; ++j){ mx = fmaxf(mx, er[j]); mn = fminf(mn, er[j]); }
    float zmax = mx - mn;
    float sum = 0.f;
    for (int j = 0; j < 32; ++j){
      float p = __expf((mx - er[j]) - zmax);
      al[tid*32 + j] = p; sum += p;
    }
    float inv = 1.f/sum;
    for (int j = 0; j < 32; ++j) al[tid*32 + j] *= inv;
  }
  const uint4* src = (const uint4*)Ybf + (size_t)b*N2*8;
  #pragma unroll
  for (int it = 0; it < 8; ++it){
    int idx = it*256 + tid;
    int j = idx >> 6, rem = idx & 63, h = rem >> 3, w = rem & 7;
    uint4 v = src[(size_t)(j*1296 + hw0 + h)*8 + w];
    *(uint4*)&yl[(j*8+h)*TAPAD + w*8] = v;
  }
  __syncthreads();
  int t = tid >> 3, h = tid & 7;
  int n = t*1296 + hw0 + h;
  float sc = scp[0];
  const uint4* xr = (const uint4*)Xbf + ((size_t)b*N2 + n)*8;
  float acc[64];
  #pragma unroll
  for (int w = 0; w < 8; ++w){
    uint4 v = xr[w];
    acc[w*8+0] = b2f_lo(v.x); acc[w*8+1] = b2f_hi(v.x);
    acc[w*8+2] = b2f_lo(v.y); acc[w*8+3] = b2f_hi(v.y);
    acc[w*8+4] = b2f_lo(v.z); acc[w*8+5] = b2f_hi(v.z);
    acc[w*8+6] = b2f_lo(v.w); acc[w*8+7] = b2f_hi(v.w);
  }
  const float* ar = &al[t*32];
  for (int j = 0; j < 32; ++j){
    float aj = sc * ar[j];
    const uint4* yr = (const uint4*)&yl[(j*8+h)*TAPAD];
    #pragma unroll
    for (int w = 0; w < 8; ++w){
      uint4 v = yr[w];
      acc[w*8+0] = fmaf(aj, b2f_lo(v.x), acc[w*8+0]);
      acc[w*8+1] = fmaf(aj, b2f_hi(v.x), acc[w*8+1]);
      acc[w*8+2] = fmaf(aj, b2f_lo(v.y), acc[w*8+2]);
      acc[w*8+3] = fmaf(aj, b2f_hi(v.y), acc[w*8+3]);
      acc[w*8+4] = fmaf(aj, b2f_lo(v.z), acc[w*8+4]);
      acc[w*8+5] = fmaf(aj, b2f_hi(v.z), acc[w*8+5]);
      acc[w*8+6] = fmaf(aj, b2f_lo(v.w), acc[w*8+6]);
      acc[w*8+7] = fmaf(aj, b2f_hi(v.w), acc[w*8+7]);
    }
  }
  uint4* orow = (uint4*)Pout + ((size_t)b*N2 + n)*8;
  #pragma unroll
  for (int w = 0; w < 8; ++w){
    uint4 v;
    v.x = (unsigned)f2b(acc[w*8+0]) | ((unsigned)f2b(acc[w*8+1]) << 16);
    v.y = (unsigned)f2b(acc[w*8+2]) | ((unsigned)f2b(acc[w*8+3]) << 16);
    v.z = (unsigned)f2b(acc[w*8+4]) | ((unsigned)f2b(acc[w*8+5]) << 16);
    v.w = (unsigned)f2b(acc[w*8+6]) | ((unsigned)f2b(acc[w*8+7]) << 16);
    orow[w] = v;
  }
}

// ---------------- host ----------------

extern "C" void kernel_launch(void* const* d_in, const int* in_sizes, int n_in,
                              void* d_out, int out_size, void* d_ws, size_t ws_size,
                              hipStream_t stream) {
  const float* x1      = (const float*)d_in[0];
  const float* x2      = (const float*)d_in[1];
  const float* w_conv1 = (const float*)d_in[2];
  const float* g_conv1 = (const float*)d_in[3];
  const float* b_conv1 = (const float*)d_in[4];
  const float* w_conv2 = (const float*)d_in[5];
  const float* g_conv2 = (const float*)d_in[6];
  const float* b_conv2 = (const float*)d_in[7];
  const float* w_tam   = (const float*)d_in[8];
  const float* g_tam   = (const float*)d_in[9];
  const float* b_tam   = (const float*)d_in[10];
  const float* w_cat   = (const float*)d_in[11];
  const float* g_cat   = (const float*)d_in[12];
  const float* b_cat   = (const float*)d_in[13];
  const float* pe_w    = (const float*)d_in[14];
  const float* pe_g    = (const float*)d_in[15];
  const float* pe_b    = (const float*)d_in[16];
  const float* pd_wq   = (const float*)d_in[17];
  const float* pd_bq   = (const float*)d_in[18];
  const float* pd_wk   = (const float*)d_in[19];
  const float* pd_bk   = (const float*)d_in[20];
  const float* pd_wv   = (const float*)d_in[21];
  const float* pd_bv   = (const float*)d_in[22];
  const float* pd_scale= (const float*)d_in[23];
  const float* ce_w    = (const float*)d_in[24];
  const float* ce_g    = (const float*)d_in[25];
  const float* ce_b    = (const float*)d_in[26];
  const float* cd_scale= (const float*)d_in[27];
  const float* te_w    = (const float*)d_in[28];
  const float* te_g    = (const float*)d_in[29];
  const float* te_b    = (const float*)d_in[30];
  const float* td_scale= (const float*)d_in[31];

  float* ws = (float*)d_ws;
  size_t off = 0;
  auto alloc = [&](size_t n){ float* p = ws + off; off += (n + 3) & ~(size_t)3; return p; };
  float* stats = alloc(16384);   // 32 slots x 512
  float* e_tam = alloc(4096);
  float* e_cam = alloc(2048);
  float* wTce  = alloc(256);
  unsigned short* Wp1  = (unsigned short*)alloc(24576);
  unsigned short* Wp2  = (unsigned short*)alloc(6144);
  unsigned short* Wpt  = (unsigned short*)alloc(6144);
  unsigned short* Wpc  = (unsigned short*)alloc(73728);
  unsigned short* Wpte = (unsigned short*)alloc(2048);
  float* xm    = alloc(331776);
  float* pp_t  = alloc(12800);
  float* pfb   = alloc(12800);
  float* vb    = alloc(12800);
  float* KWb   = alloc(12800);
  float* sbb   = alloc(256);
  float* yc    = alloc(331776);
  float* Mb    = alloc(663552);
  float* A     = alloc(5308416);
  float* Bb    = alloc(5308416);
  float* PTEf  = alloc(5308416);
  float* COMB  = alloc(31850496);

  unsigned short* P0 = (unsigned short*)COMB;
  float* Dd = COMB;
  unsigned short* Dbf  = (unsigned short*)(COMB + 10616832);
  unsigned short* PTAM = (unsigned short*)(COMB + 15925248);
  float* Rraw = COMB;
  unsigned short* PCAT1 = (unsigned short*)(COMB + 5308416);
  unsigned short* PCAT2 = (unsigned short*)(COMB + 13271040);
  unsigned short* PG    = (unsigned short*)(COMB + 21233664);
  unsigned short* PTE = (unsigned short*)PTEf;

  const float invc16 = 1.f/(4.f*20736.f);
  const float invc32 = 1.f/(4.f*41472.f);

  k_zero<<<dim3(88), 256, 0, stream>>>(stats, 22528);
  k_wprep<<<dim3(881), 256, 0, stream>>>(w_conv1, w_conv2, w_tam, w_cat, te_w, ce_w,
                                         Wp1, Wp2, Wpt, Wpc, Wpte, wTce);
  k_convT<<<dim3(81, 1, 4), 256, 0, stream>>>(x1, P0, 256, Nn, 32, 0);
  k_convT<<<dim3(81, 1, 4), 256, 0, stream>>>(x2, P0, 256, Nn, 32, 16);

  // conv1 raw: A (slot0), B (slot1), boundary planes Mb (slot21)
  k_mfconv<<<dim3(7,16,4), 256, 0, stream>>>(P0, Wp1, A,  256, 64, 1, 16, 1, 3, 1, 0, 0, 16, 32, stats + 0*512);
  k_mfconv<<<dim3(7,16,4), 256, 0, stream>>>(P0, Wp1, Bb, 256, 64, 1, 16, 1, 3, 1, 16, 16, 32, 32, stats + 1*512);
  k_mfconv<<<dim3(7,2,4),  256, 0, stream>>>(P0, Wp1, Mb, 256, 64, 1, 2, 1, 3, 1, 15, 0, 32, 32, stats + 21*512);
  k_planestats<<<dim3(1,64,2), 256, 0, stream>>>(A, Bb, stats + 22*512, stats + 23*512);
  k_combine<<<dim3(1), 128, 0, stream>>>(stats);
  k_bnT_cc<<<dim3(162,1,4), 256, 0, stream>>>(A, Mb, Bb, stats + 2*512,
                                              g_conv1, b_conv1, invc32, PTE);

  // xt2 = pw_bn_relu(xt1, te_w)
  k_mfconv<<<dim3(7,32,4), 256, 0, stream>>>(PTE, Wpte, Dd, 64, 64, 1, 32, 1, 1, 0, 0, 0, 32, 32, stats + 3*512);
  k_bnT<<<dim3(162,1,4), 256, 0, stream>>>(Dd, stats + 3*512, te_g, te_b, invc32,
                                           Dbf, nullptr, N2, 64, 0);

  // TAM
  k_tamenergy_mf<<<dim3(81, 1, 4), 256, 0, stream>>>(PTE, Dbf, e_tam);
  k_tamapply_mf<<<dim3(162, 1, 4), 256, 0, stream>>>(PTE, Dbf, e_tam, td_scale, PTAM);
  k_mfconv<<<dim3(7,16,4), 256, 0, stream>>>(PTAM, Wpt, Rraw, 64, 64, 1, 16, 2, 3, 1, 0, 0, 32, 32, stats + 4*512);
  k_bnT<<<dim3(81,1,4), 256, 0, stream>>>(Rraw, stats + 4*512, g_tam, b_tam, invc16,
                                          PCAT1, PCAT2, Nn, 192, 128);

  auto pam = [&](float* xin, unsigned short* catp, int slot_pe, int slot_c2){
    k_pool<<<dim3(1, 64, 4), 64, 0, stream>>>(xm, pp_t);
    k_pamenc1<<<dim3(50, 1, 4), 64, 0, stream>>>(pp_t, pe_w, pfb, stats + (size_t)slot_pe*512);
    k_pamenc2<<<dim3(50, 1, 4), 128, 0, stream>>>(pfb, stats + (size_t)slot_pe*512,
                                                  pe_g, pe_b, pd_wk, pd_bk, pd_wv, pd_bv,
                                                  pd_wq, pd_bq, vb, KWb, sbb);
    k_pamattn<<<dim3(81, 1, 4), 256, 0, stream>>>(xin, KWb, sbb, vb, pd_scale, PG);
    k_mfconv<<<dim3(7,16,4), 256, 0, stream>>>(PG, Wp2, Rraw, 64, 64, 1, 16, 1, 3, 1, 0, 0, 16, 16, stats + (size_t)slot_c2*512);
    k_bnT<<<dim3(81,1,4), 256, 0, stream>>>(Rraw, stats + (size_t)slot_c2*512,
                                            g_conv2, b_conv2, invc16, catp, nullptr, Nn, 192, 0);
  };
  auto cam = [&](const float* xin, unsigned short* catp, float* ecam,
                 int slot_ce, int slot_c2){
    k_tconv<<<dim3(6, 16, 4), dim3(4, 64), 0, stream>>>(xin, wTce, yc, 64, 4, 16);
    k_bnstats<<<dim3(16, 4), 256, 0, stream>>>(yc, 4, 4, Nn, 4L*Nn, (long)Nn,
                                               stats + (size_t)slot_ce*512);
    k_bnrelu<<<dim3((Nn+255)/256, 4, 4), 256, 0, stream>>>(yc, 4, Nn, 4L*Nn, (long)Nn,
                                               stats + (size_t)slot_ce*512, ce_g, ce_b, invc16);
    k_camenergy2<<<dim3(81, 1, 4), 256, 0, stream>>>(xin, yc, ecam);
    k_camapplyT<<<dim3(81, 1, 4), 256, 0, stream>>>(xin, yc, ecam, cd_scale, PG);
    k_mfconv<<<dim3(7,16,4), 256, 0, stream>>>(PG, Wp2, Rraw, 64, 64, 1, 16, 1, 3, 1, 0, 0, 16, 16, stats + (size_t)slot_c2*512);
    k_bnT<<<dim3(81,1,4), 256, 0, stream>>>(Rraw, stats + (size_t)slot_c2*512,
                                            g_conv2, b_conv2, invc16, catp, nullptr, Nn, 192, 64);
  };

  // x1 branch
  k_bnrelu_mean<<<dim3(6,64,4), 256, 0, stream>>>(A, stats + 0*512, g_conv1, b_conv1,
                                                  invc16, xm);
  pam(A, PCAT1, 5, 13);
  cam(A, PCAT2, e_cam, 15, 17);
  // x2 branch
  k_bnrelu_mean<<<dim3(6,64,4), 256, 0, stream>>>(Bb, stats + 1*512, g_conv1, b_conv1,
                                                  invc16, xm);
  pam(Bb, PCAT2, 9, 14);
  cam(Bb, PCAT1, e_cam + 1024, 16, 18);

  // final cat convs -> d_out
  float* out1 = (float*)d_out;
  float* out2 = out1 + (size_t)4*256*Nn;
  k_mfconv<<<dim3(7,16,16), 256, 0, stream>>>(PCAT1, Wpc, out1, 192, 256, 4, 16, 1, 3, 1, 0, 0, 16, 16, stats + 19*512);
  k_bnrelu<<<dim3((Nn+255)/256, 256, 4), 256, 0, stream>>>(out1, 256, Nn, 256L*Nn, (long)Nn,
                                             stats + 19*512, g_cat, b_cat, invc16);
  k_mfconv<<<dim3(7,16,16), 256, 0, stream>>>(PCAT2, Wpc, out2, 192, 256, 4, 16, 1, 3, 1, 0, 0, 16, 16, stats + 20*512);
  k_bnrelu<<<dim3((Nn+255)/256, 256, 4), 256, 0, stream>>>(out2, 256, Nn, 256L*Nn, (long)Nn,
                                             stats + 20*512, g_cat, b_cat, invc16);
}